// Round 8
// baseline (6839.447 us; speedup 1.0000x reference)
//
#include <hip/hip_runtime.h>

// ---------------------------------------------------------------------------
// AttentionDecoder. R5 law: recurrence weights read ONCE per step (col-sliced
// over all 64 batch rows). R6 law: launch overhead dominates -> ONE persistent
// kernel. R7 lesson: hipLaunchCooperativeKernel silently fails here ->
// SOFTWARE grid barrier (device-scope atomics, sense-reversing, init'd per
// call). Phase bodies are verbatim R6-verified kernels.
//   k_recur, 128 blk x 256 thr, per step:
//     PG (64 blk):  GRU elementwise -> hst/h_bf/outs
//     P1 (40 blk):  [q|gh] = h @ [Wq1;Wq2;Whh]^T  (MFMA M=64, gload16)
//     P2 (128 blk): scores/softmax/att per (b,side)
//     P3 (24 blk):  gi = att @ Wf^T + gi_x + bfull
// ---------------------------------------------------------------------------

typedef float    f32x4 __attribute__((ext_vector_type(4)));
typedef __bf16   bf16x8 __attribute__((ext_vector_type(8)));
typedef unsigned short u16x8 __attribute__((ext_vector_type(8)));

#define DEV __device__ __forceinline__

DEV unsigned short f2bf(float f) {
  unsigned u = __builtin_bit_cast(unsigned, f);
  u += 0x7fffu + ((u >> 16) & 1u);
  return (unsigned short)(u >> 16);
}
DEV float bf2f(unsigned short h) {
  return __builtin_bit_cast(float, (unsigned)h << 16);
}
DEV bf16x8 as_bf(u16x8 v) { return __builtin_bit_cast(bf16x8, v); }
DEV u16x8 zero8() {
  u16x8 r = {0, 0, 0, 0, 0, 0, 0, 0};
  return r;
}
DEV u16x8 pack8(float4 a, float4 b) {
  u16x8 r;
  r[0]=f2bf(a.x); r[1]=f2bf(a.y); r[2]=f2bf(a.z); r[3]=f2bf(a.w);
  r[4]=f2bf(b.x); r[5]=f2bf(b.y); r[6]=f2bf(b.z); r[7]=f2bf(b.w);
  return r;
}
DEV void gload16(const void* g, void* l) {
  __builtin_amdgcn_global_load_lds(
      (const __attribute__((address_space(1))) void*)g,
      (__attribute__((address_space(3))) void*)l, 16, 0, 0);
}

// --------------------- software grid barrier --------------------------------
// Sense-reversing via monotonically increasing generation. Device-scope
// atomics (cross-XCD coherent). my_gen is a per-thread register (uniform).
DEV void gridbar(unsigned* cnt, unsigned* gen, unsigned& my_gen, int nblk) {
  __syncthreads();
  __threadfence();
  if (threadIdx.x == 0) {
    my_gen++;
    unsigned prev = __hip_atomic_fetch_add(cnt, 1u, __ATOMIC_ACQ_REL,
                                           __HIP_MEMORY_SCOPE_AGENT);
    if (prev == (unsigned)nblk - 1) {
      __hip_atomic_store(cnt, 0u, __ATOMIC_RELAXED, __HIP_MEMORY_SCOPE_AGENT);
      __hip_atomic_store(gen, my_gen, __ATOMIC_RELEASE, __HIP_MEMORY_SCOPE_AGENT);
    } else {
      while (__hip_atomic_load(gen, __ATOMIC_ACQUIRE,
                               __HIP_MEMORY_SCOPE_AGENT) < my_gen)
        __builtin_amdgcn_s_sleep(4);
    }
  }
  __threadfence();
  __syncthreads();
}

__global__ void k_init(unsigned* bar) {
  if (threadIdx.x == 0) { bar[0] = 0u; bar[1] = 0u; }
}

// ------------------------------- converts ----------------------------------
__global__ __launch_bounds__(256) void k_cvt(const float* __restrict__ s,
                                             unsigned short* __restrict__ d, int n) {
  int i = (blockIdx.x * 256 + threadIdx.x) * 4;
  if (i + 4 <= n) {
    float4 v = *(const float4*)(s + i);
    d[i] = f2bf(v.x); d[i+1] = f2bf(v.y); d[i+2] = f2bf(v.z); d[i+3] = f2bf(v.w);
  } else {
    for (; i < n; i++) d[i] = f2bf(s[i]);
  }
}

// ctx_feat = [s1, s2, |s1-s2|, s1*s2]  -> bf16 [64, 16384]
__global__ __launch_bounds__(256) void k_build_ctx(const float* __restrict__ s1,
                                                   const float* __restrict__ s2,
                                                   unsigned short* __restrict__ ctx) {
  int j = blockIdx.x * 256 + threadIdx.x;
  int b = j >> 14, jj = j & 16383;
  int f = jj >> 12, k = jj & 4095;
  float a = s1[b * 4096 + k], c = s2[b * 4096 + k];
  float v = (f == 0) ? a : (f == 1) ? c : (f == 2) ? fabsf(a - c) : a * c;
  ctx[j] = f2bf(v);
}

// --------------- bf16 128x128 GEMM with global_load_lds staging -------------
// EPI 0: tanh(+bias), split col 512, PERMUTED rows (tt*64+b -> b*128+tt)
// EPI 1: +bias -> f32, ld ofld
template<int EPI>
__global__ __launch_bounds__(256) void k_gemm_lds(
    const unsigned short* __restrict__ A, int lda,
    const unsigned short* __restrict__ B, int ldb, int K,
    unsigned short* __restrict__ obf0, unsigned short* __restrict__ obf1,
    float* __restrict__ of, int ofld,
    const float* __restrict__ bias0, const float* __restrict__ bias1)
{
  __shared__ __align__(16) unsigned short As[128 * 32];
  __shared__ __align__(16) unsigned short Bs[128 * 32];
  const int tid = threadIdx.x;
  const int r0 = blockIdx.x * 128, c0 = blockIdx.y * 128;
  const int lane = tid & 63, w = tid >> 6;
  const int wr = w >> 1, wc = w & 1;
  const int fr = lane & 15, fq = lane >> 4;
  f32x4 acc[4][4] = {};

  const int srow = tid >> 2, scol = (tid & 3) * 8;
  const unsigned short* gA0 = A + (size_t)(r0 + srow) * lda + scol;
  const unsigned short* gA1 = A + (size_t)(r0 + 64 + srow) * lda + scol;
  const unsigned short* gB0 = B + (size_t)(c0 + srow) * ldb + scol;
  const unsigned short* gB1 = B + (size_t)(c0 + 64 + srow) * ldb + scol;
  unsigned short* lA0 = As + tid * 8;
  unsigned short* lA1 = As + 2048 + tid * 8;
  unsigned short* lB0 = Bs + tid * 8;
  unsigned short* lB1 = Bs + 2048 + tid * 8;

  for (int k = 0; k < K; k += 32) {
    gload16(gA0 + k, lA0);
    gload16(gA1 + k, lA1);
    gload16(gB0 + k, lB0);
    gload16(gB1 + k, lB1);
    __syncthreads();

    u16x8 af[4], bfv[4];
    #pragma unroll
    for (int mi = 0; mi < 4; mi++)
      af[mi] = *(const u16x8*)&As[(wr * 64 + mi * 16 + fr) * 32 + fq * 8];
    #pragma unroll
    for (int nj = 0; nj < 4; nj++)
      bfv[nj] = *(const u16x8*)&Bs[(wc * 64 + nj * 16 + fr) * 32 + fq * 8];
    #pragma unroll
    for (int mi = 0; mi < 4; mi++)
      #pragma unroll
      for (int nj = 0; nj < 4; nj++)
        acc[mi][nj] = __builtin_amdgcn_mfma_f32_16x16x32_bf16(
            as_bf(af[mi]), as_bf(bfv[nj]), acc[mi][nj], 0, 0, 0);
    __syncthreads();
  }

  #pragma unroll
  for (int mi = 0; mi < 4; mi++)
  #pragma unroll
  for (int nj = 0; nj < 4; nj++) {
    f32x4 a = acc[mi][nj];
    #pragma unroll
    for (int j = 0; j < 4; j++) {
      int grow = r0 + wr * 64 + mi * 16 + fq * 4 + j;
      int gcol = c0 + wc * 64 + nj * 16 + fr;
      float v = a[j];
      if constexpr (EPI == 0) {
        float bias = gcol < 512 ? bias0[gcol] : bias1[gcol - 512];
        unsigned short r = f2bf(tanhf(v + bias));
        int prow = ((grow & 63) << 7) | (grow >> 6);
        (gcol < 512 ? obf0 : obf1)[(size_t)prow * 512 + (gcol & 511)] = r;
      } else {
        of[(size_t)grow * ofld + gcol] = v + bias0[gcol];
      }
    }
  }
}

// ------------------------- generic 128x128 MFMA GEMM ------------------------
// (h0 only: A bf16, B f32, raw f32 partials via z split-K)
template<int A_BF16, int B_BF16, int EPI>
__global__ __launch_bounds__(256) void k_gemm128(
    const void* __restrict__ Ap, int lda, const void* __restrict__ Bp, int ldb,
    int M, int N, int kper,
    unsigned short* __restrict__ obf0, unsigned short* __restrict__ obf1,
    float* __restrict__ of, const float* __restrict__ bias0,
    const float* __restrict__ bias1)
{
  __shared__ __align__(16) unsigned short As[128 * 32];
  __shared__ __align__(16) unsigned short Bs[128 * 32];
  const int tid = threadIdx.x;
  const int c0 = blockIdx.x * 128, r0 = blockIdx.y * 128;
  const int k0 = blockIdx.z * kper;
  if (EPI == 2) of += (size_t)blockIdx.z * M * N;

  const int lane = tid & 63, w = tid >> 6;
  const int wr = w >> 1, wc = w & 1;
  const int fr = lane & 15, fq = lane >> 4;

  f32x4 acc[4][4] = {};

  const int srow = tid >> 1, shalf = (tid & 1) * 16;

  for (int k = k0; k < k0 + kper; k += 32) {
    u16x8 a0, a1, b0, b1;
    {
      int gr = r0 + srow;
      if (gr < M) {
        if (A_BF16) {
          const unsigned short* a = (const unsigned short*)Ap + (size_t)gr * lda + k + shalf;
          a0 = *(const u16x8*)a; a1 = *(const u16x8*)(a + 8);
        } else {
          const float* a = (const float*)Ap + (size_t)gr * lda + k + shalf;
          float4 f0 = ((const float4*)a)[0], f1 = ((const float4*)a)[1];
          float4 f2 = ((const float4*)a)[2], f3 = ((const float4*)a)[3];
          a0 = pack8(f0, f1); a1 = pack8(f2, f3);
        }
      } else { a0 = zero8(); a1 = zero8(); }
    }
    {
      int gr = c0 + srow;
      if (B_BF16) {
        const unsigned short* p = (const unsigned short*)Bp + (size_t)gr * ldb + k + shalf;
        b0 = *(const u16x8*)p; b1 = *(const u16x8*)(p + 8);
      } else {
        const float* p = (const float*)Bp + (size_t)gr * ldb + k + shalf;
        float4 f0 = ((const float4*)p)[0], f1 = ((const float4*)p)[1];
        float4 f2 = ((const float4*)p)[2], f3 = ((const float4*)p)[3];
        b0 = pack8(f0, f1); b1 = pack8(f2, f3);
      }
    }
    *(u16x8*)&As[srow * 32 + shalf]     = a0;
    *(u16x8*)&As[srow * 32 + shalf + 8] = a1;
    *(u16x8*)&Bs[srow * 32 + shalf]     = b0;
    *(u16x8*)&Bs[srow * 32 + shalf + 8] = b1;
    __syncthreads();

    u16x8 af[4], bfv[4];
    #pragma unroll
    for (int mi = 0; mi < 4; mi++)
      af[mi] = *(const u16x8*)&As[(wr * 64 + mi * 16 + fr) * 32 + fq * 8];
    #pragma unroll
    for (int nj = 0; nj < 4; nj++)
      bfv[nj] = *(const u16x8*)&Bs[(wc * 64 + nj * 16 + fr) * 32 + fq * 8];
    #pragma unroll
    for (int mi = 0; mi < 4; mi++)
      #pragma unroll
      for (int nj = 0; nj < 4; nj++)
        acc[mi][nj] = __builtin_amdgcn_mfma_f32_16x16x32_bf16(
            as_bf(af[mi]), as_bf(bfv[nj]), acc[mi][nj], 0, 0, 0);
    __syncthreads();
  }

  #pragma unroll
  for (int mi = 0; mi < 4; mi++)
  #pragma unroll
  for (int nj = 0; nj < 4; nj++) {
    f32x4 a = acc[mi][nj];
    #pragma unroll
    for (int j = 0; j < 4; j++) {
      int grow = r0 + wr * 64 + mi * 16 + fq * 4 + j;
      int gcol = c0 + wc * 64 + nj * 16 + fr;
      if (grow < M) {
        float v = a[j];
        if constexpr (EPI == 1) {
          of[(size_t)grow * N + gcol] = v + bias0[gcol];
        } else if constexpr (EPI == 2) {
          of[(size_t)grow * N + gcol] = v;
        }
      }
    }
  }
}

__global__ __launch_bounds__(256) void k_reduce_h0(const float* __restrict__ part,
                                                   const float* __restrict__ b_ctx,
                                                   float* __restrict__ h,
                                                   unsigned short* __restrict__ h_bf) {
  int j = blockIdx.x * 256 + threadIdx.x;   // < 64*512
  float s = b_ctx[j & 511];
  for (int z = 0; z < 8; z++) s += part[z * 32768 + j];
  h[j] = s;
  h_bf[j] = f2bf(s);
}

// ------------------- W_f = W_ih @ W_in  fold (one-time) ---------------------
__global__ __launch_bounds__(256) void k_wf(const float* __restrict__ W_ih,
                                            const float* __restrict__ W_in,
                                            unsigned short* __restrict__ wf_att,
                                            float* __restrict__ wfx) {
  __shared__ float wl[8][512];
  int ic = blockIdx.x, jc = blockIdx.y, tid = threadIdx.x;
  for (int x = tid; x < 8 * 512; x += 256)
    wl[x >> 9][x & 511] = W_ih[(ic * 8 + (x >> 9)) * 512 + (x & 511)];
  __syncthreads();
  int j = jc * 256 + tid;
  if (j >= 1324) return;
  float acc[8] = {};
  for (int d = 0; d < 512; d++) {
    float win = W_in[d * 1324 + j];
    #pragma unroll
    for (int r = 0; r < 8; r++) acc[r] += wl[r][d] * win;
  }
  for (int r = 0; r < 8; r++) {
    int i = ic * 8 + r;
    if (j < 300) wfx[i * 300 + j] = acc[r];
    else         wf_att[i * 1024 + (j - 300)] = f2bf(acc[r]);
  }
}

__global__ __launch_bounds__(256) void k_bfull(const float* __restrict__ W_ih,
                                               const float* __restrict__ b_in,
                                               const float* __restrict__ b_ih,
                                               float* __restrict__ bfull) {
  int i = blockIdx.x * 256 + threadIdx.x;
  if (i >= 1536) return;
  float acc = b_ih[i];
  for (int d = 0; d < 512; d++) acc += W_ih[i * 512 + d] * b_in[d];
  bfull[i] = acc;
}

// gi_x[t*64+b, :] = expl[t,b,:300] @ Wfx^T
__global__ __launch_bounds__(256) void k_gix(const float* __restrict__ expl,
                                             const float* __restrict__ wfx,
                                             float* __restrict__ gi_x) {
  __shared__ float el[16][300];
  int rc = blockIdx.x, ic = blockIdx.y, tid = threadIdx.x;
  for (int x = tid; x < 16 * 300; x += 256)
    el[x / 300][x % 300] = expl[(size_t)(rc * 16 + x / 300) * 300 + (x % 300)];
  __syncthreads();
  int c = ic * 256 + tid;
  float acc[16] = {};
  for (int k = 0; k < 300; k++) {
    float wv = wfx[c * 300 + k];
    #pragma unroll
    for (int r = 0; r < 16; r++) acc[r] += el[r][k] * wv;
  }
  for (int r = 0; r < 16; r++) gi_x[(size_t)(rc * 16 + r) * 1536 + c] = acc[r];
}

// --------------------- persistent recurrence kernel -------------------------
// 128 blocks x 256 threads, t-loop inside, 4 software grid barriers per step.
__global__ __launch_bounds__(256) void k_recur(
    float* __restrict__ hst, unsigned short* __restrict__ h_bf,
    float* __restrict__ qf, float* __restrict__ ghf, float* __restrict__ gif,
    unsigned short* __restrict__ att_bf, unsigned short* __restrict__ outs_bf,
    const unsigned short* __restrict__ wcat, const unsigned short* __restrict__ wf_att,
    const unsigned short* __restrict__ keys1, const unsigned short* __restrict__ keys2,
    const unsigned short* __restrict__ vals1, const unsigned short* __restrict__ vals2,
    const float* __restrict__ bq1, const float* __restrict__ bq2,
    const float* __restrict__ b_hh, const float* __restrict__ gi_x,
    const float* __restrict__ bfull, unsigned* __restrict__ bar)
{
  const int blk = blockIdx.x, tid = threadIdx.x;
  __shared__ __align__(16) unsigned short As[64 * 32];
  __shared__ __align__(16) unsigned short Bs[64 * 32];
  __shared__ float qv[512];
  __shared__ float sred[128][2];
  __shared__ float pr[128];

  unsigned* bcnt = bar;
  unsigned* bgen = bar + 1;
  unsigned my_gen = 0;

  const int lane = tid & 63, w = tid >> 6;
  const int fr = lane & 15, fq = lane >> 4;
  const int srow = tid >> 2, soff = (tid & 3) * 8;

  for (int t = 0; t < 32; t++) {
    // ---- PG: GRU elementwise (h(t) from step t-1's gi/gh) ----
    if (t > 0 && blk < 64) {
      const int b = blk;
      for (int d = tid; d < 512; d += 256) {
        float ir = gif[b*1536 + d], iz = gif[b*1536 + 512 + d], inn = gif[b*1536 + 1024 + d];
        float hr = ghf[b*1536 + d], hz = ghf[b*1536 + 512 + d], hn = ghf[b*1536 + 1024 + d];
        float ho = hst[b*512 + d];
        float r = 1.f / (1.f + expf(-(ir + hr)));
        float z = 1.f / (1.f + expf(-(iz + hz)));
        float n = tanhf(inn + r * hn);
        float hv = (1.f - z) * n + z * ho;
        hst[b*512 + d] = hv;
        unsigned short bf = f2bf(hv);
        h_bf[b*512 + d] = bf;
        outs_bf[(size_t)((t - 1) * 64 + b) * 512 + d] = bf;
      }
    }
    gridbar(bcnt, bgen, my_gen, 128);

    // ---- P1: [q|gh] = h @ wcat^T, 40 tiles of 64 cols ----
    if (blk < 40) {
      const int n0 = blk * 64;
      f32x4 acc[4] = {};
      for (int k = 0; k < 512; k += 32) {
        gload16(h_bf + (size_t)srow * 512 + k + soff, As + tid * 8);
        gload16(wcat + (size_t)(n0 + srow) * 512 + k + soff, Bs + tid * 8);
        __syncthreads();
        u16x8 af = *(const u16x8*)&As[(w * 16 + fr) * 32 + fq * 8];
        #pragma unroll
        for (int nj = 0; nj < 4; nj++) {
          u16x8 bfv = *(const u16x8*)&Bs[(nj * 16 + fr) * 32 + fq * 8];
          acc[nj] = __builtin_amdgcn_mfma_f32_16x16x32_bf16(as_bf(af), as_bf(bfv), acc[nj], 0, 0, 0);
        }
        __syncthreads();
      }
      #pragma unroll
      for (int nj = 0; nj < 4; nj++) {
        #pragma unroll
        for (int j = 0; j < 4; j++) {
          int row = w * 16 + fq * 4 + j;
          int col = n0 + nj * 16 + fr;
          float v = acc[nj][j];
          if (col < 512)       qf[(size_t)row * 1024 + col] = tanhf(v + bq1[col]);
          else if (col < 1024) qf[(size_t)row * 1024 + col] = tanhf(v + bq2[col - 512]);
          else                 ghf[(size_t)row * 1536 + (col - 1024)] = v + b_hh[col - 1024];
        }
      }
    }
    gridbar(bcnt, bgen, my_gen, 128);

    // ---- P2: attention per (b, side), 128 units ----
    {
      const int side = blk >> 6, b = blk & 63;
      for (int i = tid; i < 512; i += 256)
        qv[i] = qf[(size_t)b * 1024 + side * 512 + i];
      __syncthreads();

      const unsigned short* keys = side ? keys2 : keys1;
      {
        int tt = tid >> 1, half = tid & 1;
        const u16x8* krow = (const u16x8*)(keys + ((size_t)(b * 128 + tt)) * 512 + half * 256);
        float acc = 0.f;
        #pragma unroll 4
        for (int k8 = 0; k8 < 32; k8++) {
          u16x8 kv = krow[k8];
          #pragma unroll
          for (int jj = 0; jj < 8; jj++) acc += qv[half * 256 + k8 * 8 + jj] * bf2f(kv[jj]);
        }
        sred[tt][half] = acc;
      }
      __syncthreads();

      if (tid < 64) {
        float s0 = sred[tid][0] + sred[tid][1];
        float s1 = sred[tid + 64][0] + sred[tid + 64][1];
        float m = fmaxf(s0, s1);
        #pragma unroll
        for (int off = 32; off; off >>= 1) m = fmaxf(m, __shfl_xor(m, off));
        float e0 = __expf(s0 - m), e1 = __expf(s1 - m);
        float ss = e0 + e1;
        #pragma unroll
        for (int off = 32; off; off >>= 1) ss += __shfl_xor(ss, off);
        float inv = 1.f / ss;
        pr[tid] = e0 * inv;
        pr[tid + 64] = e1 * inv;
      }
      __syncthreads();

      const unsigned short* vals = side ? vals2 : vals1;
      {
        int a0 = tid * 2;
        float acc0 = 0.f, acc1 = 0.f;
        for (int tt = 0; tt < 128; tt++) {
          float p = pr[tt];
          unsigned v = *(const unsigned*)(vals + ((size_t)(b * 128 + tt)) * 512 + a0);
          acc0 += p * bf2f((unsigned short)(v & 0xffffu));
          acc1 += p * bf2f((unsigned short)(v >> 16));
        }
        att_bf[(size_t)b * 1024 + side * 512 + a0]     = f2bf(acc0);
        att_bf[(size_t)b * 1024 + side * 512 + a0 + 1] = f2bf(acc1);
      }
    }
    gridbar(bcnt, bgen, my_gen, 128);

    // ---- P3: gi = att @ wf_att^T + gi_x + bfull, 24 tiles ----
    if (blk < 24) {
      const int n0 = blk * 64;
      f32x4 acc[4] = {};
      for (int k = 0; k < 1024; k += 32) {
        gload16(att_bf + (size_t)srow * 1024 + k + soff, As + tid * 8);
        gload16(wf_att + (size_t)(n0 + srow) * 1024 + k + soff, Bs + tid * 8);
        __syncthreads();
        u16x8 af = *(const u16x8*)&As[(w * 16 + fr) * 32 + fq * 8];
        #pragma unroll
        for (int nj = 0; nj < 4; nj++) {
          u16x8 bfv = *(const u16x8*)&Bs[(nj * 16 + fr) * 32 + fq * 8];
          acc[nj] = __builtin_amdgcn_mfma_f32_16x16x32_bf16(as_bf(af), as_bf(bfv), acc[nj], 0, 0, 0);
        }
        __syncthreads();
      }
      #pragma unroll
      for (int nj = 0; nj < 4; nj++) {
        #pragma unroll
        for (int j = 0; j < 4; j++) {
          int row = w * 16 + fq * 4 + j;
          int col = n0 + nj * 16 + fr;
          gif[(size_t)row * 1536 + col] =
              acc[nj][j] + gi_x[(size_t)(t * 64 + row) * 1536 + col] + bfull[col];
        }
      }
    }
    gridbar(bcnt, bgen, my_gen, 128);
  }

  // ---- final GRU -> outs[31] ----
  if (blk < 64) {
    const int b = blk;
    for (int d = tid; d < 512; d += 256) {
      float ir = gif[b*1536 + d], iz = gif[b*1536 + 512 + d], inn = gif[b*1536 + 1024 + d];
      float hr = ghf[b*1536 + d], hz = ghf[b*1536 + 512 + d], hn = ghf[b*1536 + 1024 + d];
      float ho = hst[b*512 + d];
      float r = 1.f / (1.f + expf(-(ir + hr)));
      float z = 1.f / (1.f + expf(-(iz + hz)));
      float n = tanhf(inn + r * hn);
      float hv = (1.f - z) * n + z * ho;
      outs_bf[(size_t)(31 * 64 + b) * 512 + d] = f2bf(hv);
    }
  }
}

// ---------------------------------------------------------------------------
extern "C" void kernel_launch(void* const* d_in, const int* in_sizes, int n_in,
                              void* d_out, int out_size, void* d_ws, size_t ws_size,
                              hipStream_t stream) {
  const float* expl  = (const float*)d_in[0];
  const float* enc1  = (const float*)d_in[1];
  const float* enc2  = (const float*)d_in[2];
  const float* s1e   = (const float*)d_in[3];
  const float* s2e   = (const float*)d_in[4];
  const float* W_ctx = (const float*)d_in[5];
  const float* b_ctx = (const float*)d_in[6];
  const float* Wq1   = (const float*)d_in[7];
  const float* bq1   = (const float*)d_in[8];
  const float* Wk1   = (const float*)d_in[9];
  const float* bk1   = (const float*)d_in[10];
  const float* Wv1   = (const float*)d_in[11];
  const float* bv1   = (const float*)d_in[12];
  const float* Wq2   = (const float*)d_in[13];
  const float* bq2   = (const float*)d_in[14];
  const float* Wk2   = (const float*)d_in[15];
  const float* bk2   = (const float*)d_in[16];
  const float* Wv2   = (const float*)d_in[17];
  const float* bv2   = (const float*)d_in[18];
  const float* W_in  = (const float*)d_in[19];
  const float* b_in  = (const float*)d_in[20];
  const float* W_ih  = (const float*)d_in[21];
  const float* b_ih  = (const float*)d_in[22];
  const float* W_hh  = (const float*)d_in[23];
  const float* b_hh  = (const float*)d_in[24];
  const float* W_voc = (const float*)d_in[25];
  const float* b_voc = (const float*)d_in[26];
  float* out = (float*)d_out;

  char* ws = (char*)d_ws;
  unsigned short* keys1  = (unsigned short*)(ws + 0);          // [b*128+tt][512]
  unsigned short* vals1  = (unsigned short*)(ws + 8388608);
  unsigned short* keys2  = (unsigned short*)(ws + 16777216);
  unsigned short* vals2  = (unsigned short*)(ws + 25165824);
  unsigned short* encbf  = (unsigned short*)(ws + 33554432);   // 67.1 MB
  unsigned short* wkv    = (unsigned short*)(ws + 100663296);  // 8.4 MB
  unsigned short* wvoc   = (unsigned short*)(ws + 109051904);  // 32.8 MB
  unsigned short* wcat   = (unsigned short*)(ws + 141819904);  // [2560][512]
  unsigned short* wf_att = (unsigned short*)(ws + 144441344);  // [1536][1024]
  float*          wfx    = (float*)(ws + 147587072);
  float*          bfull  = (float*)(ws + 149430272);
  float*          gi_x   = (float*)(ws + 149436416);           // 12.6 MB
  unsigned short* ctx_bf = (unsigned short*)(ws + 162019328);
  float*          part   = (float*)(ws + 164116480);
  float*          hst    = (float*)(ws + 165165056);
  unsigned short* h_bf   = (unsigned short*)(ws + 165296128);
  float*          qf     = (float*)(ws + 165361664);
  float*          ghf    = (float*)(ws + 165623808);
  float*          gif    = (float*)(ws + 166017024);
  unsigned short* att_bf = (unsigned short*)(ws + 166410240);
  unsigned short* outs_bf= (unsigned short*)(ws + 166541312);
  unsigned*       bar    = (unsigned*)(ws + 168638464);        // 2 x u32
  // end ~168.7 MB

  auto cvt = [&](const float* s, unsigned short* d, int n) {
    k_cvt<<<(n + 1023) / 1024, 256, 0, stream>>>(s, d, n);
  };

  // ---- keys/vals side 1 ----
  cvt(enc1, encbf, 8192 * 4096);
  cvt(Wk1, wkv, 512 * 4096);
  cvt(Wv1, wkv + 512 * 4096, 512 * 4096);
  k_gemm_lds<0><<<dim3(64, 8), 256, 0, stream>>>(
      encbf, 4096, wkv, 4096, 4096, keys1, vals1, nullptr, 0, bk1, bv1);
  // ---- keys/vals side 2 ----
  cvt(enc2, encbf, 8192 * 4096);
  cvt(Wk2, wkv, 512 * 4096);
  cvt(Wv2, wkv + 512 * 4096, 512 * 4096);
  k_gemm_lds<0><<<dim3(64, 8), 256, 0, stream>>>(
      encbf, 4096, wkv, 4096, 4096, keys2, vals2, nullptr, 0, bk2, bv2);

  // ---- weight converts ----
  cvt(W_voc, wvoc, 32000 * 512);
  cvt(Wq1, wcat, 512 * 512);
  cvt(Wq2, wcat + 512 * 512, 512 * 512);
  cvt(W_hh, wcat + 1024 * 512, 1536 * 512);

  // ---- Wf fold + gi_x ----
  k_wf<<<dim3(192, 6), 256, 0, stream>>>(W_ih, W_in, wf_att, wfx);
  k_bfull<<<6, 256, 0, stream>>>(W_ih, b_in, b_ih, bfull);
  k_gix<<<dim3(128, 6), 256, 0, stream>>>(expl, wfx, gi_x);

  // ---- h0 ----
  k_build_ctx<<<4096, 256, 0, stream>>>(s1e, s2e, ctx_bf);
  k_gemm128<1, 0, 2><<<dim3(4, 1, 8), 256, 0, stream>>>(
      ctx_bf, 16384, W_ctx, 16384, 64, 512, 2048,
      nullptr, nullptr, part, nullptr, nullptr);
  k_reduce_h0<<<128, 256, 0, stream>>>(part, b_ctx, hst, h_bf);

  // ---- recurrence: ONE persistent kernel, software grid barriers ----
  k_init<<<1, 64, 0, stream>>>(bar);
  k_recur<<<128, 256, 0, stream>>>(hst, h_bf, qf, ghf, gif, att_bf, outs_bf,
                                   wcat, wf_att, keys1, keys2, vals1, vals2,
                                   bq1, bq2, b_hh, gi_x, bfull, bar);

  // ---- logits = outs @ W_voc^T + b_voc ----
  k_gemm_lds<1><<<dim3(16, 250), 256, 0, stream>>>(
      outs_bf, 512, wvoc, 512, 512, nullptr, nullptr, out, 32000, b_voc, nullptr);
}

// Round 9
// 3452.172 us; speedup vs baseline: 1.9812x; 1.9812x over previous
//
#include <hip/hip_runtime.h>

// ---------------------------------------------------------------------------
// AttentionDecoder. Laws so far:
//   R5: recurrence weights read ONCE per step (col-sliced over batch rows).
//   R6: lean kernels beat fewer-but-fat kernels; graph launches ~7us each.
//   R8: software grid barriers (acquire-poll) trash L2 -> never again.
// R9: 3 launches/step:
//   K1 k_qgh   (40 blk): [q|gh] = h @ [Wq1;Wq2;Whh]^T, barrier-free direct MFMA
//   K2 k_att   (128 blk): scores/softmax/att per (b,side)   [unchanged R6]
//   K3 k_gicomb (8 blk x 768): gi 3-gate tiles (MFMA) + GRU fused ->
//                hst/h_bf/outs[t]  (kills k_gru launch + gif roundtrip)
// ---------------------------------------------------------------------------

typedef float    f32x4 __attribute__((ext_vector_type(4)));
typedef __bf16   bf16x8 __attribute__((ext_vector_type(8)));
typedef unsigned short u16x8 __attribute__((ext_vector_type(8)));

#define DEV __device__ __forceinline__

DEV unsigned short f2bf(float f) {
  unsigned u = __builtin_bit_cast(unsigned, f);
  u += 0x7fffu + ((u >> 16) & 1u);
  return (unsigned short)(u >> 16);
}
DEV float bf2f(unsigned short h) {
  return __builtin_bit_cast(float, (unsigned)h << 16);
}
DEV bf16x8 as_bf(u16x8 v) { return __builtin_bit_cast(bf16x8, v); }
DEV u16x8 zero8() {
  u16x8 r = {0, 0, 0, 0, 0, 0, 0, 0};
  return r;
}
DEV u16x8 pack8(float4 a, float4 b) {
  u16x8 r;
  r[0]=f2bf(a.x); r[1]=f2bf(a.y); r[2]=f2bf(a.z); r[3]=f2bf(a.w);
  r[4]=f2bf(b.x); r[5]=f2bf(b.y); r[6]=f2bf(b.z); r[7]=f2bf(b.w);
  return r;
}
DEV void gload16(const void* g, void* l) {
  __builtin_amdgcn_global_load_lds(
      (const __attribute__((address_space(1))) void*)g,
      (__attribute__((address_space(3))) void*)l, 16, 0, 0);
}

// ------------------------------- converts ----------------------------------
__global__ __launch_bounds__(256) void k_cvt(const float* __restrict__ s,
                                             unsigned short* __restrict__ d, int n) {
  int i = (blockIdx.x * 256 + threadIdx.x) * 4;
  if (i + 4 <= n) {
    float4 v = *(const float4*)(s + i);
    d[i] = f2bf(v.x); d[i+1] = f2bf(v.y); d[i+2] = f2bf(v.z); d[i+3] = f2bf(v.w);
  } else {
    for (; i < n; i++) d[i] = f2bf(s[i]);
  }
}

// ctx_feat = [s1, s2, |s1-s2|, s1*s2]  -> bf16 [64, 16384]
__global__ __launch_bounds__(256) void k_build_ctx(const float* __restrict__ s1,
                                                   const float* __restrict__ s2,
                                                   unsigned short* __restrict__ ctx) {
  int j = blockIdx.x * 256 + threadIdx.x;
  int b = j >> 14, jj = j & 16383;
  int f = jj >> 12, k = jj & 4095;
  float a = s1[b * 4096 + k], c = s2[b * 4096 + k];
  float v = (f == 0) ? a : (f == 1) ? c : (f == 2) ? fabsf(a - c) : a * c;
  ctx[j] = f2bf(v);
}

// --------------- bf16 128x128 GEMM with global_load_lds staging -------------
// EPI 0: tanh(+bias), split col 512, PERMUTED rows (tt*64+b -> b*128+tt)
// EPI 1: +bias -> f32, ld ofld
template<int EPI>
__global__ __launch_bounds__(256) void k_gemm_lds(
    const unsigned short* __restrict__ A, int lda,
    const unsigned short* __restrict__ B, int ldb, int K,
    unsigned short* __restrict__ obf0, unsigned short* __restrict__ obf1,
    float* __restrict__ of, int ofld,
    const float* __restrict__ bias0, const float* __restrict__ bias1)
{
  __shared__ __align__(16) unsigned short As[128 * 32];
  __shared__ __align__(16) unsigned short Bs[128 * 32];
  const int tid = threadIdx.x;
  const int r0 = blockIdx.x * 128, c0 = blockIdx.y * 128;
  const int lane = tid & 63, w = tid >> 6;
  const int wr = w >> 1, wc = w & 1;
  const int fr = lane & 15, fq = lane >> 4;
  f32x4 acc[4][4] = {};

  const int srow = tid >> 2, scol = (tid & 3) * 8;
  const unsigned short* gA0 = A + (size_t)(r0 + srow) * lda + scol;
  const unsigned short* gA1 = A + (size_t)(r0 + 64 + srow) * lda + scol;
  const unsigned short* gB0 = B + (size_t)(c0 + srow) * ldb + scol;
  const unsigned short* gB1 = B + (size_t)(c0 + 64 + srow) * ldb + scol;
  unsigned short* lA0 = As + tid * 8;
  unsigned short* lA1 = As + 2048 + tid * 8;
  unsigned short* lB0 = Bs + tid * 8;
  unsigned short* lB1 = Bs + 2048 + tid * 8;

  for (int k = 0; k < K; k += 32) {
    gload16(gA0 + k, lA0);
    gload16(gA1 + k, lA1);
    gload16(gB0 + k, lB0);
    gload16(gB1 + k, lB1);
    __syncthreads();

    u16x8 af[4], bfv[4];
    #pragma unroll
    for (int mi = 0; mi < 4; mi++)
      af[mi] = *(const u16x8*)&As[(wr * 64 + mi * 16 + fr) * 32 + fq * 8];
    #pragma unroll
    for (int nj = 0; nj < 4; nj++)
      bfv[nj] = *(const u16x8*)&Bs[(wc * 64 + nj * 16 + fr) * 32 + fq * 8];
    #pragma unroll
    for (int mi = 0; mi < 4; mi++)
      #pragma unroll
      for (int nj = 0; nj < 4; nj++)
        acc[mi][nj] = __builtin_amdgcn_mfma_f32_16x16x32_bf16(
            as_bf(af[mi]), as_bf(bfv[nj]), acc[mi][nj], 0, 0, 0);
    __syncthreads();
  }

  #pragma unroll
  for (int mi = 0; mi < 4; mi++)
  #pragma unroll
  for (int nj = 0; nj < 4; nj++) {
    f32x4 a = acc[mi][nj];
    #pragma unroll
    for (int j = 0; j < 4; j++) {
      int grow = r0 + wr * 64 + mi * 16 + fq * 4 + j;
      int gcol = c0 + wc * 64 + nj * 16 + fr;
      float v = a[j];
      if constexpr (EPI == 0) {
        float bias = gcol < 512 ? bias0[gcol] : bias1[gcol - 512];
        unsigned short r = f2bf(tanhf(v + bias));
        int prow = ((grow & 63) << 7) | (grow >> 6);
        (gcol < 512 ? obf0 : obf1)[(size_t)prow * 512 + (gcol & 511)] = r;
      } else {
        of[(size_t)grow * ofld + gcol] = v + bias0[gcol];
      }
    }
  }
}

// ------------------------- generic 128x128 MFMA GEMM ------------------------
// (h0 only: A bf16, B f32, raw f32 partials via z split-K)
template<int A_BF16, int B_BF16, int EPI>
__global__ __launch_bounds__(256) void k_gemm128(
    const void* __restrict__ Ap, int lda, const void* __restrict__ Bp, int ldb,
    int M, int N, int kper,
    unsigned short* __restrict__ obf0, unsigned short* __restrict__ obf1,
    float* __restrict__ of, const float* __restrict__ bias0,
    const float* __restrict__ bias1)
{
  __shared__ __align__(16) unsigned short As[128 * 32];
  __shared__ __align__(16) unsigned short Bs[128 * 32];
  const int tid = threadIdx.x;
  const int c0 = blockIdx.x * 128, r0 = blockIdx.y * 128;
  const int k0 = blockIdx.z * kper;
  if (EPI == 2) of += (size_t)blockIdx.z * M * N;

  const int lane = tid & 63, w = tid >> 6;
  const int wr = w >> 1, wc = w & 1;
  const int fr = lane & 15, fq = lane >> 4;

  f32x4 acc[4][4] = {};

  const int srow = tid >> 1, shalf = (tid & 1) * 16;

  for (int k = k0; k < k0 + kper; k += 32) {
    u16x8 a0, a1, b0, b1;
    {
      int gr = r0 + srow;
      if (gr < M) {
        if (A_BF16) {
          const unsigned short* a = (const unsigned short*)Ap + (size_t)gr * lda + k + shalf;
          a0 = *(const u16x8*)a; a1 = *(const u16x8*)(a + 8);
        } else {
          const float* a = (const float*)Ap + (size_t)gr * lda + k + shalf;
          float4 f0 = ((const float4*)a)[0], f1 = ((const float4*)a)[1];
          float4 f2 = ((const float4*)a)[2], f3 = ((const float4*)a)[3];
          a0 = pack8(f0, f1); a1 = pack8(f2, f3);
        }
      } else { a0 = zero8(); a1 = zero8(); }
    }
    {
      int gr = c0 + srow;
      if (B_BF16) {
        const unsigned short* p = (const unsigned short*)Bp + (size_t)gr * ldb + k + shalf;
        b0 = *(const u16x8*)p; b1 = *(const u16x8*)(p + 8);
      } else {
        const float* p = (const float*)Bp + (size_t)gr * ldb + k + shalf;
        float4 f0 = ((const float4*)p)[0], f1 = ((const float4*)p)[1];
        float4 f2 = ((const float4*)p)[2], f3 = ((const float4*)p)[3];
        b0 = pack8(f0, f1); b1 = pack8(f2, f3);
      }
    }
    *(u16x8*)&As[srow * 32 + shalf]     = a0;
    *(u16x8*)&As[srow * 32 + shalf + 8] = a1;
    *(u16x8*)&Bs[srow * 32 + shalf]     = b0;
    *(u16x8*)&Bs[srow * 32 + shalf + 8] = b1;
    __syncthreads();

    u16x8 af[4], bfv[4];
    #pragma unroll
    for (int mi = 0; mi < 4; mi++)
      af[mi] = *(const u16x8*)&As[(wr * 64 + mi * 16 + fr) * 32 + fq * 8];
    #pragma unroll
    for (int nj = 0; nj < 4; nj++)
      bfv[nj] = *(const u16x8*)&Bs[(wc * 64 + nj * 16 + fr) * 32 + fq * 8];
    #pragma unroll
    for (int mi = 0; mi < 4; mi++)
      #pragma unroll
      for (int nj = 0; nj < 4; nj++)
        acc[mi][nj] = __builtin_amdgcn_mfma_f32_16x16x32_bf16(
            as_bf(af[mi]), as_bf(bfv[nj]), acc[mi][nj], 0, 0, 0);
    __syncthreads();
  }

  #pragma unroll
  for (int mi = 0; mi < 4; mi++)
  #pragma unroll
  for (int nj = 0; nj < 4; nj++) {
    f32x4 a = acc[mi][nj];
    #pragma unroll
    for (int j = 0; j < 4; j++) {
      int grow = r0 + wr * 64 + mi * 16 + fq * 4 + j;
      int gcol = c0 + wc * 64 + nj * 16 + fr;
      if (grow < M) {
        float v = a[j];
        if constexpr (EPI == 1) {
          of[(size_t)grow * N + gcol] = v + bias0[gcol];
        } else if constexpr (EPI == 2) {
          of[(size_t)grow * N + gcol] = v;
        }
      }
    }
  }
}

__global__ __launch_bounds__(256) void k_reduce_h0(const float* __restrict__ part,
                                                   const float* __restrict__ b_ctx,
                                                   float* __restrict__ h,
                                                   unsigned short* __restrict__ h_bf) {
  int j = blockIdx.x * 256 + threadIdx.x;   // < 64*512
  float s = b_ctx[j & 511];
  for (int z = 0; z < 8; z++) s += part[z * 32768 + j];
  h[j] = s;
  h_bf[j] = f2bf(s);
}

// ------------------- W_f = W_ih @ W_in  fold (one-time) ---------------------
__global__ __launch_bounds__(256) void k_wf(const float* __restrict__ W_ih,
                                            const float* __restrict__ W_in,
                                            unsigned short* __restrict__ wf_att,
                                            float* __restrict__ wfx) {
  __shared__ float wl[8][512];
  int ic = blockIdx.x, jc = blockIdx.y, tid = threadIdx.x;
  for (int x = tid; x < 8 * 512; x += 256)
    wl[x >> 9][x & 511] = W_ih[(ic * 8 + (x >> 9)) * 512 + (x & 511)];
  __syncthreads();
  int j = jc * 256 + tid;
  if (j >= 1324) return;
  float acc[8] = {};
  for (int d = 0; d < 512; d++) {
    float win = W_in[d * 1324 + j];
    #pragma unroll
    for (int r = 0; r < 8; r++) acc[r] += wl[r][d] * win;
  }
  for (int r = 0; r < 8; r++) {
    int i = ic * 8 + r;
    if (j < 300) wfx[i * 300 + j] = acc[r];
    else         wf_att[i * 1024 + (j - 300)] = f2bf(acc[r]);
  }
}

__global__ __launch_bounds__(256) void k_bfull(const float* __restrict__ W_ih,
                                               const float* __restrict__ b_in,
                                               const float* __restrict__ b_ih,
                                               float* __restrict__ bfull) {
  int i = blockIdx.x * 256 + threadIdx.x;
  if (i >= 1536) return;
  float acc = b_ih[i];
  for (int d = 0; d < 512; d++) acc += W_ih[i * 512 + d] * b_in[d];
  bfull[i] = acc;
}

// gi_x[t*64+b, :] = expl[t,b,:300] @ Wfx^T
__global__ __launch_bounds__(256) void k_gix(const float* __restrict__ expl,
                                             const float* __restrict__ wfx,
                                             float* __restrict__ gi_x) {
  __shared__ float el[16][300];
  int rc = blockIdx.x, ic = blockIdx.y, tid = threadIdx.x;
  for (int x = tid; x < 16 * 300; x += 256)
    el[x / 300][x % 300] = expl[(size_t)(rc * 16 + x / 300) * 300 + (x % 300)];
  __syncthreads();
  int c = ic * 256 + tid;
  float acc[16] = {};
  for (int k = 0; k < 300; k++) {
    float wv = wfx[c * 300 + k];
    #pragma unroll
    for (int r = 0; r < 16; r++) acc[r] += el[r][k] * wv;
  }
  for (int r = 0; r < 16; r++) gi_x[(size_t)(rc * 16 + r) * 1536 + c] = acc[r];
}

// ------------------- K1: barrier-free [q|gh] matvec -------------------------
// 40 blocks x 256 thr (4 waves). C[64,2560] = h_bf[64,512] @ wcat[2560,512]^T.
// Wave w owns rows [w*16, w*16+16). No LDS, no syncthreads: A/B fragments
// loaded directly from global (L2-hot), compiler pipelines freely.
__global__ __launch_bounds__(256) void k_qgh(
    const unsigned short* __restrict__ h_bf,
    const unsigned short* __restrict__ wcat,
    const float* __restrict__ bq1, const float* __restrict__ bq2,
    const float* __restrict__ b_hh,
    float* __restrict__ qf, float* __restrict__ ghf)
{
  const int tid = threadIdx.x;
  const int n0 = blockIdx.x * 64;
  const int lane = tid & 63, w = tid >> 6;
  const int fr = lane & 15, fq = lane >> 4;
  f32x4 acc[4] = {};
  const unsigned short* arow = h_bf + (size_t)(w * 16 + fr) * 512 + fq * 8;
  const unsigned short* brow = wcat + (size_t)(n0 + fr) * 512 + fq * 8;

  #pragma unroll 4
  for (int kk = 0; kk < 16; kk++) {
    u16x8 av = *(const u16x8*)(arow + kk * 32);
    #pragma unroll
    for (int nj = 0; nj < 4; nj++) {
      u16x8 bv = *(const u16x8*)(brow + (size_t)nj * 16 * 512 + kk * 32);
      acc[nj] = __builtin_amdgcn_mfma_f32_16x16x32_bf16(as_bf(av), as_bf(bv), acc[nj], 0, 0, 0);
    }
  }
  #pragma unroll
  for (int nj = 0; nj < 4; nj++) {
    #pragma unroll
    for (int j = 0; j < 4; j++) {
      int row = w * 16 + fq * 4 + j;
      int col = n0 + nj * 16 + fr;
      float v = acc[nj][j];
      if (col < 512)       qf[(size_t)row * 1024 + col] = tanhf(v + bq1[col]);
      else if (col < 1024) qf[(size_t)row * 1024 + col] = tanhf(v + bq2[col - 512]);
      else                 ghf[(size_t)row * 1536 + (col - 1024)] = v + b_hh[col - 1024];
    }
  }
}

// ------------------- K2: attention (unchanged from R6) ----------------------
__global__ __launch_bounds__(256) void k_att(
    const float* __restrict__ qf,
    const unsigned short* __restrict__ keys1, const unsigned short* __restrict__ keys2,
    const unsigned short* __restrict__ vals1, const unsigned short* __restrict__ vals2,
    unsigned short* __restrict__ att_bf)
{
  const int id = blockIdx.x, side = id >> 6, b = id & 63;
  const int tid = threadIdx.x;
  __shared__ float qv[512];
  __shared__ float sred[128][2];
  __shared__ float pr[128];

  for (int i = tid; i < 512; i += 256)
    qv[i] = qf[(size_t)b * 1024 + side * 512 + i];
  __syncthreads();

  const unsigned short* keys = side ? keys2 : keys1;
  {
    int tt = tid >> 1, half = tid & 1;
    const u16x8* krow = (const u16x8*)(keys + ((size_t)(b * 128 + tt)) * 512 + half * 256);
    float acc = 0.f;
    #pragma unroll 4
    for (int k8 = 0; k8 < 32; k8++) {
      u16x8 kv = krow[k8];
      #pragma unroll
      for (int jj = 0; jj < 8; jj++) acc += qv[half * 256 + k8 * 8 + jj] * bf2f(kv[jj]);
    }
    sred[tt][half] = acc;
  }
  __syncthreads();

  if (tid < 64) {
    float s0 = sred[tid][0] + sred[tid][1];
    float s1 = sred[tid + 64][0] + sred[tid + 64][1];
    float m = fmaxf(s0, s1);
    #pragma unroll
    for (int off = 32; off; off >>= 1) m = fmaxf(m, __shfl_xor(m, off));
    float e0 = __expf(s0 - m), e1 = __expf(s1 - m);
    float ss = e0 + e1;
    #pragma unroll
    for (int off = 32; off; off >>= 1) ss += __shfl_xor(ss, off);
    float inv = 1.f / ss;
    pr[tid] = e0 * inv;
    pr[tid + 64] = e1 * inv;
  }
  __syncthreads();

  const unsigned short* vals = side ? vals2 : vals1;
  {
    int a0 = tid * 2;
    float acc0 = 0.f, acc1 = 0.f;
    for (int tt = 0; tt < 128; tt++) {
      float p = pr[tt];
      unsigned v = *(const unsigned*)(vals + ((size_t)(b * 128 + tt)) * 512 + a0);
      acc0 += p * bf2f((unsigned short)(v & 0xffffu));
      acc1 += p * bf2f((unsigned short)(v >> 16));
    }
    att_bf[(size_t)b * 1024 + side * 512 + a0]     = f2bf(acc0);
    att_bf[(size_t)b * 1024 + side * 512 + a0 + 1] = f2bf(acc1);
  }
}

// ------------- K3: gi 3-gate tiles (MFMA) + GRU, fused ----------------------
// 8 blocks x 768 thr (12 waves = 3 gate sub-units x 4 waves). Block j owns
// gi cols {j*64, 512+j*64, 1024+j*64} (K=1024, barrier-free direct MFMA),
// so the GRU gate triplet for h cols [j*64,(j+1)*64) is block-local. Then GRU
// -> hst (in-place slice), h_bf, outs[t]. No gif global buffer, no k_gru.
__global__ __launch_bounds__(768) void k_gicomb(
    int t, const unsigned short* __restrict__ att_bf,
    const unsigned short* __restrict__ wf_att,
    const float* __restrict__ gi_x, const float* __restrict__ bfull,
    const float* __restrict__ ghf,
    float* __restrict__ hst, unsigned short* __restrict__ h_bf,
    unsigned short* __restrict__ outs_bf)
{
  __shared__ float gis[3][64][64];
  const int tid = threadIdx.x, j = blockIdx.x;
  const int lane = tid & 63, w = tid >> 6;
  const int g = w >> 2, ww = w & 3;
  const int fr = lane & 15, fq = lane >> 4;
  f32x4 acc[4] = {};
  const int c0 = g * 512 + j * 64;
  const unsigned short* arow = att_bf + (size_t)(ww * 16 + fr) * 1024 + fq * 8;
  const unsigned short* brow = wf_att + (size_t)(c0 + fr) * 1024 + fq * 8;

  #pragma unroll 4
  for (int kk = 0; kk < 32; kk++) {
    u16x8 av = *(const u16x8*)(arow + kk * 32);
    #pragma unroll
    for (int nj = 0; nj < 4; nj++) {
      u16x8 bv = *(const u16x8*)(brow + (size_t)nj * 16 * 1024 + kk * 32);
      acc[nj] = __builtin_amdgcn_mfma_f32_16x16x32_bf16(as_bf(av), as_bf(bv), acc[nj], 0, 0, 0);
    }
  }
  #pragma unroll
  for (int nj = 0; nj < 4; nj++) {
    #pragma unroll
    for (int jj = 0; jj < 4; jj++) {
      int row = ww * 16 + fq * 4 + jj;          // batch row b
      int d64 = nj * 16 + fr;
      int gcol = c0 + d64;
      gis[g][row][d64] = acc[nj][jj]
          + gi_x[(size_t)(t * 64 + row) * 1536 + gcol] + bfull[gcol];
    }
  }
  __syncthreads();

  for (int e = tid; e < 4096; e += 768) {
    int b = e >> 6, d64 = e & 63, d = j * 64 + d64;
    float ir = gis[0][b][d64], iz = gis[1][b][d64], inn = gis[2][b][d64];
    float hr = ghf[b*1536 + d], hz = ghf[b*1536 + 512 + d], hn = ghf[b*1536 + 1024 + d];
    float ho = hst[b*512 + d];
    float r = 1.f / (1.f + expf(-(ir + hr)));
    float z = 1.f / (1.f + expf(-(iz + hz)));
    float n = tanhf(inn + r * hn);
    float hv = (1.f - z) * n + z * ho;
    hst[b*512 + d] = hv;
    unsigned short bf = f2bf(hv);
    h_bf[b*512 + d] = bf;
    outs_bf[(size_t)(t * 64 + b) * 512 + d] = bf;
  }
}

// ---------------------------------------------------------------------------
extern "C" void kernel_launch(void* const* d_in, const int* in_sizes, int n_in,
                              void* d_out, int out_size, void* d_ws, size_t ws_size,
                              hipStream_t stream) {
  const float* expl  = (const float*)d_in[0];
  const float* enc1  = (const float*)d_in[1];
  const float* enc2  = (const float*)d_in[2];
  const float* s1e   = (const float*)d_in[3];
  const float* s2e   = (const float*)d_in[4];
  const float* W_ctx = (const float*)d_in[5];
  const float* b_ctx = (const float*)d_in[6];
  const float* Wq1   = (const float*)d_in[7];
  const float* bq1   = (const float*)d_in[8];
  const float* Wk1   = (const float*)d_in[9];
  const float* bk1   = (const float*)d_in[10];
  const float* Wv1   = (const float*)d_in[11];
  const float* bv1   = (const float*)d_in[12];
  const float* Wq2   = (const float*)d_in[13];
  const float* bq2   = (const float*)d_in[14];
  const float* Wk2   = (const float*)d_in[15];
  const float* bk2   = (const float*)d_in[16];
  const float* Wv2   = (const float*)d_in[17];
  const float* bv2   = (const float*)d_in[18];
  const float* W_in  = (const float*)d_in[19];
  const float* b_in  = (const float*)d_in[20];
  const float* W_ih  = (const float*)d_in[21];
  const float* b_ih  = (const float*)d_in[22];
  const float* W_hh  = (const float*)d_in[23];
  const float* b_hh  = (const float*)d_in[24];
  const float* W_voc = (const float*)d_in[25];
  const float* b_voc = (const float*)d_in[26];
  float* out = (float*)d_out;

  char* ws = (char*)d_ws;
  unsigned short* keys1  = (unsigned short*)(ws + 0);          // [b*128+tt][512]
  unsigned short* vals1  = (unsigned short*)(ws + 8388608);
  unsigned short* keys2  = (unsigned short*)(ws + 16777216);
  unsigned short* vals2  = (unsigned short*)(ws + 25165824);
  unsigned short* encbf  = (unsigned short*)(ws + 33554432);   // 67.1 MB
  unsigned short* wkv    = (unsigned short*)(ws + 100663296);  // 8.4 MB
  unsigned short* wvoc   = (unsigned short*)(ws + 109051904);  // 32.8 MB
  unsigned short* wcat   = (unsigned short*)(ws + 141819904);  // [2560][512]
  unsigned short* wf_att = (unsigned short*)(ws + 144441344);  // [1536][1024]
  float*          wfx    = (float*)(ws + 147587072);
  float*          bfull  = (float*)(ws + 149430272);
  float*          gi_x   = (float*)(ws + 149436416);           // 12.6 MB
  unsigned short* ctx_bf = (unsigned short*)(ws + 162019328);
  float*          part   = (float*)(ws + 164116480);
  float*          hst    = (float*)(ws + 165165056);
  unsigned short* h_bf   = (unsigned short*)(ws + 165296128);
  float*          qf     = (float*)(ws + 165361664);
  float*          ghf    = (float*)(ws + 165623808);
  unsigned short* att_bf = (unsigned short*)(ws + 166410240);
  unsigned short* outs_bf= (unsigned short*)(ws + 166541312);
  // end ~168.6 MB

  auto cvt = [&](const float* s, unsigned short* d, int n) {
    k_cvt<<<(n + 1023) / 1024, 256, 0, stream>>>(s, d, n);
  };

  // ---- keys/vals side 1 ----
  cvt(enc1, encbf, 8192 * 4096);
  cvt(Wk1, wkv, 512 * 4096);
  cvt(Wv1, wkv + 512 * 4096, 512 * 4096);
  k_gemm_lds<0><<<dim3(64, 8), 256, 0, stream>>>(
      encbf, 4096, wkv, 4096, 4096, keys1, vals1, nullptr, 0, bk1, bv1);
  // ---- keys/vals side 2 ----
  cvt(enc2, encbf, 8192 * 4096);
  cvt(Wk2, wkv, 512 * 4096);
  cvt(Wv2, wkv + 512 * 4096, 512 * 4096);
  k_gemm_lds<0><<<dim3(64, 8), 256, 0, stream>>>(
      encbf, 4096, wkv, 4096, 4096, keys2, vals2, nullptr, 0, bk2, bv2);

  // ---- weight converts ----
  cvt(W_voc, wvoc, 32000 * 512);
  cvt(Wq1, wcat, 512 * 512);
  cvt(Wq2, wcat + 512 * 512, 512 * 512);
  cvt(W_hh, wcat + 1024 * 512, 1536 * 512);

  // ---- Wf fold + gi_x ----
  k_wf<<<dim3(192, 6), 256, 0, stream>>>(W_ih, W_in, wf_att, wfx);
  k_bfull<<<6, 256, 0, stream>>>(W_ih, b_in, b_ih, bfull);
  k_gix<<<dim3(128, 6), 256, 0, stream>>>(expl, wfx, gi_x);

  // ---- h0 ----
  k_build_ctx<<<4096, 256, 0, stream>>>(s1e, s2e, ctx_bf);
  k_gemm128<1, 0, 2><<<dim3(4, 1, 8), 256, 0, stream>>>(
      ctx_bf, 16384, W_ctx, 16384, 64, 512, 2048,
      nullptr, nullptr, part, nullptr, nullptr);
  k_reduce_h0<<<128, 256, 0, stream>>>(part, b_ctx, hst, h_bf);

  // ---- recurrence: 3 launches per step ----
  for (int t = 0; t < 32; t++) {
    k_qgh<<<40, 256, 0, stream>>>(h_bf, wcat, bq1, bq2, b_hh, qf, ghf);
    k_att<<<128, 256, 0, stream>>>(qf, keys1, keys2, vals1, vals2, att_bf);
    k_gicomb<<<8, 768, 0, stream>>>(t, att_bf, wf_att, gi_x, bfull, ghf,
                                    hst, h_bf, outs_bf);
  }

  // ---- logits = outs @ W_voc^T + b_voc ----
  k_gemm_lds<1><<<dim3(16, 250), 256, 0, stream>>>(
      outs_bf, 512, wvoc, 512, 512, nullptr, nullptr, out, 32000, b_voc, nullptr);
}

// Round 10
// 2998.097 us; speedup vs baseline: 2.2813x; 1.1515x over previous
//
#include <hip/hip_runtime.h>

// ---------------------------------------------------------------------------
// AttentionDecoder. Laws:
//   R5: recurrence weights read ONCE per step (col-sliced over batch rows).
//   R8: software grid barriers trash L2 -> never.
//   R9: LDS-staged MFMA (gload16) beats barrier-free direct-global MFMA.
// R10: 3 launches/step:
//   S1 k_hqg (40 blk): redundant-GRU -> chunked LDS h tile; B fully prestaged
//      (16x gload16 in flight under GRU); 1 barrier; MFMA -> qf, ghf.
//      Blocks 0-7 write h state (double-buffered) + outs[t-1].
//   S2 k_att (128 blk): scores/softmax/att per (b,side)    [R6 verbatim]
//   S3 k_gi  (24 blk): gi = att @ Wf^T + gi_x + bfull      [R6 verbatim]
//   k_final: outs[31].
// ---------------------------------------------------------------------------

typedef float    f32x4 __attribute__((ext_vector_type(4)));
typedef __bf16   bf16x8 __attribute__((ext_vector_type(8)));
typedef unsigned short u16x8 __attribute__((ext_vector_type(8)));

#define DEV __device__ __forceinline__

DEV unsigned short f2bf(float f) {
  unsigned u = __builtin_bit_cast(unsigned, f);
  u += 0x7fffu + ((u >> 16) & 1u);
  return (unsigned short)(u >> 16);
}
DEV float bf2f(unsigned short h) {
  return __builtin_bit_cast(float, (unsigned)h << 16);
}
DEV bf16x8 as_bf(u16x8 v) { return __builtin_bit_cast(bf16x8, v); }
DEV u16x8 zero8() {
  u16x8 r = {0, 0, 0, 0, 0, 0, 0, 0};
  return r;
}
DEV u16x8 pack8(float4 a, float4 b) {
  u16x8 r;
  r[0]=f2bf(a.x); r[1]=f2bf(a.y); r[2]=f2bf(a.z); r[3]=f2bf(a.w);
  r[4]=f2bf(b.x); r[5]=f2bf(b.y); r[6]=f2bf(b.z); r[7]=f2bf(b.w);
  return r;
}
DEV void gload16(const void* g, void* l) {
  __builtin_amdgcn_global_load_lds(
      (const __attribute__((address_space(1))) void*)g,
      (__attribute__((address_space(3))) void*)l, 16, 0, 0);
}
DEV float gru1(float ir, float iz, float inn, float hr, float hz, float hn,
               float ho) {
  float r = 1.f / (1.f + expf(-(ir + hr)));
  float z = 1.f / (1.f + expf(-(iz + hz)));
  float n = tanhf(inn + r * hn);
  return (1.f - z) * n + z * ho;
}

// ------------------------------- converts ----------------------------------
__global__ __launch_bounds__(256) void k_cvt(const float* __restrict__ s,
                                             unsigned short* __restrict__ d, int n) {
  int i = (blockIdx.x * 256 + threadIdx.x) * 4;
  if (i + 4 <= n) {
    float4 v = *(const float4*)(s + i);
    d[i] = f2bf(v.x); d[i+1] = f2bf(v.y); d[i+2] = f2bf(v.z); d[i+3] = f2bf(v.w);
  } else {
    for (; i < n; i++) d[i] = f2bf(s[i]);
  }
}

// ctx_feat = [s1, s2, |s1-s2|, s1*s2]  -> bf16 [64, 16384]
__global__ __launch_bounds__(256) void k_build_ctx(const float* __restrict__ s1,
                                                   const float* __restrict__ s2,
                                                   unsigned short* __restrict__ ctx) {
  int j = blockIdx.x * 256 + threadIdx.x;
  int b = j >> 14, jj = j & 16383;
  int f = jj >> 12, k = jj & 4095;
  float a = s1[b * 4096 + k], c = s2[b * 4096 + k];
  float v = (f == 0) ? a : (f == 1) ? c : (f == 2) ? fabsf(a - c) : a * c;
  ctx[j] = f2bf(v);
}

// --------------- bf16 128x128 GEMM with global_load_lds staging -------------
// EPI 0: tanh(+bias), split col 512, PERMUTED rows (tt*64+b -> b*128+tt)
// EPI 1: +bias -> f32, ld ofld
template<int EPI>
__global__ __launch_bounds__(256) void k_gemm_lds(
    const unsigned short* __restrict__ A, int lda,
    const unsigned short* __restrict__ B, int ldb, int K,
    unsigned short* __restrict__ obf0, unsigned short* __restrict__ obf1,
    float* __restrict__ of, int ofld,
    const float* __restrict__ bias0, const float* __restrict__ bias1)
{
  __shared__ __align__(16) unsigned short As[128 * 32];
  __shared__ __align__(16) unsigned short Bs[128 * 32];
  const int tid = threadIdx.x;
  const int r0 = blockIdx.x * 128, c0 = blockIdx.y * 128;
  const int lane = tid & 63, w = tid >> 6;
  const int wr = w >> 1, wc = w & 1;
  const int fr = lane & 15, fq = lane >> 4;
  f32x4 acc[4][4] = {};

  const int srow = tid >> 2, scol = (tid & 3) * 8;
  const unsigned short* gA0 = A + (size_t)(r0 + srow) * lda + scol;
  const unsigned short* gA1 = A + (size_t)(r0 + 64 + srow) * lda + scol;
  const unsigned short* gB0 = B + (size_t)(c0 + srow) * ldb + scol;
  const unsigned short* gB1 = B + (size_t)(c0 + 64 + srow) * ldb + scol;
  unsigned short* lA0 = As + tid * 8;
  unsigned short* lA1 = As + 2048 + tid * 8;
  unsigned short* lB0 = Bs + tid * 8;
  unsigned short* lB1 = Bs + 2048 + tid * 8;

  for (int k = 0; k < K; k += 32) {
    gload16(gA0 + k, lA0);
    gload16(gA1 + k, lA1);
    gload16(gB0 + k, lB0);
    gload16(gB1 + k, lB1);
    __syncthreads();

    u16x8 af[4], bfv[4];
    #pragma unroll
    for (int mi = 0; mi < 4; mi++)
      af[mi] = *(const u16x8*)&As[(wr * 64 + mi * 16 + fr) * 32 + fq * 8];
    #pragma unroll
    for (int nj = 0; nj < 4; nj++)
      bfv[nj] = *(const u16x8*)&Bs[(wc * 64 + nj * 16 + fr) * 32 + fq * 8];
    #pragma unroll
    for (int mi = 0; mi < 4; mi++)
      #pragma unroll
      for (int nj = 0; nj < 4; nj++)
        acc[mi][nj] = __builtin_amdgcn_mfma_f32_16x16x32_bf16(
            as_bf(af[mi]), as_bf(bfv[nj]), acc[mi][nj], 0, 0, 0);
    __syncthreads();
  }

  #pragma unroll
  for (int mi = 0; mi < 4; mi++)
  #pragma unroll
  for (int nj = 0; nj < 4; nj++) {
    f32x4 a = acc[mi][nj];
    #pragma unroll
    for (int j = 0; j < 4; j++) {
      int grow = r0 + wr * 64 + mi * 16 + fq * 4 + j;
      int gcol = c0 + wc * 64 + nj * 16 + fr;
      float v = a[j];
      if constexpr (EPI == 0) {
        float bias = gcol < 512 ? bias0[gcol] : bias1[gcol - 512];
        unsigned short r = f2bf(tanhf(v + bias));
        int prow = ((grow & 63) << 7) | (grow >> 6);
        (gcol < 512 ? obf0 : obf1)[(size_t)prow * 512 + (gcol & 511)] = r;
      } else {
        of[(size_t)grow * ofld + gcol] = v + bias0[gcol];
      }
    }
  }
}

// ------------------------- generic 128x128 MFMA GEMM ------------------------
// (h0 only: A bf16, B f32, raw f32 partials via z split-K)
template<int A_BF16, int B_BF16, int EPI>
__global__ __launch_bounds__(256) void k_gemm128(
    const void* __restrict__ Ap, int lda, const void* __restrict__ Bp, int ldb,
    int M, int N, int kper,
    unsigned short* __restrict__ obf0, unsigned short* __restrict__ obf1,
    float* __restrict__ of, const float* __restrict__ bias0,
    const float* __restrict__ bias1)
{
  __shared__ __align__(16) unsigned short As[128 * 32];
  __shared__ __align__(16) unsigned short Bs[128 * 32];
  const int tid = threadIdx.x;
  const int c0 = blockIdx.x * 128, r0 = blockIdx.y * 128;
  const int k0 = blockIdx.z * kper;
  if (EPI == 2) of += (size_t)blockIdx.z * M * N;

  const int lane = tid & 63, w = tid >> 6;
  const int wr = w >> 1, wc = w & 1;
  const int fr = lane & 15, fq = lane >> 4;

  f32x4 acc[4][4] = {};

  const int srow = tid >> 1, shalf = (tid & 1) * 16;

  for (int k = k0; k < k0 + kper; k += 32) {
    u16x8 a0, a1, b0, b1;
    {
      int gr = r0 + srow;
      if (gr < M) {
        if (A_BF16) {
          const unsigned short* a = (const unsigned short*)Ap + (size_t)gr * lda + k + shalf;
          a0 = *(const u16x8*)a; a1 = *(const u16x8*)(a + 8);
        } else {
          const float* a = (const float*)Ap + (size_t)gr * lda + k + shalf;
          float4 f0 = ((const float4*)a)[0], f1 = ((const float4*)a)[1];
          float4 f2 = ((const float4*)a)[2], f3 = ((const float4*)a)[3];
          a0 = pack8(f0, f1); a1 = pack8(f2, f3);
        }
      } else { a0 = zero8(); a1 = zero8(); }
    }
    {
      int gr = c0 + srow;
      if (B_BF16) {
        const unsigned short* p = (const unsigned short*)Bp + (size_t)gr * ldb + k + shalf;
        b0 = *(const u16x8*)p; b1 = *(const u16x8*)(p + 8);
      } else {
        const float* p = (const float*)Bp + (size_t)gr * ldb + k + shalf;
        float4 f0 = ((const float4*)p)[0], f1 = ((const float4*)p)[1];
        float4 f2 = ((const float4*)p)[2], f3 = ((const float4*)p)[3];
        b0 = pack8(f0, f1); b1 = pack8(f2, f3);
      }
    }
    *(u16x8*)&As[srow * 32 + shalf]     = a0;
    *(u16x8*)&As[srow * 32 + shalf + 8] = a1;
    *(u16x8*)&Bs[srow * 32 + shalf]     = b0;
    *(u16x8*)&Bs[srow * 32 + shalf + 8] = b1;
    __syncthreads();

    u16x8 af[4], bfv[4];
    #pragma unroll
    for (int mi = 0; mi < 4; mi++)
      af[mi] = *(const u16x8*)&As[(wr * 64 + mi * 16 + fr) * 32 + fq * 8];
    #pragma unroll
    for (int nj = 0; nj < 4; nj++)
      bfv[nj] = *(const u16x8*)&Bs[(wc * 64 + nj * 16 + fr) * 32 + fq * 8];
    #pragma unroll
    for (int mi = 0; mi < 4; mi++)
      #pragma unroll
      for (int nj = 0; nj < 4; nj++)
        acc[mi][nj] = __builtin_amdgcn_mfma_f32_16x16x32_bf16(
            as_bf(af[mi]), as_bf(bfv[nj]), acc[mi][nj], 0, 0, 0);
    __syncthreads();
  }

  #pragma unroll
  for (int mi = 0; mi < 4; mi++)
  #pragma unroll
  for (int nj = 0; nj < 4; nj++) {
    f32x4 a = acc[mi][nj];
    #pragma unroll
    for (int j = 0; j < 4; j++) {
      int grow = r0 + wr * 64 + mi * 16 + fq * 4 + j;
      int gcol = c0 + wc * 64 + nj * 16 + fr;
      if (grow < M) {
        float v = a[j];
        if constexpr (EPI == 1) {
          of[(size_t)grow * N + gcol] = v + bias0[gcol];
        } else if constexpr (EPI == 2) {
          of[(size_t)grow * N + gcol] = v;
        }
      }
    }
  }
}

__global__ __launch_bounds__(256) void k_reduce_h0(const float* __restrict__ part,
                                                   const float* __restrict__ b_ctx,
                                                   float* __restrict__ h) {
  int j = blockIdx.x * 256 + threadIdx.x;   // < 64*512
  float s = b_ctx[j & 511];
  for (int z = 0; z < 8; z++) s += part[z * 32768 + j];
  h[j] = s;
}

// ------------------- W_f = W_ih @ W_in  fold (one-time) ---------------------
__global__ __launch_bounds__(256) void k_wf(const float* __restrict__ W_ih,
                                            const float* __restrict__ W_in,
                                            unsigned short* __restrict__ wf_att,
                                            float* __restrict__ wfx) {
  __shared__ float wl[8][512];
  int ic = blockIdx.x, jc = blockIdx.y, tid = threadIdx.x;
  for (int x = tid; x < 8 * 512; x += 256)
    wl[x >> 9][x & 511] = W_ih[(ic * 8 + (x >> 9)) * 512 + (x & 511)];
  __syncthreads();
  int j = jc * 256 + tid;
  if (j >= 1324) return;
  float acc[8] = {};
  for (int d = 0; d < 512; d++) {
    float win = W_in[d * 1324 + j];
    #pragma unroll
    for (int r = 0; r < 8; r++) acc[r] += wl[r][d] * win;
  }
  for (int r = 0; r < 8; r++) {
    int i = ic * 8 + r;
    if (j < 300) wfx[i * 300 + j] = acc[r];
    else         wf_att[i * 1024 + (j - 300)] = f2bf(acc[r]);
  }
}

__global__ __launch_bounds__(256) void k_bfull(const float* __restrict__ W_ih,
                                               const float* __restrict__ b_in,
                                               const float* __restrict__ b_ih,
                                               float* __restrict__ bfull) {
  int i = blockIdx.x * 256 + threadIdx.x;
  if (i >= 1536) return;
  float acc = b_ih[i];
  for (int d = 0; d < 512; d++) acc += W_ih[i * 512 + d] * b_in[d];
  bfull[i] = acc;
}

// gi_x[t*64+b, :] = expl[t,b,:300] @ Wfx^T
__global__ __launch_bounds__(256) void k_gix(const float* __restrict__ expl,
                                             const float* __restrict__ wfx,
                                             float* __restrict__ gi_x) {
  __shared__ float el[16][300];
  int rc = blockIdx.x, ic = blockIdx.y, tid = threadIdx.x;
  for (int x = tid; x < 16 * 300; x += 256)
    el[x / 300][x % 300] = expl[(size_t)(rc * 16 + x / 300) * 300 + (x % 300)];
  __syncthreads();
  int c = ic * 256 + tid;
  float acc[16] = {};
  for (int k = 0; k < 300; k++) {
    float wv = wfx[c * 300 + k];
    #pragma unroll
    for (int r = 0; r < 16; r++) acc[r] += el[r][k] * wv;
  }
  for (int r = 0; r < 16; r++) gi_x[(size_t)(rc * 16 + r) * 1536 + c] = acc[r];
}

// --------- S1: redundant-GRU + [q|gh] matvec (LDS-staged MFMA) --------------
// 40 blocks x 256 thr. Each block: (a) issue 16 gload16 B-chunks (in flight),
// (b) recompute full 64x512 GRU -> chunked LDS hL[16][64][32] (blocks 0-7
// also write h state slice + outs[t-1]), (c) ONE barrier, (d) 16-chunk MFMA,
// (e) epilogue -> qf / ghwr. h & gh double-buffered across steps (no race).
__global__ __launch_bounds__(256) void k_hqg(
    int t, const float* __restrict__ hrd, float* __restrict__ hwr,
    const float* __restrict__ gif, const float* __restrict__ ghrd,
    float* __restrict__ ghwr,
    const unsigned short* __restrict__ wcat,
    const float* __restrict__ bq1, const float* __restrict__ bq2,
    const float* __restrict__ b_hh,
    float* __restrict__ qf, unsigned short* __restrict__ outs_bf)
{
  __shared__ __align__(16) unsigned short hL[16 * 2048];   // [c][64][32] 64KB
  __shared__ __align__(16) unsigned short BL[16 * 2048];   // [c][64][32] 64KB
  const int tid = threadIdx.x, blk = blockIdx.x;
  const int n0 = blk * 64;
  const int srow = tid >> 2, scol = (tid & 3) * 8;

  // (a) all 16 B-chunks in flight; latency hides under the GRU below
  #pragma unroll
  for (int c = 0; c < 16; c++)
    gload16(wcat + (size_t)(n0 + srow) * 512 + c * 32 + scol,
            BL + c * 2048 + tid * 8);

  // (b) h(t): GRU for t>0, copy h0 for t==0. 8192 quads of 4.
  for (int q = tid; q < 8192; q += 256) {
    int b = q >> 7, d0 = (q & 127) * 4;
    float4 hv4;
    if (t > 0) {
      float4 ir = *(const float4*)(gif + b * 1536 + d0);
      float4 iz = *(const float4*)(gif + b * 1536 + 512 + d0);
      float4 in_ = *(const float4*)(gif + b * 1536 + 1024 + d0);
      float4 hr = *(const float4*)(ghrd + b * 1536 + d0);
      float4 hz = *(const float4*)(ghrd + b * 1536 + 512 + d0);
      float4 hn = *(const float4*)(ghrd + b * 1536 + 1024 + d0);
      float4 ho = *(const float4*)(hrd + b * 512 + d0);
      hv4.x = gru1(ir.x, iz.x, in_.x, hr.x, hz.x, hn.x, ho.x);
      hv4.y = gru1(ir.y, iz.y, in_.y, hr.y, hz.y, hn.y, ho.y);
      hv4.z = gru1(ir.z, iz.z, in_.z, hr.z, hz.z, hn.z, ho.z);
      hv4.w = gru1(ir.w, iz.w, in_.w, hr.w, hz.w, hn.w, ho.w);
      if (blk < 8 && (q >> 10) == blk) {      // slice owner writes state+outs
        *(float4*)(hwr + b * 512 + d0) = hv4;
        size_t ob = (size_t)((t - 1) * 64 + b) * 512 + d0;
        outs_bf[ob]     = f2bf(hv4.x);
        outs_bf[ob + 1] = f2bf(hv4.y);
        outs_bf[ob + 2] = f2bf(hv4.z);
        outs_bf[ob + 3] = f2bf(hv4.w);
      }
    } else {
      hv4 = *(const float4*)(hrd + b * 512 + d0);
    }
    unsigned short* p = hL + (d0 >> 5) * 2048 + b * 32 + (d0 & 31);
    p[0] = f2bf(hv4.x); p[1] = f2bf(hv4.y); p[2] = f2bf(hv4.z); p[3] = f2bf(hv4.w);
  }
  __syncthreads();   // drains gload16 (vmcnt) + hL ds_writes

  // (d) MFMA: wave w owns output rows [w*16, w*16+16)
  const int lane = tid & 63, w = tid >> 6;
  const int fr = lane & 15, fq = lane >> 4;
  f32x4 acc[4] = {};
  #pragma unroll
  for (int c = 0; c < 16; c++) {
    u16x8 af = *(const u16x8*)(hL + c * 2048 + (w * 16 + fr) * 32 + fq * 8);
    #pragma unroll
    for (int nj = 0; nj < 4; nj++) {
      u16x8 bv = *(const u16x8*)(BL + c * 2048 + (nj * 16 + fr) * 32 + fq * 8);
      acc[nj] = __builtin_amdgcn_mfma_f32_16x16x32_bf16(as_bf(af), as_bf(bv), acc[nj], 0, 0, 0);
    }
  }

  // (e) epilogue
  #pragma unroll
  for (int nj = 0; nj < 4; nj++) {
    #pragma unroll
    for (int j = 0; j < 4; j++) {
      int row = w * 16 + fq * 4 + j;
      int col = n0 + nj * 16 + fr;
      float v = acc[nj][j];
      if (col < 512)       qf[(size_t)row * 1024 + col] = tanhf(v + bq1[col]);
      else if (col < 1024) qf[(size_t)row * 1024 + col] = tanhf(v + bq2[col - 512]);
      else                 ghwr[(size_t)row * 1536 + (col - 1024)] = v + b_hh[col - 1024];
    }
  }
}

// ------------------- S2: attention (R6 verbatim) ----------------------------
__global__ __launch_bounds__(256) void k_att(
    const float* __restrict__ qf,
    const unsigned short* __restrict__ keys1, const unsigned short* __restrict__ keys2,
    const unsigned short* __restrict__ vals1, const unsigned short* __restrict__ vals2,
    unsigned short* __restrict__ att_bf)
{
  const int id = blockIdx.x, side = id >> 6, b = id & 63;
  const int tid = threadIdx.x;
  __shared__ float qv[512];
  __shared__ float sred[128][2];
  __shared__ float pr[128];

  for (int i = tid; i < 512; i += 256)
    qv[i] = qf[(size_t)b * 1024 + side * 512 + i];
  __syncthreads();

  const unsigned short* keys = side ? keys2 : keys1;
  {
    int tt = tid >> 1, half = tid & 1;
    const u16x8* krow = (const u16x8*)(keys + ((size_t)(b * 128 + tt)) * 512 + half * 256);
    float acc = 0.f;
    #pragma unroll 4
    for (int k8 = 0; k8 < 32; k8++) {
      u16x8 kv = krow[k8];
      #pragma unroll
      for (int jj = 0; jj < 8; jj++) acc += qv[half * 256 + k8 * 8 + jj] * bf2f(kv[jj]);
    }
    sred[tt][half] = acc;
  }
  __syncthreads();

  if (tid < 64) {
    float s0 = sred[tid][0] + sred[tid][1];
    float s1 = sred[tid + 64][0] + sred[tid + 64][1];
    float m = fmaxf(s0, s1);
    #pragma unroll
    for (int off = 32; off; off >>= 1) m = fmaxf(m, __shfl_xor(m, off));
    float e0 = __expf(s0 - m), e1 = __expf(s1 - m);
    float ss = e0 + e1;
    #pragma unroll
    for (int off = 32; off; off >>= 1) ss += __shfl_xor(ss, off);
    float inv = 1.f / ss;
    pr[tid] = e0 * inv;
    pr[tid + 64] = e1 * inv;
  }
  __syncthreads();

  const unsigned short* vals = side ? vals2 : vals1;
  {
    int a0 = tid * 2;
    float acc0 = 0.f, acc1 = 0.f;
    for (int tt = 0; tt < 128; tt++) {
      float p = pr[tt];
      unsigned v = *(const unsigned*)(vals + ((size_t)(b * 128 + tt)) * 512 + a0);
      acc0 += p * bf2f((unsigned short)(v & 0xffffu));
      acc1 += p * bf2f((unsigned short)(v >> 16));
    }
    att_bf[(size_t)b * 1024 + side * 512 + a0]     = f2bf(acc0);
    att_bf[(size_t)b * 1024 + side * 512 + a0 + 1] = f2bf(acc1);
  }
}

// ------------------- S3: gi matvec (R6 k_mv64<1> verbatim) ------------------
__global__ __launch_bounds__(256) void k_gi(
    int t, const unsigned short* __restrict__ att_bf,
    const unsigned short* __restrict__ wf_att,
    const float* __restrict__ gi_x, const float* __restrict__ bfull,
    float* __restrict__ gif)
{
  __shared__ __align__(16) unsigned short As[64 * 32];
  __shared__ __align__(16) unsigned short Bs[64 * 32];
  const int tid = threadIdx.x;
  const int n0 = blockIdx.x * 64;
  const int lane = tid & 63, w = tid >> 6;
  const int fr = lane & 15, fq = lane >> 4;
  f32x4 acc[4] = {};
  const int srow = tid >> 2, soff = (tid & 3) * 8;

  for (int k = 0; k < 1024; k += 32) {
    gload16(att_bf + (size_t)srow * 1024 + k + soff, As + tid * 8);
    gload16(wf_att + (size_t)(n0 + srow) * 1024 + k + soff, Bs + tid * 8);
    __syncthreads();
    u16x8 af = *(const u16x8*)&As[(w * 16 + fr) * 32 + fq * 8];
    #pragma unroll
    for (int nj = 0; nj < 4; nj++) {
      u16x8 bfv = *(const u16x8*)&Bs[(nj * 16 + fr) * 32 + fq * 8];
      acc[nj] = __builtin_amdgcn_mfma_f32_16x16x32_bf16(as_bf(af), as_bf(bfv), acc[nj], 0, 0, 0);
    }
    __syncthreads();
  }
  #pragma unroll
  for (int nj = 0; nj < 4; nj++) {
    #pragma unroll
    for (int j = 0; j < 4; j++) {
      int row = w * 16 + fq * 4 + j;
      int col = n0 + nj * 16 + fr;
      gif[(size_t)row * 1536 + col] =
          acc[nj][j] + gi_x[(size_t)(t * 64 + row) * 1536 + col] + bfull[col];
    }
  }
}

// ------------------------------ final GRU -----------------------------------
__global__ __launch_bounds__(256) void k_final(const float* __restrict__ gi,
                                               const float* __restrict__ gh,
                                               const float* __restrict__ hrd,
                                               unsigned short* __restrict__ outs_bf) {
  int b = blockIdx.x, tid = threadIdx.x;
  for (int d = tid; d < 512; d += 256) {
    float hv = gru1(gi[b*1536 + d], gi[b*1536 + 512 + d], gi[b*1536 + 1024 + d],
                    gh[b*1536 + d], gh[b*1536 + 512 + d], gh[b*1536 + 1024 + d],
                    hrd[b*512 + d]);
    outs_bf[(size_t)(31 * 64 + b) * 512 + d] = f2bf(hv);
  }
}

// ---------------------------------------------------------------------------
extern "C" void kernel_launch(void* const* d_in, const int* in_sizes, int n_in,
                              void* d_out, int out_size, void* d_ws, size_t ws_size,
                              hipStream_t stream) {
  const float* expl  = (const float*)d_in[0];
  const float* enc1  = (const float*)d_in[1];
  const float* enc2  = (const float*)d_in[2];
  const float* s1e   = (const float*)d_in[3];
  const float* s2e   = (const float*)d_in[4];
  const float* W_ctx = (const float*)d_in[5];
  const float* b_ctx = (const float*)d_in[6];
  const float* Wq1   = (const float*)d_in[7];
  const float* bq1   = (const float*)d_in[8];
  const float* Wk1   = (const float*)d_in[9];
  const float* bk1   = (const float*)d_in[10];
  const float* Wv1   = (const float*)d_in[11];
  const float* bv1   = (const float*)d_in[12];
  const float* Wq2   = (const float*)d_in[13];
  const float* bq2   = (const float*)d_in[14];
  const float* Wk2   = (const float*)d_in[15];
  const float* bk2   = (const float*)d_in[16];
  const float* Wv2   = (const float*)d_in[17];
  const float* bv2   = (const float*)d_in[18];
  const float* W_in  = (const float*)d_in[19];
  const float* b_in  = (const float*)d_in[20];
  const float* W_ih  = (const float*)d_in[21];
  const float* b_ih  = (const float*)d_in[22];
  const float* W_hh  = (const float*)d_in[23];
  const float* b_hh  = (const float*)d_in[24];
  const float* W_voc = (const float*)d_in[25];
  const float* b_voc = (const float*)d_in[26];
  float* out = (float*)d_out;

  char* ws = (char*)d_ws;
  unsigned short* keys1  = (unsigned short*)(ws + 0);          // [b*128+tt][512]
  unsigned short* vals1  = (unsigned short*)(ws + 8388608);
  unsigned short* keys2  = (unsigned short*)(ws + 16777216);
  unsigned short* vals2  = (unsigned short*)(ws + 25165824);
  unsigned short* encbf  = (unsigned short*)(ws + 33554432);   // 67.1 MB
  unsigned short* wkv    = (unsigned short*)(ws + 100663296);  // 8.4 MB
  unsigned short* wvoc   = (unsigned short*)(ws + 109051904);  // 32.8 MB
  unsigned short* wcat   = (unsigned short*)(ws + 141819904);  // [2560][512]
  unsigned short* wf_att = (unsigned short*)(ws + 144441344);  // [1536][1024]
  float*          wfx    = (float*)(ws + 147587072);
  float*          bfull  = (float*)(ws + 149430272);
  float*          gi_x   = (float*)(ws + 149436416);           // 12.6 MB
  unsigned short* ctx_bf = (unsigned short*)(ws + 162019328);
  float*          part   = (float*)(ws + 164116480);
  float*          h0f    = (float*)(ws + 165165056);           // 128 KB
  float*          hbuf0  = (float*)(ws + 165296128);           // 128 KB
  float*          hbuf1  = (float*)(ws + 165427200);           // 128 KB
  float*          qf     = (float*)(ws + 165558272);           // 256 KB
  float*          ghbuf0 = (float*)(ws + 165820416);           // 384 KB
  float*          ghbuf1 = (float*)(ws + 166213632);           // 384 KB
  float*          gif    = (float*)(ws + 166606848);           // 384 KB
  unsigned short* att_bf = (unsigned short*)(ws + 167000064);  // 128 KB
  unsigned short* outs_bf= (unsigned short*)(ws + 167131136);  // 2 MB
  // end ~169.2 MB

  auto cvt = [&](const float* s, unsigned short* d, int n) {
    k_cvt<<<(n + 1023) / 1024, 256, 0, stream>>>(s, d, n);
  };

  // ---- keys/vals side 1 ----
  cvt(enc1, encbf, 8192 * 4096);
  cvt(Wk1, wkv, 512 * 4096);
  cvt(Wv1, wkv + 512 * 4096, 512 * 4096);
  k_gemm_lds<0><<<dim3(64, 8), 256, 0, stream>>>(
      encbf, 4096, wkv, 4096, 4096, keys1, vals1, nullptr, 0, bk1, bv1);
  // ---- keys/vals side 2 ----
  cvt(enc2, encbf, 8192 * 4096);
  cvt(Wk2, wkv, 512 * 4096);
  cvt(Wv2, wkv + 512 * 4096, 512 * 4096);
  k_gemm_lds<0><<<dim3(64, 8), 256, 0, stream>>>(
      encbf, 4096, wkv, 4096, 4096, keys2, vals2, nullptr, 0, bk2, bv2);

  // ---- weight converts ----
  cvt(W_voc, wvoc, 32000 * 512);
  cvt(Wq1, wcat, 512 * 512);
  cvt(Wq2, wcat + 512 * 512, 512 * 512);
  cvt(W_hh, wcat + 1024 * 512, 1536 * 512);

  // ---- Wf fold + gi_x ----
  k_wf<<<dim3(192, 6), 256, 0, stream>>>(W_ih, W_in, wf_att, wfx);
  k_bfull<<<6, 256, 0, stream>>>(W_ih, b_in, b_ih, bfull);
  k_gix<<<dim3(128, 6), 256, 0, stream>>>(expl, wfx, gi_x);

  // ---- h0 ----
  k_build_ctx<<<4096, 256, 0, stream>>>(s1e, s2e, ctx_bf);
  k_gemm128<1, 0, 2><<<dim3(4, 1, 8), 256, 0, stream>>>(
      ctx_bf, 16384, W_ctx, 16384, 64, 512, 2048,
      nullptr, nullptr, part, nullptr, nullptr);
  k_reduce_h0<<<128, 256, 0, stream>>>(part, b_ctx, h0f);

  // ---- recurrence: 3 launches per step ----
  float* hb[2]  = { hbuf0, hbuf1 };
  float* ghb[2] = { ghbuf0, ghbuf1 };
  for (int t = 0; t < 32; t++) {
    const float* hrd  = (t <= 1) ? h0f : hb[(t - 1) & 1];
    const float* ghrd = (t == 0) ? ghbuf0 : ghb[(t - 1) & 1];
    k_hqg<<<40, 256, 0, stream>>>(t, hrd, hb[t & 1], gif, ghrd, ghb[t & 1],
                                  wcat, bq1, bq2, b_hh, qf, outs_bf);
    k_att<<<128, 256, 0, stream>>>(qf, keys1, keys2, vals1, vals2, att_bf);
    k_gi<<<24, 256, 0, stream>>>(t, att_bf, wf_att, gi_x, bfull, gif);
  }
  k_final<<<64, 256, 0, stream>>>(gif, ghbuf1, hbuf1, outs_bf);

  // ---- logits = outs @ W_voc^T + b_voc ----
  k_gemm_lds<1><<<dim3(16, 250), 256, 0, stream>>>(
      outs_bf, 512, wvoc, 512, 512, nullptr, nullptr, out, 32000, b_voc, nullptr);
}

// Round 11
// 2335.473 us; speedup vs baseline: 2.9285x; 1.2837x over previous
//
#include <hip/hip_runtime.h>

// ---------------------------------------------------------------------------
// AttentionDecoder. Laws:
//   R5: recurrence weights/state reads partitioned across blocks, never
//       replicated (replication cost = size x blocks / L2 BW).
//   R8: software grid barriers trash L2 -> never.
//   R9: LDS-staged MFMA (gload16) beats barrier-free direct-global MFMA.
//   R10: launch count is secondary to per-kernel exec efficiency.
// R11 = R6 (best, 2080us) + k_gicomb fusion: 3 launches/step:
//   S1 k_mv64<0> (40 blk): [q|gh] = h @ [Wq1;Wq2;Whh]^T (MFMA, gload16)
//   S2 k_att    (128 blk): scores/softmax/att per (b,side)
//   S3 k_gicomb   (8 blk): gi 3-gate tiles (LDS-staged MFMA) + partitioned GRU
//                          -> hst/h_bf/outs[t]   (replaces k_gi+k_gru+k_final)
// ---------------------------------------------------------------------------

typedef float    f32x4 __attribute__((ext_vector_type(4)));
typedef __bf16   bf16x8 __attribute__((ext_vector_type(8)));
typedef unsigned short u16x8 __attribute__((ext_vector_type(8)));

#define DEV __device__ __forceinline__

DEV unsigned short f2bf(float f) {
  unsigned u = __builtin_bit_cast(unsigned, f);
  u += 0x7fffu + ((u >> 16) & 1u);
  return (unsigned short)(u >> 16);
}
DEV float bf2f(unsigned short h) {
  return __builtin_bit_cast(float, (unsigned)h << 16);
}
DEV bf16x8 as_bf(u16x8 v) { return __builtin_bit_cast(bf16x8, v); }
DEV u16x8 zero8() {
  u16x8 r = {0, 0, 0, 0, 0, 0, 0, 0};
  return r;
}
DEV u16x8 pack8(float4 a, float4 b) {
  u16x8 r;
  r[0]=f2bf(a.x); r[1]=f2bf(a.y); r[2]=f2bf(a.z); r[3]=f2bf(a.w);
  r[4]=f2bf(b.x); r[5]=f2bf(b.y); r[6]=f2bf(b.z); r[7]=f2bf(b.w);
  return r;
}
DEV void gload16(const void* g, void* l) {
  __builtin_amdgcn_global_load_lds(
      (const __attribute__((address_space(1))) void*)g,
      (__attribute__((address_space(3))) void*)l, 16, 0, 0);
}
DEV float gru1(float ir, float iz, float inn, float hr, float hz, float hn,
               float ho) {
  float r = 1.f / (1.f + expf(-(ir + hr)));
  float z = 1.f / (1.f + expf(-(iz + hz)));
  float n = tanhf(inn + r * hn);
  return (1.f - z) * n + z * ho;
}

// ------------------------------- converts ----------------------------------
__global__ __launch_bounds__(256) void k_cvt(const float* __restrict__ s,
                                             unsigned short* __restrict__ d, int n) {
  int i = (blockIdx.x * 256 + threadIdx.x) * 4;
  if (i + 4 <= n) {
    float4 v = *(const float4*)(s + i);
    d[i] = f2bf(v.x); d[i+1] = f2bf(v.y); d[i+2] = f2bf(v.z); d[i+3] = f2bf(v.w);
  } else {
    for (; i < n; i++) d[i] = f2bf(s[i]);
  }
}

// ctx_feat = [s1, s2, |s1-s2|, s1*s2]  -> bf16 [64, 16384]
__global__ __launch_bounds__(256) void k_build_ctx(const float* __restrict__ s1,
                                                   const float* __restrict__ s2,
                                                   unsigned short* __restrict__ ctx) {
  int j = blockIdx.x * 256 + threadIdx.x;
  int b = j >> 14, jj = j & 16383;
  int f = jj >> 12, k = jj & 4095;
  float a = s1[b * 4096 + k], c = s2[b * 4096 + k];
  float v = (f == 0) ? a : (f == 1) ? c : (f == 2) ? fabsf(a - c) : a * c;
  ctx[j] = f2bf(v);
}

// --------------- bf16 128x128 GEMM with global_load_lds staging -------------
// EPI 0: tanh(+bias), split col 512, PERMUTED rows (tt*64+b -> b*128+tt)
// EPI 1: +bias -> f32, ld ofld
template<int EPI>
__global__ __launch_bounds__(256) void k_gemm_lds(
    const unsigned short* __restrict__ A, int lda,
    const unsigned short* __restrict__ B, int ldb, int K,
    unsigned short* __restrict__ obf0, unsigned short* __restrict__ obf1,
    float* __restrict__ of, int ofld,
    const float* __restrict__ bias0, const float* __restrict__ bias1)
{
  __shared__ __align__(16) unsigned short As[128 * 32];
  __shared__ __align__(16) unsigned short Bs[128 * 32];
  const int tid = threadIdx.x;
  const int r0 = blockIdx.x * 128, c0 = blockIdx.y * 128;
  const int lane = tid & 63, w = tid >> 6;
  const int wr = w >> 1, wc = w & 1;
  const int fr = lane & 15, fq = lane >> 4;
  f32x4 acc[4][4] = {};

  const int srow = tid >> 2, scol = (tid & 3) * 8;
  const unsigned short* gA0 = A + (size_t)(r0 + srow) * lda + scol;
  const unsigned short* gA1 = A + (size_t)(r0 + 64 + srow) * lda + scol;
  const unsigned short* gB0 = B + (size_t)(c0 + srow) * ldb + scol;
  const unsigned short* gB1 = B + (size_t)(c0 + 64 + srow) * ldb + scol;
  unsigned short* lA0 = As + tid * 8;
  unsigned short* lA1 = As + 2048 + tid * 8;
  unsigned short* lB0 = Bs + tid * 8;
  unsigned short* lB1 = Bs + 2048 + tid * 8;

  for (int k = 0; k < K; k += 32) {
    gload16(gA0 + k, lA0);
    gload16(gA1 + k, lA1);
    gload16(gB0 + k, lB0);
    gload16(gB1 + k, lB1);
    __syncthreads();

    u16x8 af[4], bfv[4];
    #pragma unroll
    for (int mi = 0; mi < 4; mi++)
      af[mi] = *(const u16x8*)&As[(wr * 64 + mi * 16 + fr) * 32 + fq * 8];
    #pragma unroll
    for (int nj = 0; nj < 4; nj++)
      bfv[nj] = *(const u16x8*)&Bs[(wc * 64 + nj * 16 + fr) * 32 + fq * 8];
    #pragma unroll
    for (int mi = 0; mi < 4; mi++)
      #pragma unroll
      for (int nj = 0; nj < 4; nj++)
        acc[mi][nj] = __builtin_amdgcn_mfma_f32_16x16x32_bf16(
            as_bf(af[mi]), as_bf(bfv[nj]), acc[mi][nj], 0, 0, 0);
    __syncthreads();
  }

  #pragma unroll
  for (int mi = 0; mi < 4; mi++)
  #pragma unroll
  for (int nj = 0; nj < 4; nj++) {
    f32x4 a = acc[mi][nj];
    #pragma unroll
    for (int j = 0; j < 4; j++) {
      int grow = r0 + wr * 64 + mi * 16 + fq * 4 + j;
      int gcol = c0 + wc * 64 + nj * 16 + fr;
      float v = a[j];
      if constexpr (EPI == 0) {
        float bias = gcol < 512 ? bias0[gcol] : bias1[gcol - 512];
        unsigned short r = f2bf(tanhf(v + bias));
        int prow = ((grow & 63) << 7) | (grow >> 6);
        (gcol < 512 ? obf0 : obf1)[(size_t)prow * 512 + (gcol & 511)] = r;
      } else {
        of[(size_t)grow * ofld + gcol] = v + bias0[gcol];
      }
    }
  }
}

// ------------------------- generic 128x128 MFMA GEMM ------------------------
// (h0 only: A bf16, B f32, raw f32 partials via z split-K)
template<int A_BF16, int B_BF16, int EPI>
__global__ __launch_bounds__(256) void k_gemm128(
    const void* __restrict__ Ap, int lda, const void* __restrict__ Bp, int ldb,
    int M, int N, int kper,
    unsigned short* __restrict__ obf0, unsigned short* __restrict__ obf1,
    float* __restrict__ of, const float* __restrict__ bias0,
    const float* __restrict__ bias1)
{
  __shared__ __align__(16) unsigned short As[128 * 32];
  __shared__ __align__(16) unsigned short Bs[128 * 32];
  const int tid = threadIdx.x;
  const int c0 = blockIdx.x * 128, r0 = blockIdx.y * 128;
  const int k0 = blockIdx.z * kper;
  if (EPI == 2) of += (size_t)blockIdx.z * M * N;

  const int lane = tid & 63, w = tid >> 6;
  const int wr = w >> 1, wc = w & 1;
  const int fr = lane & 15, fq = lane >> 4;

  f32x4 acc[4][4] = {};

  const int srow = tid >> 1, shalf = (tid & 1) * 16;

  for (int k = k0; k < k0 + kper; k += 32) {
    u16x8 a0, a1, b0, b1;
    {
      int gr = r0 + srow;
      if (gr < M) {
        if (A_BF16) {
          const unsigned short* a = (const unsigned short*)Ap + (size_t)gr * lda + k + shalf;
          a0 = *(const u16x8*)a; a1 = *(const u16x8*)(a + 8);
        } else {
          const float* a = (const float*)Ap + (size_t)gr * lda + k + shalf;
          float4 f0 = ((const float4*)a)[0], f1 = ((const float4*)a)[1];
          float4 f2 = ((const float4*)a)[2], f3 = ((const float4*)a)[3];
          a0 = pack8(f0, f1); a1 = pack8(f2, f3);
        }
      } else { a0 = zero8(); a1 = zero8(); }
    }
    {
      int gr = c0 + srow;
      if (B_BF16) {
        const unsigned short* p = (const unsigned short*)Bp + (size_t)gr * ldb + k + shalf;
        b0 = *(const u16x8*)p; b1 = *(const u16x8*)(p + 8);
      } else {
        const float* p = (const float*)Bp + (size_t)gr * ldb + k + shalf;
        float4 f0 = ((const float4*)p)[0], f1 = ((const float4*)p)[1];
        float4 f2 = ((const float4*)p)[2], f3 = ((const float4*)p)[3];
        b0 = pack8(f0, f1); b1 = pack8(f2, f3);
      }
    }
    *(u16x8*)&As[srow * 32 + shalf]     = a0;
    *(u16x8*)&As[srow * 32 + shalf + 8] = a1;
    *(u16x8*)&Bs[srow * 32 + shalf]     = b0;
    *(u16x8*)&Bs[srow * 32 + shalf + 8] = b1;
    __syncthreads();

    u16x8 af[4], bfv[4];
    #pragma unroll
    for (int mi = 0; mi < 4; mi++)
      af[mi] = *(const u16x8*)&As[(wr * 64 + mi * 16 + fr) * 32 + fq * 8];
    #pragma unroll
    for (int nj = 0; nj < 4; nj++)
      bfv[nj] = *(const u16x8*)&Bs[(wc * 64 + nj * 16 + fr) * 32 + fq * 8];
    #pragma unroll
    for (int mi = 0; mi < 4; mi++)
      #pragma unroll
      for (int nj = 0; nj < 4; nj++)
        acc[mi][nj] = __builtin_amdgcn_mfma_f32_16x16x32_bf16(
            as_bf(af[mi]), as_bf(bfv[nj]), acc[mi][nj], 0, 0, 0);
    __syncthreads();
  }

  #pragma unroll
  for (int mi = 0; mi < 4; mi++)
  #pragma unroll
  for (int nj = 0; nj < 4; nj++) {
    f32x4 a = acc[mi][nj];
    #pragma unroll
    for (int j = 0; j < 4; j++) {
      int grow = r0 + wr * 64 + mi * 16 + fq * 4 + j;
      int gcol = c0 + wc * 64 + nj * 16 + fr;
      if (grow < M) {
        float v = a[j];
        if constexpr (EPI == 1) {
          of[(size_t)grow * N + gcol] = v + bias0[gcol];
        } else if constexpr (EPI == 2) {
          of[(size_t)grow * N + gcol] = v;
        }
      }
    }
  }
}

__global__ __launch_bounds__(256) void k_reduce_h0(const float* __restrict__ part,
                                                   const float* __restrict__ b_ctx,
                                                   float* __restrict__ h,
                                                   unsigned short* __restrict__ h_bf) {
  int j = blockIdx.x * 256 + threadIdx.x;   // < 64*512
  float s = b_ctx[j & 511];
  for (int z = 0; z < 8; z++) s += part[z * 32768 + j];
  h[j] = s;
  h_bf[j] = f2bf(s);
}

// ------------------- W_f = W_ih @ W_in  fold (one-time) ---------------------
__global__ __launch_bounds__(256) void k_wf(const float* __restrict__ W_ih,
                                            const float* __restrict__ W_in,
                                            unsigned short* __restrict__ wf_att,
                                            float* __restrict__ wfx) {
  __shared__ float wl[8][512];
  int ic = blockIdx.x, jc = blockIdx.y, tid = threadIdx.x;
  for (int x = tid; x < 8 * 512; x += 256)
    wl[x >> 9][x & 511] = W_ih[(ic * 8 + (x >> 9)) * 512 + (x & 511)];
  __syncthreads();
  int j = jc * 256 + tid;
  if (j >= 1324) return;
  float acc[8] = {};
  for (int d = 0; d < 512; d++) {
    float win = W_in[d * 1324 + j];
    #pragma unroll
    for (int r = 0; r < 8; r++) acc[r] += wl[r][d] * win;
  }
  for (int r = 0; r < 8; r++) {
    int i = ic * 8 + r;
    if (j < 300) wfx[i * 300 + j] = acc[r];
    else         wf_att[i * 1024 + (j - 300)] = f2bf(acc[r]);
  }
}

__global__ __launch_bounds__(256) void k_bfull(const float* __restrict__ W_ih,
                                               const float* __restrict__ b_in,
                                               const float* __restrict__ b_ih,
                                               float* __restrict__ bfull) {
  int i = blockIdx.x * 256 + threadIdx.x;
  if (i >= 1536) return;
  float acc = b_ih[i];
  for (int d = 0; d < 512; d++) acc += W_ih[i * 512 + d] * b_in[d];
  bfull[i] = acc;
}

// gi_x[t*64+b, :] = expl[t,b,:300] @ Wfx^T
__global__ __launch_bounds__(256) void k_gix(const float* __restrict__ expl,
                                             const float* __restrict__ wfx,
                                             float* __restrict__ gi_x) {
  __shared__ float el[16][300];
  int rc = blockIdx.x, ic = blockIdx.y, tid = threadIdx.x;
  for (int x = tid; x < 16 * 300; x += 256)
    el[x / 300][x % 300] = expl[(size_t)(rc * 16 + x / 300) * 300 + (x % 300)];
  __syncthreads();
  int c = ic * 256 + tid;
  float acc[16] = {};
  for (int k = 0; k < 300; k++) {
    float wv = wfx[c * 300 + k];
    #pragma unroll
    for (int r = 0; r < 16; r++) acc[r] += el[r][k] * wv;
  }
  for (int r = 0; r < 16; r++) gi_x[(size_t)(rc * 16 + r) * 1536 + c] = acc[r];
}

// --------------- S1: per-step 64-row MFMA col-slice (R6 verbatim) -----------
// C[64, 2560] = h_bf[64,512] @ wcat[2560,512]^T, one 64x64 tile per block.
// col<1024 -> qf = tanh(v+bq), else ghf = v + b_hh.
template<int EPI>
__global__ __launch_bounds__(256) void k_mv64(
    const unsigned short* __restrict__ A, int lda,
    const unsigned short* __restrict__ B, int K,
    float* __restrict__ o1, float* __restrict__ o2,
    const float* __restrict__ x1, const float* __restrict__ x2,
    const float* __restrict__ x3, int t)
{
  __shared__ __align__(16) unsigned short As[64 * 32];
  __shared__ __align__(16) unsigned short Bs[64 * 32];
  const int tid = threadIdx.x;
  const int n0 = blockIdx.x * 64;
  const int lane = tid & 63, w = tid >> 6;
  const int fr = lane & 15, fq = lane >> 4;
  f32x4 acc[4] = {};
  const int srow = tid >> 2, soff = (tid & 3) * 8;

  for (int k = 0; k < K; k += 32) {
    gload16(A + (size_t)srow * lda + k + soff, As + tid * 8);
    gload16(B + (size_t)(n0 + srow) * K + k + soff, Bs + tid * 8);
    __syncthreads();
    u16x8 af = *(const u16x8*)&As[(w * 16 + fr) * 32 + fq * 8];
    #pragma unroll
    for (int nj = 0; nj < 4; nj++) {
      u16x8 bfv = *(const u16x8*)&Bs[(nj * 16 + fr) * 32 + fq * 8];
      acc[nj] = __builtin_amdgcn_mfma_f32_16x16x32_bf16(as_bf(af), as_bf(bfv), acc[nj], 0, 0, 0);
    }
    __syncthreads();
  }
  #pragma unroll
  for (int nj = 0; nj < 4; nj++) {
    #pragma unroll
    for (int j = 0; j < 4; j++) {
      int row = w * 16 + fq * 4 + j;
      int col = n0 + nj * 16 + fr;
      float v = acc[nj][j];
      if constexpr (EPI == 0) {
        if (col < 512)       o1[(size_t)row * 1024 + col] = tanhf(v + x1[col]);
        else if (col < 1024) o1[(size_t)row * 1024 + col] = tanhf(v + x2[col - 512]);
        else                 o2[(size_t)row * 1536 + (col - 1024)] = v + x3[col - 1024];
      } else {
        o1[(size_t)row * 1536 + col] =
            v + x1[(size_t)(t * 64 + row) * 1536 + col] + x2[col];
      }
    }
  }
}

// ------------------- S2: attention (R6 verbatim) ----------------------------
__global__ __launch_bounds__(256) void k_att(
    const float* __restrict__ qf,
    const unsigned short* __restrict__ keys1, const unsigned short* __restrict__ keys2,
    const unsigned short* __restrict__ vals1, const unsigned short* __restrict__ vals2,
    unsigned short* __restrict__ att_bf)
{
  const int id = blockIdx.x, side = id >> 6, b = id & 63;
  const int tid = threadIdx.x;
  __shared__ float qv[512];
  __shared__ float sred[128][2];
  __shared__ float pr[128];

  for (int i = tid; i < 512; i += 256)
    qv[i] = qf[(size_t)b * 1024 + side * 512 + i];
  __syncthreads();

  const unsigned short* keys = side ? keys2 : keys1;
  {
    int tt = tid >> 1, half = tid & 1;
    const u16x8* krow = (const u16x8*)(keys + ((size_t)(b * 128 + tt)) * 512 + half * 256);
    float acc = 0.f;
    #pragma unroll 4
    for (int k8 = 0; k8 < 32; k8++) {
      u16x8 kv = krow[k8];
      #pragma unroll
      for (int jj = 0; jj < 8; jj++) acc += qv[half * 256 + k8 * 8 + jj] * bf2f(kv[jj]);
    }
    sred[tt][half] = acc;
  }
  __syncthreads();

  if (tid < 64) {
    float s0 = sred[tid][0] + sred[tid][1];
    float s1 = sred[tid + 64][0] + sred[tid + 64][1];
    float m = fmaxf(s0, s1);
    #pragma unroll
    for (int off = 32; off; off >>= 1) m = fmaxf(m, __shfl_xor(m, off));
    float e0 = __expf(s0 - m), e1 = __expf(s1 - m);
    float ss = e0 + e1;
    #pragma unroll
    for (int off = 32; off; off >>= 1) ss += __shfl_xor(ss, off);
    float inv = 1.f / ss;
    pr[tid] = e0 * inv;
    pr[tid + 64] = e1 * inv;
  }
  __syncthreads();

  const unsigned short* vals = side ? vals2 : vals1;
  {
    int a0 = tid * 2;
    float acc0 = 0.f, acc1 = 0.f;
    for (int tt = 0; tt < 128; tt++) {
      float p = pr[tt];
      unsigned v = *(const unsigned*)(vals + ((size_t)(b * 128 + tt)) * 512 + a0);
      acc0 += p * bf2f((unsigned short)(v & 0xffffu));
      acc1 += p * bf2f((unsigned short)(v >> 16));
    }
    att_bf[(size_t)b * 1024 + side * 512 + a0]     = f2bf(acc0);
    att_bf[(size_t)b * 1024 + side * 512 + a0 + 1] = f2bf(acc1);
  }
}

// --------- S3: gi 3-gate tiles (LDS-staged MFMA) + partitioned GRU ----------
// 8 blocks x 768 thr (12 waves = 3 gates x 4 waves). Block j owns gi cols
// {j*64, 512+j*64, 1024+j*64} (K=1024). att staged ONCE per k-chunk (shared
// by all gates); Bs[g] staged by gate-g threads. Gate triplet lands in LDS
// gis[3][64][64] -> GRU for d-slice [j*64,(j+1)*64) x all b (partitioned).
__global__ __launch_bounds__(768) void k_gicomb(
    int t, const unsigned short* __restrict__ att_bf,
    const unsigned short* __restrict__ wf_att,
    const float* __restrict__ gi_x, const float* __restrict__ bfull,
    const float* __restrict__ ghf,
    float* __restrict__ hst, unsigned short* __restrict__ h_bf,
    unsigned short* __restrict__ outs_bf)
{
  __shared__ __align__(16) unsigned short As[64 * 32];        // 4 KB
  __shared__ __align__(16) unsigned short Bs[3][64 * 32];     // 12 KB
  __shared__ float gis[3][64 * 64];                           // 48 KB
  const int tid = threadIdx.x, j = blockIdx.x;
  const int g = tid >> 8;            // gate 0..2
  const int lt = tid & 255;
  const int srow = lt >> 2, soff = (lt & 3) * 8;
  const int lane = tid & 63, w = tid >> 6;
  const int ww = w & 3;
  const int fr = lane & 15, fq = lane >> 4;
  f32x4 acc[4] = {};
  const int c0 = g * 512 + j * 64;

  for (int k = 0; k < 1024; k += 32) {
    if (tid < 256)
      gload16(att_bf + (size_t)srow * 1024 + k + soff, As + lt * 8);
    gload16(wf_att + (size_t)(c0 + srow) * 1024 + k + soff, Bs[g] + lt * 8);
    __syncthreads();
    u16x8 af = *(const u16x8*)&As[(ww * 16 + fr) * 32 + fq * 8];
    #pragma unroll
    for (int nj = 0; nj < 4; nj++) {
      u16x8 bfv = *(const u16x8*)&Bs[g][(nj * 16 + fr) * 32 + fq * 8];
      acc[nj] = __builtin_amdgcn_mfma_f32_16x16x32_bf16(as_bf(af), as_bf(bfv), acc[nj], 0, 0, 0);
    }
    __syncthreads();
  }

  #pragma unroll
  for (int nj = 0; nj < 4; nj++) {
    #pragma unroll
    for (int jj = 0; jj < 4; jj++) {
      int row = ww * 16 + fq * 4 + jj;      // batch b
      int d64 = nj * 16 + fr;
      gis[g][row * 64 + d64] = acc[nj][jj]
          + gi_x[(size_t)(t * 64 + row) * 1536 + c0 + d64] + bfull[c0 + d64];
    }
  }
  __syncthreads();

  // GRU for d-slice [j*64, (j+1)*64) across all 64 b: 4096 outputs / 768 thr
  for (int e = tid; e < 4096; e += 768) {
    int b = e >> 6, d64 = e & 63, d = j * 64 + d64;
    float hv = gru1(gis[0][b * 64 + d64], gis[1][b * 64 + d64], gis[2][b * 64 + d64],
                    ghf[b * 1536 + d], ghf[b * 1536 + 512 + d], ghf[b * 1536 + 1024 + d],
                    hst[b * 512 + d]);
    hst[b * 512 + d] = hv;
    unsigned short bf = f2bf(hv);
    h_bf[b * 512 + d] = bf;
    outs_bf[(size_t)(t * 64 + b) * 512 + d] = bf;
  }
}

// ---------------------------------------------------------------------------
extern "C" void kernel_launch(void* const* d_in, const int* in_sizes, int n_in,
                              void* d_out, int out_size, void* d_ws, size_t ws_size,
                              hipStream_t stream) {
  const float* expl  = (const float*)d_in[0];
  const float* enc1  = (const float*)d_in[1];
  const float* enc2  = (const float*)d_in[2];
  const float* s1e   = (const float*)d_in[3];
  const float* s2e   = (const float*)d_in[4];
  const float* W_ctx = (const float*)d_in[5];
  const float* b_ctx = (const float*)d_in[6];
  const float* Wq1   = (const float*)d_in[7];
  const float* bq1   = (const float*)d_in[8];
  const float* Wk1   = (const float*)d_in[9];
  const float* bk1   = (const float*)d_in[10];
  const float* Wv1   = (const float*)d_in[11];
  const float* bv1   = (const float*)d_in[12];
  const float* Wq2   = (const float*)d_in[13];
  const float* bq2   = (const float*)d_in[14];
  const float* Wk2   = (const float*)d_in[15];
  const float* bk2   = (const float*)d_in[16];
  const float* Wv2   = (const float*)d_in[17];
  const float* bv2   = (const float*)d_in[18];
  const float* W_in  = (const float*)d_in[19];
  const float* b_in  = (const float*)d_in[20];
  const float* W_ih  = (const float*)d_in[21];
  const float* b_ih  = (const float*)d_in[22];
  const float* W_hh  = (const float*)d_in[23];
  const float* b_hh  = (const float*)d_in[24];
  const float* W_voc = (const float*)d_in[25];
  const float* b_voc = (const float*)d_in[26];
  float* out = (float*)d_out;

  char* ws = (char*)d_ws;
  unsigned short* keys1  = (unsigned short*)(ws + 0);          // [b*128+tt][512]
  unsigned short* vals1  = (unsigned short*)(ws + 8388608);
  unsigned short* keys2  = (unsigned short*)(ws + 16777216);
  unsigned short* vals2  = (unsigned short*)(ws + 25165824);
  unsigned short* encbf  = (unsigned short*)(ws + 33554432);   // 67.1 MB
  unsigned short* wkv    = (unsigned short*)(ws + 100663296);  // 8.4 MB
  unsigned short* wvoc   = (unsigned short*)(ws + 109051904);  // 32.8 MB
  unsigned short* wcat   = (unsigned short*)(ws + 141819904);  // [2560][512]
  unsigned short* wf_att = (unsigned short*)(ws + 144441344);  // [1536][1024]
  float*          wfx    = (float*)(ws + 147587072);
  float*          bfull  = (float*)(ws + 149430272);
  float*          gi_x   = (float*)(ws + 149436416);           // 12.6 MB
  unsigned short* ctx_bf = (unsigned short*)(ws + 162019328);
  float*          part   = (float*)(ws + 164116480);
  float*          hst    = (float*)(ws + 165165056);           // 128 KB
  unsigned short* h_bf   = (unsigned short*)(ws + 165296128);  // 64 KB
  float*          qf     = (float*)(ws + 165361664);           // 256 KB
  float*          ghf    = (float*)(ws + 165623808);           // 384 KB
  unsigned short* att_bf = (unsigned short*)(ws + 166410240);  // 128 KB
  unsigned short* outs_bf= (unsigned short*)(ws + 166541312);  // 2 MB
  // end ~168.6 MB

  auto cvt = [&](const float* s, unsigned short* d, int n) {
    k_cvt<<<(n + 1023) / 1024, 256, 0, stream>>>(s, d, n);
  };

  // ---- keys/vals side 1 ----
  cvt(enc1, encbf, 8192 * 4096);
  cvt(Wk1, wkv, 512 * 4096);
  cvt(Wv1, wkv + 512 * 4096, 512 * 4096);
  k_gemm_lds<0><<<dim3(64, 8), 256, 0, stream>>>(
      encbf, 4096, wkv, 4096, 4096, keys1, vals1, nullptr, 0, bk1, bv1);
  // ---- keys/vals side 2 ----
  cvt(enc2, encbf, 8192 * 4096);
  cvt(Wk2, wkv, 512 * 4096);
  cvt(Wv2, wkv + 512 * 4096, 512 * 4096);
  k_gemm_lds<0><<<dim3(64, 8), 256, 0, stream>>>(
      encbf, 4096, wkv, 4096, 4096, keys2, vals2, nullptr, 0, bk2, bv2);

  // ---- weight converts ----
  cvt(W_voc, wvoc, 32000 * 512);
  cvt(Wq1, wcat, 512 * 512);
  cvt(Wq2, wcat + 512 * 512, 512 * 512);
  cvt(W_hh, wcat + 1024 * 512, 1536 * 512);

  // ---- Wf fold + gi_x ----
  k_wf<<<dim3(192, 6), 256, 0, stream>>>(W_ih, W_in, wf_att, wfx);
  k_bfull<<<6, 256, 0, stream>>>(W_ih, b_in, b_ih, bfull);
  k_gix<<<dim3(128, 6), 256, 0, stream>>>(expl, wfx, gi_x);

  // ---- h0 ----
  k_build_ctx<<<4096, 256, 0, stream>>>(s1e, s2e, ctx_bf);
  k_gemm128<1, 0, 2><<<dim3(4, 1, 8), 256, 0, stream>>>(
      ctx_bf, 16384, W_ctx, 16384, 64, 512, 2048,
      nullptr, nullptr, part, nullptr, nullptr);
  k_reduce_h0<<<128, 256, 0, stream>>>(part, b_ctx, hst, h_bf);

  // ---- recurrence: 3 launches per step ----
  for (int t = 0; t < 32; t++) {
    k_mv64<0><<<40, 256, 0, stream>>>(h_bf, 512, wcat, 512,
                                      qf, ghf, bq1, bq2, b_hh, 0);
    k_att<<<128, 256, 0, stream>>>(qf, keys1, keys2, vals1, vals2, att_bf);
    k_gicomb<<<8, 768, 0, stream>>>(t, att_bf, wf_att, gi_x, bfull, ghf,
                                    hst, h_bf, outs_bf);
  }

  // ---- logits = outs @ W_voc^T + b_voc ----
  k_gemm_lds<1><<<dim3(16, 250), 256, 0, stream>>>(
      outs_bf, 512, wvoc, 512, 512, nullptr, nullptr, out, 32000, b_voc, nullptr);
}

// Round 12
// 1634.685 us; speedup vs baseline: 4.1840x; 1.4287x over previous
//
#include <hip/hip_runtime.h>

// ---------------------------------------------------------------------------
// AttentionDecoder. Laws:
//   R5: weights/state reads partitioned across blocks, never replicated.
//   R8: software grid barriers trash L2 -> never.
//   R9: LDS-staged MFMA (gload16) beats barrier-free direct-global MFMA.
//   R10/R11: keep >=24-block parallelism; launch saving (~6us) < exec loss
//            from fat fused kernels. Full-LDS-stage + 1 barrier is verified.
// R12 = R6 chain (4 launches/step) with single-barrier fully-staged matvecs:
//   S1 k_mv64f (40 blk): [q|gh] = h @ wcat^T; A+B fully staged, ONE barrier
//   S2 k_att  (128 blk): scores/softmax/att per (b,side)    [R6 verbatim]
//   S3 k_giK   (48 blk): gi partials, split-K (2x24), fully staged, ONE barrier
//   S4 k_gru2  (64 blk): gi = gip0+gip1+gi_x+bfull; GRU -> hst/h_bf/outs[t]
// ---------------------------------------------------------------------------

typedef float    f32x4 __attribute__((ext_vector_type(4)));
typedef __bf16   bf16x8 __attribute__((ext_vector_type(8)));
typedef unsigned short u16x8 __attribute__((ext_vector_type(8)));

#define DEV __device__ __forceinline__

DEV unsigned short f2bf(float f) {
  unsigned u = __builtin_bit_cast(unsigned, f);
  u += 0x7fffu + ((u >> 16) & 1u);
  return (unsigned short)(u >> 16);
}
DEV float bf2f(unsigned short h) {
  return __builtin_bit_cast(float, (unsigned)h << 16);
}
DEV bf16x8 as_bf(u16x8 v) { return __builtin_bit_cast(bf16x8, v); }
DEV u16x8 zero8() {
  u16x8 r = {0, 0, 0, 0, 0, 0, 0, 0};
  return r;
}
DEV u16x8 pack8(float4 a, float4 b) {
  u16x8 r;
  r[0]=f2bf(a.x); r[1]=f2bf(a.y); r[2]=f2bf(a.z); r[3]=f2bf(a.w);
  r[4]=f2bf(b.x); r[5]=f2bf(b.y); r[6]=f2bf(b.z); r[7]=f2bf(b.w);
  return r;
}
DEV void gload16(const void* g, void* l) {
  __builtin_amdgcn_global_load_lds(
      (const __attribute__((address_space(1))) void*)g,
      (__attribute__((address_space(3))) void*)l, 16, 0, 0);
}
DEV float gru1(float ir, float iz, float inn, float hr, float hz, float hn,
               float ho) {
  float r = 1.f / (1.f + expf(-(ir + hr)));
  float z = 1.f / (1.f + expf(-(iz + hz)));
  float n = tanhf(inn + r * hn);
  return (1.f - z) * n + z * ho;
}

// ------------------------------- converts ----------------------------------
__global__ __launch_bounds__(256) void k_cvt(const float* __restrict__ s,
                                             unsigned short* __restrict__ d, int n) {
  int i = (blockIdx.x * 256 + threadIdx.x) * 4;
  if (i + 4 <= n) {
    float4 v = *(const float4*)(s + i);
    d[i] = f2bf(v.x); d[i+1] = f2bf(v.y); d[i+2] = f2bf(v.z); d[i+3] = f2bf(v.w);
  } else {
    for (; i < n; i++) d[i] = f2bf(s[i]);
  }
}

// ctx_feat = [s1, s2, |s1-s2|, s1*s2]  -> bf16 [64, 16384]
__global__ __launch_bounds__(256) void k_build_ctx(const float* __restrict__ s1,
                                                   const float* __restrict__ s2,
                                                   unsigned short* __restrict__ ctx) {
  int j = blockIdx.x * 256 + threadIdx.x;
  int b = j >> 14, jj = j & 16383;
  int f = jj >> 12, k = jj & 4095;
  float a = s1[b * 4096 + k], c = s2[b * 4096 + k];
  float v = (f == 0) ? a : (f == 1) ? c : (f == 2) ? fabsf(a - c) : a * c;
  ctx[j] = f2bf(v);
}

// --------------- bf16 128x128 GEMM with global_load_lds staging -------------
// EPI 0: tanh(+bias), split col 512, PERMUTED rows (tt*64+b -> b*128+tt)
// EPI 1: +bias -> f32, ld ofld
template<int EPI>
__global__ __launch_bounds__(256) void k_gemm_lds(
    const unsigned short* __restrict__ A, int lda,
    const unsigned short* __restrict__ B, int ldb, int K,
    unsigned short* __restrict__ obf0, unsigned short* __restrict__ obf1,
    float* __restrict__ of, int ofld,
    const float* __restrict__ bias0, const float* __restrict__ bias1)
{
  __shared__ __align__(16) unsigned short As[128 * 32];
  __shared__ __align__(16) unsigned short Bs[128 * 32];
  const int tid = threadIdx.x;
  const int r0 = blockIdx.x * 128, c0 = blockIdx.y * 128;
  const int lane = tid & 63, w = tid >> 6;
  const int wr = w >> 1, wc = w & 1;
  const int fr = lane & 15, fq = lane >> 4;
  f32x4 acc[4][4] = {};

  const int srow = tid >> 2, scol = (tid & 3) * 8;
  const unsigned short* gA0 = A + (size_t)(r0 + srow) * lda + scol;
  const unsigned short* gA1 = A + (size_t)(r0 + 64 + srow) * lda + scol;
  const unsigned short* gB0 = B + (size_t)(c0 + srow) * ldb + scol;
  const unsigned short* gB1 = B + (size_t)(c0 + 64 + srow) * ldb + scol;
  unsigned short* lA0 = As + tid * 8;
  unsigned short* lA1 = As + 2048 + tid * 8;
  unsigned short* lB0 = Bs + tid * 8;
  unsigned short* lB1 = Bs + 2048 + tid * 8;

  for (int k = 0; k < K; k += 32) {
    gload16(gA0 + k, lA0);
    gload16(gA1 + k, lA1);
    gload16(gB0 + k, lB0);
    gload16(gB1 + k, lB1);
    __syncthreads();

    u16x8 af[4], bfv[4];
    #pragma unroll
    for (int mi = 0; mi < 4; mi++)
      af[mi] = *(const u16x8*)&As[(wr * 64 + mi * 16 + fr) * 32 + fq * 8];
    #pragma unroll
    for (int nj = 0; nj < 4; nj++)
      bfv[nj] = *(const u16x8*)&Bs[(wc * 64 + nj * 16 + fr) * 32 + fq * 8];
    #pragma unroll
    for (int mi = 0; mi < 4; mi++)
      #pragma unroll
      for (int nj = 0; nj < 4; nj++)
        acc[mi][nj] = __builtin_amdgcn_mfma_f32_16x16x32_bf16(
            as_bf(af[mi]), as_bf(bfv[nj]), acc[mi][nj], 0, 0, 0);
    __syncthreads();
  }

  #pragma unroll
  for (int mi = 0; mi < 4; mi++)
  #pragma unroll
  for (int nj = 0; nj < 4; nj++) {
    f32x4 a = acc[mi][nj];
    #pragma unroll
    for (int j = 0; j < 4; j++) {
      int grow = r0 + wr * 64 + mi * 16 + fq * 4 + j;
      int gcol = c0 + wc * 64 + nj * 16 + fr;
      float v = a[j];
      if constexpr (EPI == 0) {
        float bias = gcol < 512 ? bias0[gcol] : bias1[gcol - 512];
        unsigned short r = f2bf(tanhf(v + bias));
        int prow = ((grow & 63) << 7) | (grow >> 6);
        (gcol < 512 ? obf0 : obf1)[(size_t)prow * 512 + (gcol & 511)] = r;
      } else {
        of[(size_t)grow * ofld + gcol] = v + bias0[gcol];
      }
    }
  }
}

// ------------------------- generic 128x128 MFMA GEMM ------------------------
// (h0 only: A bf16, B f32, raw f32 partials via z split-K)
template<int A_BF16, int B_BF16, int EPI>
__global__ __launch_bounds__(256) void k_gemm128(
    const void* __restrict__ Ap, int lda, const void* __restrict__ Bp, int ldb,
    int M, int N, int kper,
    unsigned short* __restrict__ obf0, unsigned short* __restrict__ obf1,
    float* __restrict__ of, const float* __restrict__ bias0,
    const float* __restrict__ bias1)
{
  __shared__ __align__(16) unsigned short As[128 * 32];
  __shared__ __align__(16) unsigned short Bs[128 * 32];
  const int tid = threadIdx.x;
  const int c0 = blockIdx.x * 128, r0 = blockIdx.y * 128;
  const int k0 = blockIdx.z * kper;
  if (EPI == 2) of += (size_t)blockIdx.z * M * N;

  const int lane = tid & 63, w = tid >> 6;
  const int wr = w >> 1, wc = w & 1;
  const int fr = lane & 15, fq = lane >> 4;

  f32x4 acc[4][4] = {};

  const int srow = tid >> 1, shalf = (tid & 1) * 16;

  for (int k = k0; k < k0 + kper; k += 32) {
    u16x8 a0, a1, b0, b1;
    {
      int gr = r0 + srow;
      if (gr < M) {
        if (A_BF16) {
          const unsigned short* a = (const unsigned short*)Ap + (size_t)gr * lda + k + shalf;
          a0 = *(const u16x8*)a; a1 = *(const u16x8*)(a + 8);
        } else {
          const float* a = (const float*)Ap + (size_t)gr * lda + k + shalf;
          float4 f0 = ((const float4*)a)[0], f1 = ((const float4*)a)[1];
          float4 f2 = ((const float4*)a)[2], f3 = ((const float4*)a)[3];
          a0 = pack8(f0, f1); a1 = pack8(f2, f3);
        }
      } else { a0 = zero8(); a1 = zero8(); }
    }
    {
      int gr = c0 + srow;
      if (B_BF16) {
        const unsigned short* p = (const unsigned short*)Bp + (size_t)gr * ldb + k + shalf;
        b0 = *(const u16x8*)p; b1 = *(const u16x8*)(p + 8);
      } else {
        const float* p = (const float*)Bp + (size_t)gr * ldb + k + shalf;
        float4 f0 = ((const float4*)p)[0], f1 = ((const float4*)p)[1];
        float4 f2 = ((const float4*)p)[2], f3 = ((const float4*)p)[3];
        b0 = pack8(f0, f1); b1 = pack8(f2, f3);
      }
    }
    *(u16x8*)&As[srow * 32 + shalf]     = a0;
    *(u16x8*)&As[srow * 32 + shalf + 8] = a1;
    *(u16x8*)&Bs[srow * 32 + shalf]     = b0;
    *(u16x8*)&Bs[srow * 32 + shalf + 8] = b1;
    __syncthreads();

    u16x8 af[4], bfv[4];
    #pragma unroll
    for (int mi = 0; mi < 4; mi++)
      af[mi] = *(const u16x8*)&As[(wr * 64 + mi * 16 + fr) * 32 + fq * 8];
    #pragma unroll
    for (int nj = 0; nj < 4; nj++)
      bfv[nj] = *(const u16x8*)&Bs[(wc * 64 + nj * 16 + fr) * 32 + fq * 8];
    #pragma unroll
    for (int mi = 0; mi < 4; mi++)
      #pragma unroll
      for (int nj = 0; nj < 4; nj++)
        acc[mi][nj] = __builtin_amdgcn_mfma_f32_16x16x32_bf16(
            as_bf(af[mi]), as_bf(bfv[nj]), acc[mi][nj], 0, 0, 0);
    __syncthreads();
  }

  #pragma unroll
  for (int mi = 0; mi < 4; mi++)
  #pragma unroll
  for (int nj = 0; nj < 4; nj++) {
    f32x4 a = acc[mi][nj];
    #pragma unroll
    for (int j = 0; j < 4; j++) {
      int grow = r0 + wr * 64 + mi * 16 + fq * 4 + j;
      int gcol = c0 + wc * 64 + nj * 16 + fr;
      if (grow < M) {
        float v = a[j];
        if constexpr (EPI == 1) {
          of[(size_t)grow * N + gcol] = v + bias0[gcol];
        } else if constexpr (EPI == 2) {
          of[(size_t)grow * N + gcol] = v;
        }
      }
    }
  }
}

__global__ __launch_bounds__(256) void k_reduce_h0(const float* __restrict__ part,
                                                   const float* __restrict__ b_ctx,
                                                   float* __restrict__ h,
                                                   unsigned short* __restrict__ h_bf) {
  int j = blockIdx.x * 256 + threadIdx.x;   // < 64*512
  float s = b_ctx[j & 511];
  for (int z = 0; z < 8; z++) s += part[z * 32768 + j];
  h[j] = s;
  h_bf[j] = f2bf(s);
}

// ------------------- W_f = W_ih @ W_in  fold (one-time) ---------------------
__global__ __launch_bounds__(256) void k_wf(const float* __restrict__ W_ih,
                                            const float* __restrict__ W_in,
                                            unsigned short* __restrict__ wf_att,
                                            float* __restrict__ wfx) {
  __shared__ float wl[8][512];
  int ic = blockIdx.x, jc = blockIdx.y, tid = threadIdx.x;
  for (int x = tid; x < 8 * 512; x += 256)
    wl[x >> 9][x & 511] = W_ih[(ic * 8 + (x >> 9)) * 512 + (x & 511)];
  __syncthreads();
  int j = jc * 256 + tid;
  if (j >= 1324) return;
  float acc[8] = {};
  for (int d = 0; d < 512; d++) {
    float win = W_in[d * 1324 + j];
    #pragma unroll
    for (int r = 0; r < 8; r++) acc[r] += wl[r][d] * win;
  }
  for (int r = 0; r < 8; r++) {
    int i = ic * 8 + r;
    if (j < 300) wfx[i * 300 + j] = acc[r];
    else         wf_att[i * 1024 + (j - 300)] = f2bf(acc[r]);
  }
}

__global__ __launch_bounds__(256) void k_bfull(const float* __restrict__ W_ih,
                                               const float* __restrict__ b_in,
                                               const float* __restrict__ b_ih,
                                               float* __restrict__ bfull) {
  int i = blockIdx.x * 256 + threadIdx.x;
  if (i >= 1536) return;
  float acc = b_ih[i];
  for (int d = 0; d < 512; d++) acc += W_ih[i * 512 + d] * b_in[d];
  bfull[i] = acc;
}

// gi_x[t*64+b, :] = expl[t,b,:300] @ Wfx^T
__global__ __launch_bounds__(256) void k_gix(const float* __restrict__ expl,
                                             const float* __restrict__ wfx,
                                             float* __restrict__ gi_x) {
  __shared__ float el[16][300];
  int rc = blockIdx.x, ic = blockIdx.y, tid = threadIdx.x;
  for (int x = tid; x < 16 * 300; x += 256)
    el[x / 300][x % 300] = expl[(size_t)(rc * 16 + x / 300) * 300 + (x % 300)];
  __syncthreads();
  int c = ic * 256 + tid;
  float acc[16] = {};
  for (int k = 0; k < 300; k++) {
    float wv = wfx[c * 300 + k];
    #pragma unroll
    for (int r = 0; r < 16; r++) acc[r] += el[r][k] * wv;
  }
  for (int r = 0; r < 16; r++) gi_x[(size_t)(rc * 16 + r) * 1536 + c] = acc[r];
}

// ---- S1: [q|gh] matvec, A+B FULLY staged, ONE barrier (R10-verified layout)-
// 40 blocks x 256 thr. C[64,2560] = h_bf[64,512] @ wcat[2560,512]^T.
// 32 gload16 in flight per thread -> single vmcnt drain at the barrier.
__global__ __launch_bounds__(256) void k_mv64f(
    const unsigned short* __restrict__ A,      // h_bf [64][512]
    const unsigned short* __restrict__ B,      // wcat [2560][512]
    const float* __restrict__ bq1, const float* __restrict__ bq2,
    const float* __restrict__ b_hh,
    float* __restrict__ qf, float* __restrict__ ghf)
{
  __shared__ __align__(16) unsigned short AL[16 * 2048];   // [c][64][32] 64KB
  __shared__ __align__(16) unsigned short BL[16 * 2048];   // [c][64][32] 64KB
  const int tid = threadIdx.x;
  const int n0 = blockIdx.x * 64;
  const int srow = tid >> 2, scol = (tid & 3) * 8;

  #pragma unroll
  for (int c = 0; c < 16; c++) {
    gload16(A + (size_t)srow * 512 + c * 32 + scol, AL + c * 2048 + tid * 8);
    gload16(B + (size_t)(n0 + srow) * 512 + c * 32 + scol, BL + c * 2048 + tid * 8);
  }
  __syncthreads();

  const int lane = tid & 63, w = tid >> 6;
  const int fr = lane & 15, fq = lane >> 4;
  f32x4 acc[4] = {};
  #pragma unroll
  for (int c = 0; c < 16; c++) {
    u16x8 af = *(const u16x8*)(AL + c * 2048 + (w * 16 + fr) * 32 + fq * 8);
    #pragma unroll
    for (int nj = 0; nj < 4; nj++) {
      u16x8 bv = *(const u16x8*)(BL + c * 2048 + (nj * 16 + fr) * 32 + fq * 8);
      acc[nj] = __builtin_amdgcn_mfma_f32_16x16x32_bf16(as_bf(af), as_bf(bv), acc[nj], 0, 0, 0);
    }
  }
  #pragma unroll
  for (int nj = 0; nj < 4; nj++) {
    #pragma unroll
    for (int j = 0; j < 4; j++) {
      int row = w * 16 + fq * 4 + j;
      int col = n0 + nj * 16 + fr;
      float v = acc[nj][j];
      if (col < 512)       qf[(size_t)row * 1024 + col] = tanhf(v + bq1[col]);
      else if (col < 1024) qf[(size_t)row * 1024 + col] = tanhf(v + bq2[col - 512]);
      else                 ghf[(size_t)row * 1536 + (col - 1024)] = v + b_hh[col - 1024];
    }
  }
}

// ------------------- S2: attention (R6 verbatim) ----------------------------
__global__ __launch_bounds__(256) void k_att(
    const float* __restrict__ qf,
    const unsigned short* __restrict__ keys1, const unsigned short* __restrict__ keys2,
    const unsigned short* __restrict__ vals1, const unsigned short* __restrict__ vals2,
    unsigned short* __restrict__ att_bf)
{
  const int id = blockIdx.x, side = id >> 6, b = id & 63;
  const int tid = threadIdx.x;
  __shared__ float qv[512];
  __shared__ float sred[128][2];
  __shared__ float pr[128];

  for (int i = tid; i < 512; i += 256)
    qv[i] = qf[(size_t)b * 1024 + side * 512 + i];
  __syncthreads();

  const unsigned short* keys = side ? keys2 : keys1;
  {
    int tt = tid >> 1, half = tid & 1;
    const u16x8* krow = (const u16x8*)(keys + ((size_t)(b * 128 + tt)) * 512 + half * 256);
    float acc = 0.f;
    #pragma unroll 4
    for (int k8 = 0; k8 < 32; k8++) {
      u16x8 kv = krow[k8];
      #pragma unroll
      for (int jj = 0; jj < 8; jj++) acc += qv[half * 256 + k8 * 8 + jj] * bf2f(kv[jj]);
    }
    sred[tt][half] = acc;
  }
  __syncthreads();

  if (tid < 64) {
    float s0 = sred[tid][0] + sred[tid][1];
    float s1 = sred[tid + 64][0] + sred[tid + 64][1];
    float m = fmaxf(s0, s1);
    #pragma unroll
    for (int off = 32; off; off >>= 1) m = fmaxf(m, __shfl_xor(m, off));
    float e0 = __expf(s0 - m), e1 = __expf(s1 - m);
    float ss = e0 + e1;
    #pragma unroll
    for (int off = 32; off; off >>= 1) ss += __shfl_xor(ss, off);
    float inv = 1.f / ss;
    pr[tid] = e0 * inv;
    pr[tid + 64] = e1 * inv;
  }
  __syncthreads();

  const unsigned short* vals = side ? vals2 : vals1;
  {
    int a0 = tid * 2;
    float acc0 = 0.f, acc1 = 0.f;
    for (int tt = 0; tt < 128; tt++) {
      float p = pr[tt];
      unsigned v = *(const unsigned*)(vals + ((size_t)(b * 128 + tt)) * 512 + a0);
      acc0 += p * bf2f((unsigned short)(v & 0xffffu));
      acc1 += p * bf2f((unsigned short)(v >> 16));
    }
    att_bf[(size_t)b * 1024 + side * 512 + a0]     = f2bf(acc0);
    att_bf[(size_t)b * 1024 + side * 512 + a0 + 1] = f2bf(acc1);
  }
}

// ---- S3: gi partials, split-K (2 halves x 24 col-tiles), fully staged ------
// 48 blocks x 256 thr. gip[kh][64][1536] f32 raw (epilogue adds in k_gru2).
__global__ __launch_bounds__(256) void k_giK(
    const unsigned short* __restrict__ att_bf,   // [64][1024]
    const unsigned short* __restrict__ wf_att,   // [1536][1024]
    float* __restrict__ gip)
{
  __shared__ __align__(16) unsigned short AL[16 * 2048];   // 64KB
  __shared__ __align__(16) unsigned short BL[16 * 2048];   // 64KB
  const int tid = threadIdx.x;
  const int j = blockIdx.x % 24, kh = blockIdx.x / 24;
  const int n0 = j * 64, k0 = kh * 512;
  const int srow = tid >> 2, scol = (tid & 3) * 8;

  #pragma unroll
  for (int c = 0; c < 16; c++) {
    gload16(att_bf + (size_t)srow * 1024 + k0 + c * 32 + scol, AL + c * 2048 + tid * 8);
    gload16(wf_att + (size_t)(n0 + srow) * 1024 + k0 + c * 32 + scol, BL + c * 2048 + tid * 8);
  }
  __syncthreads();

  const int lane = tid & 63, w = tid >> 6;
  const int fr = lane & 15, fq = lane >> 4;
  f32x4 acc[4] = {};
  #pragma unroll
  for (int c = 0; c < 16; c++) {
    u16x8 af = *(const u16x8*)(AL + c * 2048 + (w * 16 + fr) * 32 + fq * 8);
    #pragma unroll
    for (int nj = 0; nj < 4; nj++) {
      u16x8 bv = *(const u16x8*)(BL + c * 2048 + (nj * 16 + fr) * 32 + fq * 8);
      acc[nj] = __builtin_amdgcn_mfma_f32_16x16x32_bf16(as_bf(af), as_bf(bv), acc[nj], 0, 0, 0);
    }
  }
  #pragma unroll
  for (int nj = 0; nj < 4; nj++) {
    #pragma unroll
    for (int jj = 0; jj < 4; jj++) {
      int row = w * 16 + fq * 4 + jj;
      int col = n0 + nj * 16 + fr;
      gip[(size_t)(kh * 64 + row) * 1536 + col] = acc[nj][jj];
    }
  }
}

// ---- S4: combine partials + GRU -> hst/h_bf/outs[t] ------------------------
__global__ __launch_bounds__(512) void k_gru2(
    int t, const float* __restrict__ gip, const float* __restrict__ gi_x,
    const float* __restrict__ bfull, const float* __restrict__ ghf,
    float* __restrict__ hst, unsigned short* __restrict__ h_bf,
    unsigned short* __restrict__ outs_bf)
{
  const int b = blockIdx.x, d = threadIdx.x;
  size_t gb = (size_t)(t * 64 + b) * 1536;
  float ir = gip[(size_t)b * 1536 + d] + gip[(size_t)(64 + b) * 1536 + d]
           + gi_x[gb + d] + bfull[d];
  float iz = gip[(size_t)b * 1536 + 512 + d] + gip[(size_t)(64 + b) * 1536 + 512 + d]
           + gi_x[gb + 512 + d] + bfull[512 + d];
  float inn = gip[(size_t)b * 1536 + 1024 + d] + gip[(size_t)(64 + b) * 1536 + 1024 + d]
           + gi_x[gb + 1024 + d] + bfull[1024 + d];
  float hv = gru1(ir, iz, inn,
                  ghf[b * 1536 + d], ghf[b * 1536 + 512 + d], ghf[b * 1536 + 1024 + d],
                  hst[b * 512 + d]);
  hst[b * 512 + d] = hv;
  unsigned short bf = f2bf(hv);
  h_bf[b * 512 + d] = bf;
  outs_bf[(size_t)(t * 64 + b) * 512 + d] = bf;
}

// ---------------------------------------------------------------------------
extern "C" void kernel_launch(void* const* d_in, const int* in_sizes, int n_in,
                              void* d_out, int out_size, void* d_ws, size_t ws_size,
                              hipStream_t stream) {
  const float* expl  = (const float*)d_in[0];
  const float* enc1  = (const float*)d_in[1];
  const float* enc2  = (const float*)d_in[2];
  const float* s1e   = (const float*)d_in[3];
  const float* s2e   = (const float*)d_in[4];
  const float* W_ctx = (const float*)d_in[5];
  const float* b_ctx = (const float*)d_in[6];
  const float* Wq1   = (const float*)d_in[7];
  const float* bq1   = (const float*)d_in[8];
  const float* Wk1   = (const float*)d_in[9];
  const float* bk1   = (const float*)d_in[10];
  const float* Wv1   = (const float*)d_in[11];
  const float* bv1   = (const float*)d_in[12];
  const float* Wq2   = (const float*)d_in[13];
  const float* bq2   = (const float*)d_in[14];
  const float* Wk2   = (const float*)d_in[15];
  const float* bk2   = (const float*)d_in[16];
  const float* Wv2   = (const float*)d_in[17];
  const float* bv2   = (const float*)d_in[18];
  const float* W_in  = (const float*)d_in[19];
  const float* b_in  = (const float*)d_in[20];
  const float* W_ih  = (const float*)d_in[21];
  const float* b_ih  = (const float*)d_in[22];
  const float* W_hh  = (const float*)d_in[23];
  const float* b_hh  = (const float*)d_in[24];
  const float* W_voc = (const float*)d_in[25];
  const float* b_voc = (const float*)d_in[26];
  float* out = (float*)d_out;

  char* ws = (char*)d_ws;
  unsigned short* keys1  = (unsigned short*)(ws + 0);          // [b*128+tt][512]
  unsigned short* vals1  = (unsigned short*)(ws + 8388608);
  unsigned short* keys2  = (unsigned short*)(ws + 16777216);
  unsigned short* vals2  = (unsigned short*)(ws + 25165824);
  unsigned short* encbf  = (unsigned short*)(ws + 33554432);   // 67.1 MB
  unsigned short* wkv    = (unsigned short*)(ws + 100663296);  // 8.4 MB
  unsigned short* wvoc   = (unsigned short*)(ws + 109051904);  // 32.8 MB
  unsigned short* wcat   = (unsigned short*)(ws + 141819904);  // [2560][512]
  unsigned short* wf_att = (unsigned short*)(ws + 144441344);  // [1536][1024]
  float*          wfx    = (float*)(ws + 147587072);
  float*          bfull  = (float*)(ws + 149430272);
  float*          gi_x   = (float*)(ws + 149436416);           // 12.6 MB
  unsigned short* ctx_bf = (unsigned short*)(ws + 162019328);
  float*          part   = (float*)(ws + 164116480);
  float*          hst    = (float*)(ws + 165165056);           // 128 KB
  unsigned short* h_bf   = (unsigned short*)(ws + 165296128);  // 64 KB
  float*          qf     = (float*)(ws + 165361664);           // 256 KB
  float*          ghf    = (float*)(ws + 165623808);           // 384 KB
  unsigned short* att_bf = (unsigned short*)(ws + 166410240);  // 128 KB
  unsigned short* outs_bf= (unsigned short*)(ws + 166541312);  // 2 MB
  float*          gip    = (float*)(ws + 168638464);           // 786 KB
  // end ~169.4 MB

  auto cvt = [&](const float* s, unsigned short* d, int n) {
    k_cvt<<<(n + 1023) / 1024, 256, 0, stream>>>(s, d, n);
  };

  // ---- keys/vals side 1 ----
  cvt(enc1, encbf, 8192 * 4096);
  cvt(Wk1, wkv, 512 * 4096);
  cvt(Wv1, wkv + 512 * 4096, 512 * 4096);
  k_gemm_lds<0><<<dim3(64, 8), 256, 0, stream>>>(
      encbf, 4096, wkv, 4096, 4096, keys1, vals1, nullptr, 0, bk1, bv1);
  // ---- keys/vals side 2 ----
  cvt(enc2, encbf, 8192 * 4096);
  cvt(Wk2, wkv, 512 * 4096);
  cvt(Wv2, wkv + 512 * 4096, 512 * 4096);
  k_gemm_lds<0><<<dim3(64, 8), 256, 0, stream>>>(
      encbf, 4096, wkv, 4096, 4096, keys2, vals2, nullptr, 0, bk2, bv2);

  // ---- weight converts ----
  cvt(W_voc, wvoc, 32000 * 512);
  cvt(Wq1, wcat, 512 * 512);
  cvt(Wq2, wcat + 512 * 512, 512 * 512);
  cvt(W_hh, wcat + 1024 * 512, 1536 * 512);

  // ---- Wf fold + gi_x ----
  k_wf<<<dim3(192, 6), 256, 0, stream>>>(W_ih, W_in, wf_att, wfx);
  k_bfull<<<6, 256, 0, stream>>>(W_ih, b_in, b_ih, bfull);
  k_gix<<<dim3(128, 6), 256, 0, stream>>>(expl, wfx, gi_x);

  // ---- h0 ----
  k_build_ctx<<<4096, 256, 0, stream>>>(s1e, s2e, ctx_bf);
  k_gemm128<1, 0, 2><<<dim3(4, 1, 8), 256, 0, stream>>>(
      ctx_bf, 16384, W_ctx, 16384, 64, 512, 2048,
      nullptr, nullptr, part, nullptr, nullptr);
  k_reduce_h0<<<128, 256, 0, stream>>>(part, b_ctx, hst, h_bf);

  // ---- recurrence: 4 launches per step (R6 chain, faster kernels) ----
  for (int t = 0; t < 32; t++) {
    k_mv64f<<<40, 256, 0, stream>>>(h_bf, wcat, bq1, bq2, b_hh, qf, ghf);
    k_att<<<128, 256, 0, stream>>>(qf, keys1, keys2, vals1, vals2, att_bf);
    k_giK<<<48, 256, 0, stream>>>(att_bf, wf_att, gip);
    k_gru2<<<64, 512, 0, stream>>>(t, gip, gi_x, bfull, ghf, hst, h_bf, outs_bf);
  }

  // ---- logits = outs @ W_voc^T + b_voc ----
  k_gemm_lds<1><<<dim3(16, 250), 256, 0, stream>>>(
      outs_bf, 512, wvoc, 512, 512, nullptr, nullptr, out, 32000, b_voc, nullptr);
}

// Round 13
// 1628.235 us; speedup vs baseline: 4.2005x; 1.0040x over previous
//
#include <hip/hip_runtime.h>

// ---------------------------------------------------------------------------
// AttentionDecoder. Laws:
//   R5: weights/state reads partitioned across blocks, never replicated.
//   R8: software grid barriers trash L2 -> never.
//   R9: LDS-staged MFMA (gload16) beats barrier-free direct-global MFMA.
//   R12: small matvecs: full LDS stage (all gload16 in flight) + ONE barrier.
// R13 = R12 recurrence (unchanged) + prologue/epilogue:
//   - ONE mega-convert kernel (all f32->bf16 segments, enc2 own buffer)
//   - fused kv GEMM (both sides, one 1024-block dispatch)
//   - vocab GEMM with in-kernel XCD remap (B-panel read once per chip)
// ---------------------------------------------------------------------------

typedef float    f32x4 __attribute__((ext_vector_type(4)));
typedef __bf16   bf16x8 __attribute__((ext_vector_type(8)));
typedef unsigned short u16x8 __attribute__((ext_vector_type(8)));

#define DEV __device__ __forceinline__

DEV unsigned short f2bf(float f) {
  unsigned u = __builtin_bit_cast(unsigned, f);
  u += 0x7fffu + ((u >> 16) & 1u);
  return (unsigned short)(u >> 16);
}
DEV float bf2f(unsigned short h) {
  return __builtin_bit_cast(float, (unsigned)h << 16);
}
DEV bf16x8 as_bf(u16x8 v) { return __builtin_bit_cast(bf16x8, v); }
DEV void gload16(const void* g, void* l) {
  __builtin_amdgcn_global_load_lds(
      (const __attribute__((address_space(1))) void*)g,
      (__attribute__((address_space(3))) void*)l, 16, 0, 0);
}
DEV float gru1(float ir, float iz, float inn, float hr, float hz, float hn,
               float ho) {
  float r = 1.f / (1.f + expf(-(ir + hr)));
  float z = 1.f / (1.f + expf(-(iz + hz)));
  float n = tanhf(inn + r * hn);
  return (1.f - z) * n + z * ho;
}

// ----------------------- mega convert (one launch) --------------------------
#define NSEG 10
struct CvtSegs {
  const float* src[NSEG];
  unsigned short* dst[NSEG];
  int cum4[NSEG + 1];   // cumulative quad counts
};

__global__ __launch_bounds__(256) void k_cvt_multi(CvtSegs segs, int total4) {
  int i4 = blockIdx.x * 256 + threadIdx.x;
  if (i4 >= total4) return;
  int s = 0;
  while (i4 >= segs.cum4[s + 1]) s++;
  int off = (i4 - segs.cum4[s]) * 4;
  float4 v = *(const float4*)(segs.src[s] + off);
  unsigned short* d = segs.dst[s] + off;
  d[0] = f2bf(v.x); d[1] = f2bf(v.y); d[2] = f2bf(v.z); d[3] = f2bf(v.w);
}

// ctx_feat = [s1, s2, |s1-s2|, s1*s2]  -> bf16 [64, 16384]
__global__ __launch_bounds__(256) void k_build_ctx(const float* __restrict__ s1,
                                                   const float* __restrict__ s2,
                                                   unsigned short* __restrict__ ctx) {
  int j = blockIdx.x * 256 + threadIdx.x;
  int b = j >> 14, jj = j & 16383;
  int f = jj >> 12, k = jj & 4095;
  float a = s1[b * 4096 + k], c = s2[b * 4096 + k];
  float v = (f == 0) ? a : (f == 1) ? c : (f == 2) ? fabsf(a - c) : a * c;
  ctx[j] = f2bf(v);
}

// ---------------- fused kv GEMM (both sides, one dispatch) ------------------
// grid (128, 8): x = side*64 + row-block, y = col-block. Same-A-panel blocks
// differ by 128 in linear id -> same XCD. EPI: tanh(+bias), split col 512,
// PERMUTED row store (tt*64+b -> b*128+tt).
__global__ __launch_bounds__(256) void k_gemm_kv(
    const unsigned short* __restrict__ enc1bf, const unsigned short* __restrict__ enc2bf,
    const unsigned short* __restrict__ wkv1, const unsigned short* __restrict__ wkv2,
    unsigned short* __restrict__ keys1, unsigned short* __restrict__ vals1,
    unsigned short* __restrict__ keys2, unsigned short* __restrict__ vals2,
    const float* __restrict__ bk1, const float* __restrict__ bv1,
    const float* __restrict__ bk2, const float* __restrict__ bv2)
{
  __shared__ __align__(16) unsigned short As[128 * 32];
  __shared__ __align__(16) unsigned short Bs[128 * 32];
  const int tid = threadIdx.x;
  const int side = blockIdx.x >> 6;
  const int r0 = (blockIdx.x & 63) * 128, c0 = blockIdx.y * 128;
  const unsigned short* A = side ? enc2bf : enc1bf;
  const unsigned short* B = side ? wkv2 : wkv1;
  unsigned short* kout = side ? keys2 : keys1;
  unsigned short* vout = side ? vals2 : vals1;
  const float* bk = side ? bk2 : bk1;
  const float* bv = side ? bv2 : bv1;

  const int lane = tid & 63, w = tid >> 6;
  const int wr = w >> 1, wc = w & 1;
  const int fr = lane & 15, fq = lane >> 4;
  f32x4 acc[4][4] = {};

  const int srow = tid >> 2, scol = (tid & 3) * 8;
  const unsigned short* gA0 = A + (size_t)(r0 + srow) * 4096 + scol;
  const unsigned short* gA1 = A + (size_t)(r0 + 64 + srow) * 4096 + scol;
  const unsigned short* gB0 = B + (size_t)(c0 + srow) * 4096 + scol;
  const unsigned short* gB1 = B + (size_t)(c0 + 64 + srow) * 4096 + scol;
  unsigned short* lA0 = As + tid * 8;
  unsigned short* lA1 = As + 2048 + tid * 8;
  unsigned short* lB0 = Bs + tid * 8;
  unsigned short* lB1 = Bs + 2048 + tid * 8;

  for (int k = 0; k < 4096; k += 32) {
    gload16(gA0 + k, lA0);
    gload16(gA1 + k, lA1);
    gload16(gB0 + k, lB0);
    gload16(gB1 + k, lB1);
    __syncthreads();

    u16x8 af[4], bfv[4];
    #pragma unroll
    for (int mi = 0; mi < 4; mi++)
      af[mi] = *(const u16x8*)&As[(wr * 64 + mi * 16 + fr) * 32 + fq * 8];
    #pragma unroll
    for (int nj = 0; nj < 4; nj++)
      bfv[nj] = *(const u16x8*)&Bs[(wc * 64 + nj * 16 + fr) * 32 + fq * 8];
    #pragma unroll
    for (int mi = 0; mi < 4; mi++)
      #pragma unroll
      for (int nj = 0; nj < 4; nj++)
        acc[mi][nj] = __builtin_amdgcn_mfma_f32_16x16x32_bf16(
            as_bf(af[mi]), as_bf(bfv[nj]), acc[mi][nj], 0, 0, 0);
    __syncthreads();
  }

  #pragma unroll
  for (int mi = 0; mi < 4; mi++)
  #pragma unroll
  for (int nj = 0; nj < 4; nj++) {
    f32x4 a = acc[mi][nj];
    #pragma unroll
    for (int j = 0; j < 4; j++) {
      int grow = r0 + wr * 64 + mi * 16 + fq * 4 + j;
      int gcol = c0 + wc * 64 + nj * 16 + fr;
      float bias = gcol < 512 ? bk[gcol] : bv[gcol - 512];
      unsigned short r = f2bf(tanhf(a[j] + bias));
      int prow = ((grow & 63) << 7) | (grow >> 6);
      (gcol < 512 ? kout : vout)[(size_t)prow * 512 + (gcol & 511)] = r;
    }
  }
}

// ---------------- vocab GEMM with in-kernel XCD remap -----------------------
// 4096 blocks: L&7 = target XCD, each XCD owns 32 col-blocks x 16 row-blocks.
// B-panel (W_voc cols) then lives on ONE XCD's L2 -> fetched once per chip.
__global__ __launch_bounds__(256) void k_gemm_voc(
    const unsigned short* __restrict__ A,       // outs_bf [2048][512]
    const unsigned short* __restrict__ B,       // wvoc [32000][512]
    float* __restrict__ of, const float* __restrict__ bias)
{
  const int L = blockIdx.x;
  const int xcd = L & 7, k = L >> 3;
  const int rb = k & 15, cb = xcd * 32 + (k >> 4);
  if (cb >= 250) return;
  const int r0 = rb * 128, c0 = cb * 128;

  __shared__ __align__(16) unsigned short As[128 * 32];
  __shared__ __align__(16) unsigned short Bs[128 * 32];
  const int tid = threadIdx.x;
  const int lane = tid & 63, w = tid >> 6;
  const int wr = w >> 1, wc = w & 1;
  const int fr = lane & 15, fq = lane >> 4;
  f32x4 acc[4][4] = {};

  const int srow = tid >> 2, scol = (tid & 3) * 8;
  const unsigned short* gA0 = A + (size_t)(r0 + srow) * 512 + scol;
  const unsigned short* gA1 = A + (size_t)(r0 + 64 + srow) * 512 + scol;
  const unsigned short* gB0 = B + (size_t)(c0 + srow) * 512 + scol;
  const unsigned short* gB1 = B + (size_t)(c0 + 64 + srow) * 512 + scol;
  unsigned short* lA0 = As + tid * 8;
  unsigned short* lA1 = As + 2048 + tid * 8;
  unsigned short* lB0 = Bs + tid * 8;
  unsigned short* lB1 = Bs + 2048 + tid * 8;

  for (int kk = 0; kk < 512; kk += 32) {
    gload16(gA0 + kk, lA0);
    gload16(gA1 + kk, lA1);
    gload16(gB0 + kk, lB0);
    gload16(gB1 + kk, lB1);
    __syncthreads();

    u16x8 af[4], bfv[4];
    #pragma unroll
    for (int mi = 0; mi < 4; mi++)
      af[mi] = *(const u16x8*)&As[(wr * 64 + mi * 16 + fr) * 32 + fq * 8];
    #pragma unroll
    for (int nj = 0; nj < 4; nj++)
      bfv[nj] = *(const u16x8*)&Bs[(wc * 64 + nj * 16 + fr) * 32 + fq * 8];
    #pragma unroll
    for (int mi = 0; mi < 4; mi++)
      #pragma unroll
      for (int nj = 0; nj < 4; nj++)
        acc[mi][nj] = __builtin_amdgcn_mfma_f32_16x16x32_bf16(
            as_bf(af[mi]), as_bf(bfv[nj]), acc[mi][nj], 0, 0, 0);
    __syncthreads();
  }

  #pragma unroll
  for (int mi = 0; mi < 4; mi++)
  #pragma unroll
  for (int nj = 0; nj < 4; nj++) {
    f32x4 a = acc[mi][nj];
    #pragma unroll
    for (int j = 0; j < 4; j++) {
      int grow = r0 + wr * 64 + mi * 16 + fq * 4 + j;
      int gcol = c0 + wc * 64 + nj * 16 + fr;
      of[(size_t)grow * 32000 + gcol] = a[j] + bias[gcol];
    }
  }
}

// ------------------------- generic 128x128 MFMA GEMM ------------------------
// (h0 only: A bf16, B f32, raw f32 partials via z split-K)
__global__ __launch_bounds__(256) void k_gemm_h0(
    const unsigned short* __restrict__ Ap, int lda, const float* __restrict__ Bp,
    int ldb, int M, int N, int kper, float* __restrict__ of)
{
  __shared__ __align__(16) unsigned short As[128 * 32];
  __shared__ __align__(16) unsigned short Bs[128 * 32];
  const int tid = threadIdx.x;
  const int c0 = blockIdx.x * 128, r0 = blockIdx.y * 128;
  const int k0 = blockIdx.z * kper;
  of += (size_t)blockIdx.z * M * N;

  const int lane = tid & 63, w = tid >> 6;
  const int wr = w >> 1, wc = w & 1;
  const int fr = lane & 15, fq = lane >> 4;
  f32x4 acc[4][4] = {};
  const int srow = tid >> 1, shalf = (tid & 1) * 16;

  for (int k = k0; k < k0 + kper; k += 32) {
    u16x8 a0, a1, b0, b1;
    {
      int gr = r0 + srow;
      if (gr < M) {
        const unsigned short* a = Ap + (size_t)gr * lda + k + shalf;
        a0 = *(const u16x8*)a; a1 = *(const u16x8*)(a + 8);
      } else {
        u16x8 z = {0,0,0,0,0,0,0,0}; a0 = z; a1 = z;
      }
    }
    {
      int gr = c0 + srow;
      const float* p = Bp + (size_t)gr * ldb + k + shalf;
      float4 f0 = ((const float4*)p)[0], f1 = ((const float4*)p)[1];
      float4 f2 = ((const float4*)p)[2], f3 = ((const float4*)p)[3];
      b0[0]=f2bf(f0.x); b0[1]=f2bf(f0.y); b0[2]=f2bf(f0.z); b0[3]=f2bf(f0.w);
      b0[4]=f2bf(f1.x); b0[5]=f2bf(f1.y); b0[6]=f2bf(f1.z); b0[7]=f2bf(f1.w);
      b1[0]=f2bf(f2.x); b1[1]=f2bf(f2.y); b1[2]=f2bf(f2.z); b1[3]=f2bf(f2.w);
      b1[4]=f2bf(f3.x); b1[5]=f2bf(f3.y); b1[6]=f2bf(f3.z); b1[7]=f2bf(f3.w);
    }
    *(u16x8*)&As[srow * 32 + shalf]     = a0;
    *(u16x8*)&As[srow * 32 + shalf + 8] = a1;
    *(u16x8*)&Bs[srow * 32 + shalf]     = b0;
    *(u16x8*)&Bs[srow * 32 + shalf + 8] = b1;
    __syncthreads();

    u16x8 af[4], bfv[4];
    #pragma unroll
    for (int mi = 0; mi < 4; mi++)
      af[mi] = *(const u16x8*)&As[(wr * 64 + mi * 16 + fr) * 32 + fq * 8];
    #pragma unroll
    for (int nj = 0; nj < 4; nj++)
      bfv[nj] = *(const u16x8*)&Bs[(wc * 64 + nj * 16 + fr) * 32 + fq * 8];
    #pragma unroll
    for (int mi = 0; mi < 4; mi++)
      #pragma unroll
      for (int nj = 0; nj < 4; nj++)
        acc[mi][nj] = __builtin_amdgcn_mfma_f32_16x16x32_bf16(
            as_bf(af[mi]), as_bf(bfv[nj]), acc[mi][nj], 0, 0, 0);
    __syncthreads();
  }

  #pragma unroll
  for (int mi = 0; mi < 4; mi++)
  #pragma unroll
  for (int nj = 0; nj < 4; nj++) {
    f32x4 a = acc[mi][nj];
    #pragma unroll
    for (int j = 0; j < 4; j++) {
      int grow = r0 + wr * 64 + mi * 16 + fq * 4 + j;
      int gcol = c0 + wc * 64 + nj * 16 + fr;
      if (grow < M) of[(size_t)grow * N + gcol] = a[j];
    }
  }
}

__global__ __launch_bounds__(256) void k_reduce_h0(const float* __restrict__ part,
                                                   const float* __restrict__ b_ctx,
                                                   float* __restrict__ h,
                                                   unsigned short* __restrict__ h_bf) {
  int j = blockIdx.x * 256 + threadIdx.x;   // < 64*512
  float s = b_ctx[j & 511];
  for (int z = 0; z < 8; z++) s += part[z * 32768 + j];
  h[j] = s;
  h_bf[j] = f2bf(s);
}

// ------------------- W_f = W_ih @ W_in  fold (one-time) ---------------------
__global__ __launch_bounds__(256) void k_wf(const float* __restrict__ W_ih,
                                            const float* __restrict__ W_in,
                                            unsigned short* __restrict__ wf_att,
                                            float* __restrict__ wfx) {
  __shared__ float wl[8][512];
  int ic = blockIdx.x, jc = blockIdx.y, tid = threadIdx.x;
  for (int x = tid; x < 8 * 512; x += 256)
    wl[x >> 9][x & 511] = W_ih[(ic * 8 + (x >> 9)) * 512 + (x & 511)];
  __syncthreads();
  int j = jc * 256 + tid;
  if (j >= 1324) return;
  float acc[8] = {};
  for (int d = 0; d < 512; d++) {
    float win = W_in[d * 1324 + j];
    #pragma unroll
    for (int r = 0; r < 8; r++) acc[r] += wl[r][d] * win;
  }
  for (int r = 0; r < 8; r++) {
    int i = ic * 8 + r;
    if (j < 300) wfx[i * 300 + j] = acc[r];
    else         wf_att[i * 1024 + (j - 300)] = f2bf(acc[r]);
  }
}

__global__ __launch_bounds__(256) void k_bfull(const float* __restrict__ W_ih,
                                               const float* __restrict__ b_in,
                                               const float* __restrict__ b_ih,
                                               float* __restrict__ bfull) {
  int i = blockIdx.x * 256 + threadIdx.x;
  if (i >= 1536) return;
  float acc = b_ih[i];
  for (int d = 0; d < 512; d++) acc += W_ih[i * 512 + d] * b_in[d];
  bfull[i] = acc;
}

// gi_x[t*64+b, :] = expl[t,b,:300] @ Wfx^T
__global__ __launch_bounds__(256) void k_gix(const float* __restrict__ expl,
                                             const float* __restrict__ wfx,
                                             float* __restrict__ gi_x) {
  __shared__ float el[16][300];
  int rc = blockIdx.x, ic = blockIdx.y, tid = threadIdx.x;
  for (int x = tid; x < 16 * 300; x += 256)
    el[x / 300][x % 300] = expl[(size_t)(rc * 16 + x / 300) * 300 + (x % 300)];
  __syncthreads();
  int c = ic * 256 + tid;
  float acc[16] = {};
  for (int k = 0; k < 300; k++) {
    float wv = wfx[c * 300 + k];
    #pragma unroll
    for (int r = 0; r < 16; r++) acc[r] += el[r][k] * wv;
  }
  for (int r = 0; r < 16; r++) gi_x[(size_t)(rc * 16 + r) * 1536 + c] = acc[r];
}

// ---- S1: [q|gh] matvec, A+B FULLY staged, ONE barrier (R12 verbatim) -------
__global__ __launch_bounds__(256) void k_mv64f(
    const unsigned short* __restrict__ A,      // h_bf [64][512]
    const unsigned short* __restrict__ B,      // wcat [2560][512]
    const float* __restrict__ bq1, const float* __restrict__ bq2,
    const float* __restrict__ b_hh,
    float* __restrict__ qf, float* __restrict__ ghf)
{
  __shared__ __align__(16) unsigned short AL[16 * 2048];   // 64KB
  __shared__ __align__(16) unsigned short BL[16 * 2048];   // 64KB
  const int tid = threadIdx.x;
  const int n0 = blockIdx.x * 64;
  const int srow = tid >> 2, scol = (tid & 3) * 8;

  #pragma unroll
  for (int c = 0; c < 16; c++) {
    gload16(A + (size_t)srow * 512 + c * 32 + scol, AL + c * 2048 + tid * 8);
    gload16(B + (size_t)(n0 + srow) * 512 + c * 32 + scol, BL + c * 2048 + tid * 8);
  }
  __syncthreads();

  const int lane = tid & 63, w = tid >> 6;
  const int fr = lane & 15, fq = lane >> 4;
  f32x4 acc[4] = {};
  #pragma unroll
  for (int c = 0; c < 16; c++) {
    u16x8 af = *(const u16x8*)(AL + c * 2048 + (w * 16 + fr) * 32 + fq * 8);
    #pragma unroll
    for (int nj = 0; nj < 4; nj++) {
      u16x8 bv = *(const u16x8*)(BL + c * 2048 + (nj * 16 + fr) * 32 + fq * 8);
      acc[nj] = __builtin_amdgcn_mfma_f32_16x16x32_bf16(as_bf(af), as_bf(bv), acc[nj], 0, 0, 0);
    }
  }
  #pragma unroll
  for (int nj = 0; nj < 4; nj++) {
    #pragma unroll
    for (int j = 0; j < 4; j++) {
      int row = w * 16 + fq * 4 + j;
      int col = n0 + nj * 16 + fr;
      float v = acc[nj][j];
      if (col < 512)       qf[(size_t)row * 1024 + col] = tanhf(v + bq1[col]);
      else if (col < 1024) qf[(size_t)row * 1024 + col] = tanhf(v + bq2[col - 512]);
      else                 ghf[(size_t)row * 1536 + (col - 1024)] = v + b_hh[col - 1024];
    }
  }
}

// ------------------- S2: attention (R6 verbatim) ----------------------------
__global__ __launch_bounds__(256) void k_att(
    const float* __restrict__ qf,
    const unsigned short* __restrict__ keys1, const unsigned short* __restrict__ keys2,
    const unsigned short* __restrict__ vals1, const unsigned short* __restrict__ vals2,
    unsigned short* __restrict__ att_bf)
{
  const int id = blockIdx.x, side = id >> 6, b = id & 63;
  const int tid = threadIdx.x;
  __shared__ float qv[512];
  __shared__ float sred[128][2];
  __shared__ float pr[128];

  for (int i = tid; i < 512; i += 256)
    qv[i] = qf[(size_t)b * 1024 + side * 512 + i];
  __syncthreads();

  const unsigned short* keys = side ? keys2 : keys1;
  {
    int tt = tid >> 1, half = tid & 1;
    const u16x8* krow = (const u16x8*)(keys + ((size_t)(b * 128 + tt)) * 512 + half * 256);
    float acc = 0.f;
    #pragma unroll 4
    for (int k8 = 0; k8 < 32; k8++) {
      u16x8 kv = krow[k8];
      #pragma unroll
      for (int jj = 0; jj < 8; jj++) acc += qv[half * 256 + k8 * 8 + jj] * bf2f(kv[jj]);
    }
    sred[tt][half] = acc;
  }
  __syncthreads();

  if (tid < 64) {
    float s0 = sred[tid][0] + sred[tid][1];
    float s1 = sred[tid + 64][0] + sred[tid + 64][1];
    float m = fmaxf(s0, s1);
    #pragma unroll
    for (int off = 32; off; off >>= 1) m = fmaxf(m, __shfl_xor(m, off));
    float e0 = __expf(s0 - m), e1 = __expf(s1 - m);
    float ss = e0 + e1;
    #pragma unroll
    for (int off = 32; off; off >>= 1) ss += __shfl_xor(ss, off);
    float inv = 1.f / ss;
    pr[tid] = e0 * inv;
    pr[tid + 64] = e1 * inv;
  }
  __syncthreads();

  const unsigned short* vals = side ? vals2 : vals1;
  {
    int a0 = tid * 2;
    float acc0 = 0.f, acc1 = 0.f;
    for (int tt = 0; tt < 128; tt++) {
      float p = pr[tt];
      unsigned v = *(const unsigned*)(vals + ((size_t)(b * 128 + tt)) * 512 + a0);
      acc0 += p * bf2f((unsigned short)(v & 0xffffu));
      acc1 += p * bf2f((unsigned short)(v >> 16));
    }
    att_bf[(size_t)b * 1024 + side * 512 + a0]     = f2bf(acc0);
    att_bf[(size_t)b * 1024 + side * 512 + a0 + 1] = f2bf(acc1);
  }
}

// ---- S3: gi partials, split-K (2x24), fully staged (R12 verbatim) ----------
__global__ __launch_bounds__(256) void k_giK(
    const unsigned short* __restrict__ att_bf,   // [64][1024]
    const unsigned short* __restrict__ wf_att,   // [1536][1024]
    float* __restrict__ gip)
{
  __shared__ __align__(16) unsigned short AL[16 * 2048];
  __shared__ __align__(16) unsigned short BL[16 * 2048];
  const int tid = threadIdx.x;
  const int j = blockIdx.x % 24, kh = blockIdx.x / 24;
  const int n0 = j * 64, k0 = kh * 512;
  const int srow = tid >> 2, scol = (tid & 3) * 8;

  #pragma unroll
  for (int c = 0; c < 16; c++) {
    gload16(att_bf + (size_t)srow * 1024 + k0 + c * 32 + scol, AL + c * 2048 + tid * 8);
    gload16(wf_att + (size_t)(n0 + srow) * 1024 + k0 + c * 32 + scol, BL + c * 2048 + tid * 8);
  }
  __syncthreads();

  const int lane = tid & 63, w = tid >> 6;
  const int fr = lane & 15, fq = lane >> 4;
  f32x4 acc[4] = {};
  #pragma unroll
  for (int c = 0; c < 16; c++) {
    u16x8 af = *(const u16x8*)(AL + c * 2048 + (w * 16 + fr) * 32 + fq * 8);
    #pragma unroll
    for (int nj = 0; nj < 4; nj++) {
      u16x8 bv = *(const u16x8*)(BL + c * 2048 + (nj * 16 + fr) * 32 + fq * 8);
      acc[nj] = __builtin_amdgcn_mfma_f32_16x16x32_bf16(as_bf(af), as_bf(bv), acc[nj], 0, 0, 0);
    }
  }
  #pragma unroll
  for (int nj = 0; nj < 4; nj++) {
    #pragma unroll
    for (int jj = 0; jj < 4; jj++) {
      int row = w * 16 + fq * 4 + jj;
      int col = n0 + nj * 16 + fr;
      gip[(size_t)(kh * 64 + row) * 1536 + col] = acc[nj][jj];
    }
  }
}

// ---- S4: combine partials + GRU (R12 verbatim) -----------------------------
__global__ __launch_bounds__(512) void k_gru2(
    int t, const float* __restrict__ gip, const float* __restrict__ gi_x,
    const float* __restrict__ bfull, const float* __restrict__ ghf,
    float* __restrict__ hst, unsigned short* __restrict__ h_bf,
    unsigned short* __restrict__ outs_bf)
{
  const int b = blockIdx.x, d = threadIdx.x;
  size_t gb = (size_t)(t * 64 + b) * 1536;
  float ir = gip[(size_t)b * 1536 + d] + gip[(size_t)(64 + b) * 1536 + d]
           + gi_x[gb + d] + bfull[d];
  float iz = gip[(size_t)b * 1536 + 512 + d] + gip[(size_t)(64 + b) * 1536 + 512 + d]
           + gi_x[gb + 512 + d] + bfull[512 + d];
  float inn = gip[(size_t)b * 1536 + 1024 + d] + gip[(size_t)(64 + b) * 1536 + 1024 + d]
           + gi_x[gb + 1024 + d] + bfull[1024 + d];
  float hv = gru1(ir, iz, inn,
                  ghf[b * 1536 + d], ghf[b * 1536 + 512 + d], ghf[b * 1536 + 1024 + d],
                  hst[b * 512 + d]);
  hst[b * 512 + d] = hv;
  unsigned short bf = f2bf(hv);
  h_bf[b * 512 + d] = bf;
  outs_bf[(size_t)(t * 64 + b) * 512 + d] = bf;
}

// ---------------------------------------------------------------------------
extern "C" void kernel_launch(void* const* d_in, const int* in_sizes, int n_in,
                              void* d_out, int out_size, void* d_ws, size_t ws_size,
                              hipStream_t stream) {
  const float* expl  = (const float*)d_in[0];
  const float* enc1  = (const float*)d_in[1];
  const float* enc2  = (const float*)d_in[2];
  const float* s1e   = (const float*)d_in[3];
  const float* s2e   = (const float*)d_in[4];
  const float* W_ctx = (const float*)d_in[5];
  const float* b_ctx = (const float*)d_in[6];
  const float* Wq1   = (const float*)d_in[7];
  const float* bq1   = (const float*)d_in[8];
  const float* Wk1   = (const float*)d_in[9];
  const float* bk1   = (const float*)d_in[10];
  const float* Wv1   = (const float*)d_in[11];
  const float* bv1   = (const float*)d_in[12];
  const float* Wq2   = (const float*)d_in[13];
  const float* bq2   = (const float*)d_in[14];
  const float* Wk2   = (const float*)d_in[15];
  const float* bk2   = (const float*)d_in[16];
  const float* Wv2   = (const float*)d_in[17];
  const float* bv2   = (const float*)d_in[18];
  const float* W_in  = (const float*)d_in[19];
  const float* b_in  = (const float*)d_in[20];
  const float* W_ih  = (const float*)d_in[21];
  const float* b_ih  = (const float*)d_in[22];
  const float* W_hh  = (const float*)d_in[23];
  const float* b_hh  = (const float*)d_in[24];
  const float* W_voc = (const float*)d_in[25];
  const float* b_voc = (const float*)d_in[26];
  float* out = (float*)d_out;

  char* ws = (char*)d_ws;
  unsigned short* keys1  = (unsigned short*)(ws + 0);
  unsigned short* vals1  = (unsigned short*)(ws + 8388608);
  unsigned short* keys2  = (unsigned short*)(ws + 16777216);
  unsigned short* vals2  = (unsigned short*)(ws + 25165824);
  unsigned short* encbf1 = (unsigned short*)(ws + 33554432);   // 67.1 MB
  unsigned short* encbf2 = (unsigned short*)(ws + 100663296);  // 67.1 MB
  unsigned short* wkv1   = (unsigned short*)(ws + 167772160);  // 8.4 MB
  unsigned short* wkv2   = (unsigned short*)(ws + 176160768);  // 8.4 MB
  unsigned short* wvoc   = (unsigned short*)(ws + 184549376);  // 32.8 MB
  unsigned short* wcat   = (unsigned short*)(ws + 217317376);  // [2560][512]
  unsigned short* wf_att = (unsigned short*)(ws + 219938816);  // [1536][1024]
  float*          wfx    = (float*)(ws + 223084544);
  float*          bfull  = (float*)(ws + 224927744);
  float*          gi_x   = (float*)(ws + 224933888);           // 12.6 MB
  unsigned short* ctx_bf = (unsigned short*)(ws + 237516800);
  float*          part   = (float*)(ws + 239613952);
  float*          hst    = (float*)(ws + 240662528);
  unsigned short* h_bf   = (unsigned short*)(ws + 240793600);
  float*          qf     = (float*)(ws + 240859136);
  float*          ghf    = (float*)(ws + 241121280);
  unsigned short* att_bf = (unsigned short*)(ws + 241514496);
  unsigned short* outs_bf= (unsigned short*)(ws + 241645568);
  float*          gip    = (float*)(ws + 243742720);
  // end ~244.5 MB

  // ---- ONE mega-convert for every f32->bf16 segment ----
  {
    CvtSegs segs;
    const float* srcs[NSEG] = { enc1, enc2, Wk1, Wv1, Wk2, Wv2, W_voc,
                                Wq1, Wq2, W_hh };
    unsigned short* dsts[NSEG] = { encbf1, encbf2, wkv1, wkv1 + 512*4096,
                                   wkv2, wkv2 + 512*4096, wvoc,
                                   wcat, wcat + 512*512, wcat + 1024*512 };
    int ns[NSEG] = { 8192*4096, 8192*4096, 512*4096, 512*4096, 512*4096,
                     512*4096, 32000*512, 512*512, 512*512, 1536*512 };
    int cum = 0;
    for (int s = 0; s < NSEG; s++) {
      segs.src[s] = srcs[s]; segs.dst[s] = dsts[s];
      segs.cum4[s] = cum; cum += ns[s] / 4;
    }
    segs.cum4[NSEG] = cum;
    k_cvt_multi<<<(cum + 255) / 256, 256, 0, stream>>>(segs, cum);
  }

  // ---- fused kv GEMM (both sides, one dispatch) ----
  k_gemm_kv<<<dim3(128, 8), 256, 0, stream>>>(
      encbf1, encbf2, wkv1, wkv2, keys1, vals1, keys2, vals2,
      bk1, bv1, bk2, bv2);

  // ---- Wf fold + gi_x ----
  k_wf<<<dim3(192, 6), 256, 0, stream>>>(W_ih, W_in, wf_att, wfx);
  k_bfull<<<6, 256, 0, stream>>>(W_ih, b_in, b_ih, bfull);
  k_gix<<<dim3(128, 6), 256, 0, stream>>>(expl, wfx, gi_x);

  // ---- h0 ----
  k_build_ctx<<<4096, 256, 0, stream>>>(s1e, s2e, ctx_bf);
  k_gemm_h0<<<dim3(4, 1, 8), 256, 0, stream>>>(
      ctx_bf, 16384, W_ctx, 16384, 64, 512, 2048, part);
  k_reduce_h0<<<128, 256, 0, stream>>>(part, b_ctx, hst, h_bf);

  // ---- recurrence: 4 launches per step (R12 verbatim) ----
  for (int t = 0; t < 32; t++) {
    k_mv64f<<<40, 256, 0, stream>>>(h_bf, wcat, bq1, bq2, b_hh, qf, ghf);
    k_att<<<128, 256, 0, stream>>>(qf, keys1, keys2, vals1, vals2, att_bf);
    k_giK<<<48, 256, 0, stream>>>(att_bf, wf_att, gip);
    k_gru2<<<64, 512, 0, stream>>>(t, gip, gi_x, bfull, ghf, hst, h_bf, outs_bf);
  }

  // ---- logits = outs @ W_voc^T + b_voc (XCD-remapped) ----
  k_gemm_voc<<<4096, 256, 0, stream>>>(outs_bf, wvoc, out, b_voc);
}

// Round 14
// 1622.361 us; speedup vs baseline: 4.2157x; 1.0036x over previous
//
#include <hip/hip_runtime.h>

// ---------------------------------------------------------------------------
// AttentionDecoder. Laws:
//   R5: weights/state reads partitioned across blocks, never replicated.
//   R8: software grid barriers trash L2 -> never.
//   R9: LDS-staged MFMA (gload16) beats barrier-free direct-global MFMA.
//   R12: small matvecs: full LDS stage (all gload16 in flight) + ONE barrier.
//   R13: kv GEMM is barrier/latency-bound (128 iters x 2 barriers).
// R14 = R13 with BK=64 double-chunk staging in kv + vocab GEMMs
//   (halves barrier-drain count; 8 gload16 in flight per round).
// ---------------------------------------------------------------------------

typedef float    f32x4 __attribute__((ext_vector_type(4)));
typedef __bf16   bf16x8 __attribute__((ext_vector_type(8)));
typedef unsigned short u16x8 __attribute__((ext_vector_type(8)));

#define DEV __device__ __forceinline__

DEV unsigned short f2bf(float f) {
  unsigned u = __builtin_bit_cast(unsigned, f);
  u += 0x7fffu + ((u >> 16) & 1u);
  return (unsigned short)(u >> 16);
}
DEV float bf2f(unsigned short h) {
  return __builtin_bit_cast(float, (unsigned)h << 16);
}
DEV bf16x8 as_bf(u16x8 v) { return __builtin_bit_cast(bf16x8, v); }
DEV void gload16(const void* g, void* l) {
  __builtin_amdgcn_global_load_lds(
      (const __attribute__((address_space(1))) void*)g,
      (__attribute__((address_space(3))) void*)l, 16, 0, 0);
}
DEV float gru1(float ir, float iz, float inn, float hr, float hz, float hn,
               float ho) {
  float r = 1.f / (1.f + expf(-(ir + hr)));
  float z = 1.f / (1.f + expf(-(iz + hz)));
  float n = tanhf(inn + r * hn);
  return (1.f - z) * n + z * ho;
}

// ----------------------- mega convert (one launch) --------------------------
#define NSEG 10
struct CvtSegs {
  const float* src[NSEG];
  unsigned short* dst[NSEG];
  int cum4[NSEG + 1];   // cumulative quad counts
};

__global__ __launch_bounds__(256) void k_cvt_multi(CvtSegs segs, int total4) {
  int i4 = blockIdx.x * 256 + threadIdx.x;
  if (i4 >= total4) return;
  int s = 0;
  while (i4 >= segs.cum4[s + 1]) s++;
  int off = (i4 - segs.cum4[s]) * 4;
  float4 v = *(const float4*)(segs.src[s] + off);
  unsigned short* d = segs.dst[s] + off;
  d[0] = f2bf(v.x); d[1] = f2bf(v.y); d[2] = f2bf(v.z); d[3] = f2bf(v.w);
}

// ctx_feat = [s1, s2, |s1-s2|, s1*s2]  -> bf16 [64, 16384]
__global__ __launch_bounds__(256) void k_build_ctx(const float* __restrict__ s1,
                                                   const float* __restrict__ s2,
                                                   unsigned short* __restrict__ ctx) {
  int j = blockIdx.x * 256 + threadIdx.x;
  int b = j >> 14, jj = j & 16383;
  int f = jj >> 12, k = jj & 4095;
  float a = s1[b * 4096 + k], c = s2[b * 4096 + k];
  float v = (f == 0) ? a : (f == 1) ? c : (f == 2) ? fabsf(a - c) : a * c;
  ctx[j] = f2bf(v);
}

// ---------------- fused kv GEMM, BK=64 double-chunk -------------------------
// grid (128, 8): x = side*64 + row-block, y = col-block. EPI: tanh(+bias),
// split col 512, PERMUTED row store (tt*64+b -> b*128+tt).
__global__ __launch_bounds__(256) void k_gemm_kv(
    const unsigned short* __restrict__ enc1bf, const unsigned short* __restrict__ enc2bf,
    const unsigned short* __restrict__ wkv1, const unsigned short* __restrict__ wkv2,
    unsigned short* __restrict__ keys1, unsigned short* __restrict__ vals1,
    unsigned short* __restrict__ keys2, unsigned short* __restrict__ vals2,
    const float* __restrict__ bk1, const float* __restrict__ bv1,
    const float* __restrict__ bk2, const float* __restrict__ bv2)
{
  __shared__ __align__(16) unsigned short As[2][128 * 32];
  __shared__ __align__(16) unsigned short Bs[2][128 * 32];
  const int tid = threadIdx.x;
  const int side = blockIdx.x >> 6;
  const int r0 = (blockIdx.x & 63) * 128, c0 = blockIdx.y * 128;
  const unsigned short* A = side ? enc2bf : enc1bf;
  const unsigned short* B = side ? wkv2 : wkv1;
  unsigned short* kout = side ? keys2 : keys1;
  unsigned short* vout = side ? vals2 : vals1;
  const float* bk = side ? bk2 : bk1;
  const float* bv = side ? bv2 : bv1;

  const int lane = tid & 63, w = tid >> 6;
  const int wr = w >> 1, wc = w & 1;
  const int fr = lane & 15, fq = lane >> 4;
  f32x4 acc[4][4] = {};

  const int srow = tid >> 2, scol = (tid & 3) * 8;
  const unsigned short* gA0 = A + (size_t)(r0 + srow) * 4096 + scol;
  const unsigned short* gA1 = A + (size_t)(r0 + 64 + srow) * 4096 + scol;
  const unsigned short* gB0 = B + (size_t)(c0 + srow) * 4096 + scol;
  const unsigned short* gB1 = B + (size_t)(c0 + 64 + srow) * 4096 + scol;

  for (int k = 0; k < 4096; k += 64) {
    #pragma unroll
    for (int c = 0; c < 2; c++) {
      gload16(gA0 + k + c * 32, As[c] + tid * 8);
      gload16(gA1 + k + c * 32, As[c] + 2048 + tid * 8);
      gload16(gB0 + k + c * 32, Bs[c] + tid * 8);
      gload16(gB1 + k + c * 32, Bs[c] + 2048 + tid * 8);
    }
    __syncthreads();

    #pragma unroll
    for (int c = 0; c < 2; c++) {
      u16x8 af[4], bfv[4];
      #pragma unroll
      for (int mi = 0; mi < 4; mi++)
        af[mi] = *(const u16x8*)&As[c][(wr * 64 + mi * 16 + fr) * 32 + fq * 8];
      #pragma unroll
      for (int nj = 0; nj < 4; nj++)
        bfv[nj] = *(const u16x8*)&Bs[c][(wc * 64 + nj * 16 + fr) * 32 + fq * 8];
      #pragma unroll
      for (int mi = 0; mi < 4; mi++)
        #pragma unroll
        for (int nj = 0; nj < 4; nj++)
          acc[mi][nj] = __builtin_amdgcn_mfma_f32_16x16x32_bf16(
              as_bf(af[mi]), as_bf(bfv[nj]), acc[mi][nj], 0, 0, 0);
    }
    __syncthreads();
  }

  #pragma unroll
  for (int mi = 0; mi < 4; mi++)
  #pragma unroll
  for (int nj = 0; nj < 4; nj++) {
    f32x4 a = acc[mi][nj];
    #pragma unroll
    for (int j = 0; j < 4; j++) {
      int grow = r0 + wr * 64 + mi * 16 + fq * 4 + j;
      int gcol = c0 + wc * 64 + nj * 16 + fr;
      float bias = gcol < 512 ? bk[gcol] : bv[gcol - 512];
      unsigned short r = f2bf(tanhf(a[j] + bias));
      int prow = ((grow & 63) << 7) | (grow >> 6);
      (gcol < 512 ? kout : vout)[(size_t)prow * 512 + (gcol & 511)] = r;
    }
  }
}

// ---------------- vocab GEMM, XCD remap + BK=64 double-chunk ----------------
__global__ __launch_bounds__(256) void k_gemm_voc(
    const unsigned short* __restrict__ A,       // outs_bf [2048][512]
    const unsigned short* __restrict__ B,       // wvoc [32000][512]
    float* __restrict__ of, const float* __restrict__ bias)
{
  const int L = blockIdx.x;
  const int xcd = L & 7, k = L >> 3;
  const int rb = k & 15, cb = xcd * 32 + (k >> 4);
  if (cb >= 250) return;
  const int r0 = rb * 128, c0 = cb * 128;

  __shared__ __align__(16) unsigned short As[2][128 * 32];
  __shared__ __align__(16) unsigned short Bs[2][128 * 32];
  const int tid = threadIdx.x;
  const int lane = tid & 63, w = tid >> 6;
  const int wr = w >> 1, wc = w & 1;
  const int fr = lane & 15, fq = lane >> 4;
  f32x4 acc[4][4] = {};

  const int srow = tid >> 2, scol = (tid & 3) * 8;
  const unsigned short* gA0 = A + (size_t)(r0 + srow) * 512 + scol;
  const unsigned short* gA1 = A + (size_t)(r0 + 64 + srow) * 512 + scol;
  const unsigned short* gB0 = B + (size_t)(c0 + srow) * 512 + scol;
  const unsigned short* gB1 = B + (size_t)(c0 + 64 + srow) * 512 + scol;

  for (int kk = 0; kk < 512; kk += 64) {
    #pragma unroll
    for (int c = 0; c < 2; c++) {
      gload16(gA0 + kk + c * 32, As[c] + tid * 8);
      gload16(gA1 + kk + c * 32, As[c] + 2048 + tid * 8);
      gload16(gB0 + kk + c * 32, Bs[c] + tid * 8);
      gload16(gB1 + kk + c * 32, Bs[c] + 2048 + tid * 8);
    }
    __syncthreads();

    #pragma unroll
    for (int c = 0; c < 2; c++) {
      u16x8 af[4], bfv[4];
      #pragma unroll
      for (int mi = 0; mi < 4; mi++)
        af[mi] = *(const u16x8*)&As[c][(wr * 64 + mi * 16 + fr) * 32 + fq * 8];
      #pragma unroll
      for (int nj = 0; nj < 4; nj++)
        bfv[nj] = *(const u16x8*)&Bs[c][(wc * 64 + nj * 16 + fr) * 32 + fq * 8];
      #pragma unroll
      for (int mi = 0; mi < 4; mi++)
        #pragma unroll
        for (int nj = 0; nj < 4; nj++)
          acc[mi][nj] = __builtin_amdgcn_mfma_f32_16x16x32_bf16(
              as_bf(af[mi]), as_bf(bfv[nj]), acc[mi][nj], 0, 0, 0);
    }
    __syncthreads();
  }

  #pragma unroll
  for (int mi = 0; mi < 4; mi++)
  #pragma unroll
  for (int nj = 0; nj < 4; nj++) {
    f32x4 a = acc[mi][nj];
    #pragma unroll
    for (int j = 0; j < 4; j++) {
      int grow = r0 + wr * 64 + mi * 16 + fq * 4 + j;
      int gcol = c0 + wc * 64 + nj * 16 + fr;
      of[(size_t)grow * 32000 + gcol] = a[j] + bias[gcol];
    }
  }
}

// ------------------------- h0 GEMM (A bf16, B f32) --------------------------
__global__ __launch_bounds__(256) void k_gemm_h0(
    const unsigned short* __restrict__ Ap, int lda, const float* __restrict__ Bp,
    int ldb, int M, int N, int kper, float* __restrict__ of)
{
  __shared__ __align__(16) unsigned short As[128 * 32];
  __shared__ __align__(16) unsigned short Bs[128 * 32];
  const int tid = threadIdx.x;
  const int c0 = blockIdx.x * 128, r0 = blockIdx.y * 128;
  const int k0 = blockIdx.z * kper;
  of += (size_t)blockIdx.z * M * N;

  const int lane = tid & 63, w = tid >> 6;
  const int wr = w >> 1, wc = w & 1;
  const int fr = lane & 15, fq = lane >> 4;
  f32x4 acc[4][4] = {};
  const int srow = tid >> 1, shalf = (tid & 1) * 16;

  for (int k = k0; k < k0 + kper; k += 32) {
    u16x8 a0, a1, b0, b1;
    {
      int gr = r0 + srow;
      if (gr < M) {
        const unsigned short* a = Ap + (size_t)gr * lda + k + shalf;
        a0 = *(const u16x8*)a; a1 = *(const u16x8*)(a + 8);
      } else {
        u16x8 z = {0,0,0,0,0,0,0,0}; a0 = z; a1 = z;
      }
    }
    {
      int gr = c0 + srow;
      const float* p = Bp + (size_t)gr * ldb + k + shalf;
      float4 f0 = ((const float4*)p)[0], f1 = ((const float4*)p)[1];
      float4 f2 = ((const float4*)p)[2], f3 = ((const float4*)p)[3];
      b0[0]=f2bf(f0.x); b0[1]=f2bf(f0.y); b0[2]=f2bf(f0.z); b0[3]=f2bf(f0.w);
      b0[4]=f2bf(f1.x); b0[5]=f2bf(f1.y); b0[6]=f2bf(f1.z); b0[7]=f2bf(f1.w);
      b1[0]=f2bf(f2.x); b1[1]=f2bf(f2.y); b1[2]=f2bf(f2.z); b1[3]=f2bf(f2.w);
      b1[4]=f2bf(f3.x); b1[5]=f2bf(f3.y); b1[6]=f2bf(f3.z); b1[7]=f2bf(f3.w);
    }
    *(u16x8*)&As[srow * 32 + shalf]     = a0;
    *(u16x8*)&As[srow * 32 + shalf + 8] = a1;
    *(u16x8*)&Bs[srow * 32 + shalf]     = b0;
    *(u16x8*)&Bs[srow * 32 + shalf + 8] = b1;
    __syncthreads();

    u16x8 af[4], bfv[4];
    #pragma unroll
    for (int mi = 0; mi < 4; mi++)
      af[mi] = *(const u16x8*)&As[(wr * 64 + mi * 16 + fr) * 32 + fq * 8];
    #pragma unroll
    for (int nj = 0; nj < 4; nj++)
      bfv[nj] = *(const u16x8*)&Bs[(wc * 64 + nj * 16 + fr) * 32 + fq * 8];
    #pragma unroll
    for (int mi = 0; mi < 4; mi++)
      #pragma unroll
      for (int nj = 0; nj < 4; nj++)
        acc[mi][nj] = __builtin_amdgcn_mfma_f32_16x16x32_bf16(
            as_bf(af[mi]), as_bf(bfv[nj]), acc[mi][nj], 0, 0, 0);
    __syncthreads();
  }

  #pragma unroll
  for (int mi = 0; mi < 4; mi++)
  #pragma unroll
  for (int nj = 0; nj < 4; nj++) {
    f32x4 a = acc[mi][nj];
    #pragma unroll
    for (int j = 0; j < 4; j++) {
      int grow = r0 + wr * 64 + mi * 16 + fq * 4 + j;
      int gcol = c0 + wc * 64 + nj * 16 + fr;
      if (grow < M) of[(size_t)grow * N + gcol] = a[j];
    }
  }
}

__global__ __launch_bounds__(256) void k_reduce_h0(const float* __restrict__ part,
                                                   const float* __restrict__ b_ctx,
                                                   float* __restrict__ h,
                                                   unsigned short* __restrict__ h_bf) {
  int j = blockIdx.x * 256 + threadIdx.x;   // < 64*512
  float s = b_ctx[j & 511];
  for (int z = 0; z < 8; z++) s += part[z * 32768 + j];
  h[j] = s;
  h_bf[j] = f2bf(s);
}

// ------------------- W_f = W_ih @ W_in  fold (one-time) ---------------------
__global__ __launch_bounds__(256) void k_wf(const float* __restrict__ W_ih,
                                            const float* __restrict__ W_in,
                                            unsigned short* __restrict__ wf_att,
                                            float* __restrict__ wfx) {
  __shared__ float wl[8][512];
  int ic = blockIdx.x, jc = blockIdx.y, tid = threadIdx.x;
  for (int x = tid; x < 8 * 512; x += 256)
    wl[x >> 9][x & 511] = W_ih[(ic * 8 + (x >> 9)) * 512 + (x & 511)];
  __syncthreads();
  int j = jc * 256 + tid;
  if (j >= 1324) return;
  float acc[8] = {};
  for (int d = 0; d < 512; d++) {
    float win = W_in[d * 1324 + j];
    #pragma unroll
    for (int r = 0; r < 8; r++) acc[r] += wl[r][d] * win;
  }
  for (int r = 0; r < 8; r++) {
    int i = ic * 8 + r;
    if (j < 300) wfx[i * 300 + j] = acc[r];
    else         wf_att[i * 1024 + (j - 300)] = f2bf(acc[r]);
  }
}

__global__ __launch_bounds__(256) void k_bfull(const float* __restrict__ W_ih,
                                               const float* __restrict__ b_in,
                                               const float* __restrict__ b_ih,
                                               float* __restrict__ bfull) {
  int i = blockIdx.x * 256 + threadIdx.x;
  if (i >= 1536) return;
  float acc = b_ih[i];
  for (int d = 0; d < 512; d++) acc += W_ih[i * 512 + d] * b_in[d];
  bfull[i] = acc;
}

// gi_x[t*64+b, :] = expl[t,b,:300] @ Wfx^T
__global__ __launch_bounds__(256) void k_gix(const float* __restrict__ expl,
                                             const float* __restrict__ wfx,
                                             float* __restrict__ gi_x) {
  __shared__ float el[16][300];
  int rc = blockIdx.x, ic = blockIdx.y, tid = threadIdx.x;
  for (int x = tid; x < 16 * 300; x += 256)
    el[x / 300][x % 300] = expl[(size_t)(rc * 16 + x / 300) * 300 + (x % 300)];
  __syncthreads();
  int c = ic * 256 + tid;
  float acc[16] = {};
  for (int k = 0; k < 300; k++) {
    float wv = wfx[c * 300 + k];
    #pragma unroll
    for (int r = 0; r < 16; r++) acc[r] += el[r][k] * wv;
  }
  for (int r = 0; r < 16; r++) gi_x[(size_t)(rc * 16 + r) * 1536 + c] = acc[r];
}

// ---- S1: [q|gh] matvec, A+B FULLY staged, ONE barrier (R12 verbatim) -------
__global__ __launch_bounds__(256) void k_mv64f(
    const unsigned short* __restrict__ A,      // h_bf [64][512]
    const unsigned short* __restrict__ B,      // wcat [2560][512]
    const float* __restrict__ bq1, const float* __restrict__ bq2,
    const float* __restrict__ b_hh,
    float* __restrict__ qf, float* __restrict__ ghf)
{
  __shared__ __align__(16) unsigned short AL[16 * 2048];   // 64KB
  __shared__ __align__(16) unsigned short BL[16 * 2048];   // 64KB
  const int tid = threadIdx.x;
  const int n0 = blockIdx.x * 64;
  const int srow = tid >> 2, scol = (tid & 3) * 8;

  #pragma unroll
  for (int c = 0; c < 16; c++) {
    gload16(A + (size_t)srow * 512 + c * 32 + scol, AL + c * 2048 + tid * 8);
    gload16(B + (size_t)(n0 + srow) * 512 + c * 32 + scol, BL + c * 2048 + tid * 8);
  }
  __syncthreads();

  const int lane = tid & 63, w = tid >> 6;
  const int fr = lane & 15, fq = lane >> 4;
  f32x4 acc[4] = {};
  #pragma unroll
  for (int c = 0; c < 16; c++) {
    u16x8 af = *(const u16x8*)(AL + c * 2048 + (w * 16 + fr) * 32 + fq * 8);
    #pragma unroll
    for (int nj = 0; nj < 4; nj++) {
      u16x8 bv = *(const u16x8*)(BL + c * 2048 + (nj * 16 + fr) * 32 + fq * 8);
      acc[nj] = __builtin_amdgcn_mfma_f32_16x16x32_bf16(as_bf(af), as_bf(bv), acc[nj], 0, 0, 0);
    }
  }
  #pragma unroll
  for (int nj = 0; nj < 4; nj++) {
    #pragma unroll
    for (int j = 0; j < 4; j++) {
      int row = w * 16 + fq * 4 + j;
      int col = n0 + nj * 16 + fr;
      float v = acc[nj][j];
      if (col < 512)       qf[(size_t)row * 1024 + col] = tanhf(v + bq1[col]);
      else if (col < 1024) qf[(size_t)row * 1024 + col] = tanhf(v + bq2[col - 512]);
      else                 ghf[(size_t)row * 1536 + (col - 1024)] = v + b_hh[col - 1024];
    }
  }
}

// ------------------- S2: attention (R6 verbatim) ----------------------------
__global__ __launch_bounds__(256) void k_att(
    const float* __restrict__ qf,
    const unsigned short* __restrict__ keys1, const unsigned short* __restrict__ keys2,
    const unsigned short* __restrict__ vals1, const unsigned short* __restrict__ vals2,
    unsigned short* __restrict__ att_bf)
{
  const int id = blockIdx.x, side = id >> 6, b = id & 63;
  const int tid = threadIdx.x;
  __shared__ float qv[512];
  __shared__ float sred[128][2];
  __shared__ float pr[128];

  for (int i = tid; i < 512; i += 256)
    qv[i] = qf[(size_t)b * 1024 + side * 512 + i];
  __syncthreads();

  const unsigned short* keys = side ? keys2 : keys1;
  {
    int tt = tid >> 1, half = tid & 1;
    const u16x8* krow = (const u16x8*)(keys + ((size_t)(b * 128 + tt)) * 512 + half * 256);
    float acc = 0.f;
    #pragma unroll 4
    for (int k8 = 0; k8 < 32; k8++) {
      u16x8 kv = krow[k8];
      #pragma unroll
      for (int jj = 0; jj < 8; jj++) acc += qv[half * 256 + k8 * 8 + jj] * bf2f(kv[jj]);
    }
    sred[tt][half] = acc;
  }
  __syncthreads();

  if (tid < 64) {
    float s0 = sred[tid][0] + sred[tid][1];
    float s1 = sred[tid + 64][0] + sred[tid + 64][1];
    float m = fmaxf(s0, s1);
    #pragma unroll
    for (int off = 32; off; off >>= 1) m = fmaxf(m, __shfl_xor(m, off));
    float e0 = __expf(s0 - m), e1 = __expf(s1 - m);
    float ss = e0 + e1;
    #pragma unroll
    for (int off = 32; off; off >>= 1) ss += __shfl_xor(ss, off);
    float inv = 1.f / ss;
    pr[tid] = e0 * inv;
    pr[tid + 64] = e1 * inv;
  }
  __syncthreads();

  const unsigned short* vals = side ? vals2 : vals1;
  {
    int a0 = tid * 2;
    float acc0 = 0.f, acc1 = 0.f;
    for (int tt = 0; tt < 128; tt++) {
      float p = pr[tt];
      unsigned v = *(const unsigned*)(vals + ((size_t)(b * 128 + tt)) * 512 + a0);
      acc0 += p * bf2f((unsigned short)(v & 0xffffu));
      acc1 += p * bf2f((unsigned short)(v >> 16));
    }
    att_bf[(size_t)b * 1024 + side * 512 + a0]     = f2bf(acc0);
    att_bf[(size_t)b * 1024 + side * 512 + a0 + 1] = f2bf(acc1);
  }
}

// ---- S3: gi partials, split-K (2x24), fully staged (R12 verbatim) ----------
__global__ __launch_bounds__(256) void k_giK(
    const unsigned short* __restrict__ att_bf,   // [64][1024]
    const unsigned short* __restrict__ wf_att,   // [1536][1024]
    float* __restrict__ gip)
{
  __shared__ __align__(16) unsigned short AL[16 * 2048];
  __shared__ __align__(16) unsigned short BL[16 * 2048];
  const int tid = threadIdx.x;
  const int j = blockIdx.x % 24, kh = blockIdx.x / 24;
  const int n0 = j * 64, k0 = kh * 512;
  const int srow = tid >> 2, scol = (tid & 3) * 8;

  #pragma unroll
  for (int c = 0; c < 16; c++) {
    gload16(att_bf + (size_t)srow * 1024 + k0 + c * 32 + scol, AL + c * 2048 + tid * 8);
    gload16(wf_att + (size_t)(n0 + srow) * 1024 + k0 + c * 32 + scol, BL + c * 2048 + tid * 8);
  }
  __syncthreads();

  const int lane = tid & 63, w = tid >> 6;
  const int fr = lane & 15, fq = lane >> 4;
  f32x4 acc[4] = {};
  #pragma unroll
  for (int c = 0; c < 16; c++) {
    u16x8 af = *(const u16x8*)(AL + c * 2048 + (w * 16 + fr) * 32 + fq * 8);
    #pragma unroll
    for (int nj = 0; nj < 4; nj++) {
      u16x8 bv = *(const u16x8*)(BL + c * 2048 + (nj * 16 + fr) * 32 + fq * 8);
      acc[nj] = __builtin_amdgcn_mfma_f32_16x16x32_bf16(as_bf(af), as_bf(bv), acc[nj], 0, 0, 0);
    }
  }
  #pragma unroll
  for (int nj = 0; nj < 4; nj++) {
    #pragma unroll
    for (int jj = 0; jj < 4; jj++) {
      int row = w * 16 + fq * 4 + jj;
      int col = n0 + nj * 16 + fr;
      gip[(size_t)(kh * 64 + row) * 1536 + col] = acc[nj][jj];
    }
  }
}

// ---- S4: combine partials + GRU (R12 verbatim) -----------------------------
__global__ __launch_bounds__(512) void k_gru2(
    int t, const float* __restrict__ gip, const float* __restrict__ gi_x,
    const float* __restrict__ bfull, const float* __restrict__ ghf,
    float* __restrict__ hst, unsigned short* __restrict__ h_bf,
    unsigned short* __restrict__ outs_bf)
{
  const int b = blockIdx.x, d = threadIdx.x;
  size_t gb = (size_t)(t * 64 + b) * 1536;
  float ir = gip[(size_t)b * 1536 + d] + gip[(size_t)(64 + b) * 1536 + d]
           + gi_x[gb + d] + bfull[d];
  float iz = gip[(size_t)b * 1536 + 512 + d] + gip[(size_t)(64 + b) * 1536 + 512 + d]
           + gi_x[gb + 512 + d] + bfull[512 + d];
  float inn = gip[(size_t)b * 1536 + 1024 + d] + gip[(size_t)(64 + b) * 1536 + 1024 + d]
           + gi_x[gb + 1024 + d] + bfull[1024 + d];
  float hv = gru1(ir, iz, inn,
                  ghf[b * 1536 + d], ghf[b * 1536 + 512 + d], ghf[b * 1536 + 1024 + d],
                  hst[b * 512 + d]);
  hst[b * 512 + d] = hv;
  unsigned short bf = f2bf(hv);
  h_bf[b * 512 + d] = bf;
  outs_bf[(size_t)(t * 64 + b) * 512 + d] = bf;
}

// ---------------------------------------------------------------------------
extern "C" void kernel_launch(void* const* d_in, const int* in_sizes, int n_in,
                              void* d_out, int out_size, void* d_ws, size_t ws_size,
                              hipStream_t stream) {
  const float* expl  = (const float*)d_in[0];
  const float* enc1  = (const float*)d_in[1];
  const float* enc2  = (const float*)d_in[2];
  const float* s1e   = (const float*)d_in[3];
  const float* s2e   = (const float*)d_in[4];
  const float* W_ctx = (const float*)d_in[5];
  const float* b_ctx = (const float*)d_in[6];
  const float* Wq1   = (const float*)d_in[7];
  const float* bq1   = (const float*)d_in[8];
  const float* Wk1   = (const float*)d_in[9];
  const float* bk1   = (const float*)d_in[10];
  const float* Wv1   = (const float*)d_in[11];
  const float* bv1   = (const float*)d_in[12];
  const float* Wq2   = (const float*)d_in[13];
  const float* bq2   = (const float*)d_in[14];
  const float* Wk2   = (const float*)d_in[15];
  const float* bk2   = (const float*)d_in[16];
  const float* Wv2   = (const float*)d_in[17];
  const float* bv2   = (const float*)d_in[18];
  const float* W_in  = (const float*)d_in[19];
  const float* b_in  = (const float*)d_in[20];
  const float* W_ih  = (const float*)d_in[21];
  const float* b_ih  = (const float*)d_in[22];
  const float* W_hh  = (const float*)d_in[23];
  const float* b_hh  = (const float*)d_in[24];
  const float* W_voc = (const float*)d_in[25];
  const float* b_voc = (const float*)d_in[26];
  float* out = (float*)d_out;

  char* ws = (char*)d_ws;
  unsigned short* keys1  = (unsigned short*)(ws + 0);
  unsigned short* vals1  = (unsigned short*)(ws + 8388608);
  unsigned short* keys2  = (unsigned short*)(ws + 16777216);
  unsigned short* vals2  = (unsigned short*)(ws + 25165824);
  unsigned short* encbf1 = (unsigned short*)(ws + 33554432);   // 67.1 MB
  unsigned short* encbf2 = (unsigned short*)(ws + 100663296);  // 67.1 MB
  unsigned short* wkv1   = (unsigned short*)(ws + 167772160);  // 8.4 MB
  unsigned short* wkv2   = (unsigned short*)(ws + 176160768);  // 8.4 MB
  unsigned short* wvoc   = (unsigned short*)(ws + 184549376);  // 32.8 MB
  unsigned short* wcat   = (unsigned short*)(ws + 217317376);  // [2560][512]
  unsigned short* wf_att = (unsigned short*)(ws + 219938816);  // [1536][1024]
  float*          wfx    = (float*)(ws + 223084544);
  float*          bfull  = (float*)(ws + 224927744);
  float*          gi_x   = (float*)(ws + 224933888);           // 12.6 MB
  unsigned short* ctx_bf = (unsigned short*)(ws + 237516800);
  float*          part   = (float*)(ws + 239613952);
  float*          hst    = (float*)(ws + 240662528);
  unsigned short* h_bf   = (unsigned short*)(ws + 240793600);
  float*          qf     = (float*)(ws + 240859136);
  float*          ghf    = (float*)(ws + 241121280);
  unsigned short* att_bf = (unsigned short*)(ws + 241514496);
  unsigned short* outs_bf= (unsigned short*)(ws + 241645568);
  float*          gip    = (float*)(ws + 243742720);
  // end ~244.5 MB

  // ---- ONE mega-convert for every f32->bf16 segment ----
  {
    CvtSegs segs;
    const float* srcs[NSEG] = { enc1, enc2, Wk1, Wv1, Wk2, Wv2, W_voc,
                                Wq1, Wq2, W_hh };
    unsigned short* dsts[NSEG] = { encbf1, encbf2, wkv1, wkv1 + 512*4096,
                                   wkv2, wkv2 + 512*4096, wvoc,
                                   wcat, wcat + 512*512, wcat + 1024*512 };
    int ns[NSEG] = { 8192*4096, 8192*4096, 512*4096, 512*4096, 512*4096,
                     512*4096, 32000*512, 512*512, 512*512, 1536*512 };
    int cum = 0;
    for (int s = 0; s < NSEG; s++) {
      segs.src[s] = srcs[s]; segs.dst[s] = dsts[s];
      segs.cum4[s] = cum; cum += ns[s] / 4;
    }
    segs.cum4[NSEG] = cum;
    k_cvt_multi<<<(cum + 255) / 256, 256, 0, stream>>>(segs, cum);
  }

  // ---- fused kv GEMM (both sides, one dispatch, BK=64) ----
  k_gemm_kv<<<dim3(128, 8), 256, 0, stream>>>(
      encbf1, encbf2, wkv1, wkv2, keys1, vals1, keys2, vals2,
      bk1, bv1, bk2, bv2);

  // ---- Wf fold + gi_x ----
  k_wf<<<dim3(192, 6), 256, 0, stream>>>(W_ih, W_in, wf_att, wfx);
  k_bfull<<<6, 256, 0, stream>>>(W_ih, b_in, b_ih, bfull);
  k_gix<<<dim3(128, 6), 256, 0, stream>>>(expl, wfx, gi_x);

  // ---- h0 ----
  k_build_ctx<<<4096, 256, 0, stream>>>(s1e, s2e, ctx_bf);
  k_gemm_h0<<<dim3(4, 1, 8), 256, 0, stream>>>(
      ctx_bf, 16384, W_ctx, 16384, 64, 512, 2048, part);
  k_reduce_h0<<<128, 256, 0, stream>>>(part, b_ctx, hst, h_bf);

  // ---- recurrence: 4 launches per step (R12 verbatim) ----
  for (int t = 0; t < 32; t++) {
    k_mv64f<<<40, 256, 0, stream>>>(h_bf, wcat, bq1, bq2, b_hh, qf, ghf);
    k_att<<<128, 256, 0, stream>>>(qf, keys1, keys2, vals1, vals2, att_bf);
    k_giK<<<48, 256, 0, stream>>>(att_bf, wf_att, gip);
    k_gru2<<<64, 512, 0, stream>>>(t, gip, gi_x, bfull, ghf, hst, h_bf, outs_bf);
  }

  // ---- logits = outs @ W_voc^T + b_voc (XCD-remapped, BK=64) ----
  k_gemm_voc<<<4096, 256, 0, stream>>>(outs_bf, wvoc, out, b_voc);
}

// Round 15
// 1614.254 us; speedup vs baseline: 4.2369x; 1.0050x over previous
//
#include <hip/hip_runtime.h>

// ---------------------------------------------------------------------------
// AttentionDecoder. Laws:
//   R5: weights/state reads partitioned across blocks, never replicated.
//   R8: software grid barriers trash L2 -> never.
//   R9: LDS-staged MFMA (gload16) beats barrier-free direct-global MFMA.
//   R12: small matvecs: full LDS stage (all gload16 in flight) + ONE barrier.
//   R14: BK=64 double-chunk halves barrier drains (kv 238->201us).
// R15: LDS bank-conflict fix (8-way -> 2-way) via BOTH-sides swizzle:
//   gload16 dest is linear -> swizzle per-lane GLOBAL source slot
//   (slot ^= (srow>>1)&3) and apply the same XOR on fragment reads
//   (fq' = fq ^ ((row>>1)&3)). slot = (row&1)*4 + fq' is bijective over
//   8 consecutive rows -> 2 lanes/16B-slot = conflict-free.
// ---------------------------------------------------------------------------

typedef float    f32x4 __attribute__((ext_vector_type(4)));
typedef __bf16   bf16x8 __attribute__((ext_vector_type(8)));
typedef unsigned short u16x8 __attribute__((ext_vector_type(8)));

#define DEV __device__ __forceinline__

DEV unsigned short f2bf(float f) {
  unsigned u = __builtin_bit_cast(unsigned, f);
  u += 0x7fffu + ((u >> 16) & 1u);
  return (unsigned short)(u >> 16);
}
DEV float bf2f(unsigned short h) {
  return __builtin_bit_cast(float, (unsigned)h << 16);
}
DEV bf16x8 as_bf(u16x8 v) { return __builtin_bit_cast(bf16x8, v); }
DEV void gload16(const void* g, void* l) {
  __builtin_amdgcn_global_load_lds(
      (const __attribute__((address_space(1))) void*)g,
      (__attribute__((address_space(3))) void*)l, 16, 0, 0);
}
DEV float gru1(float ir, float iz, float inn, float hr, float hz, float hn,
               float ho) {
  float r = 1.f / (1.f + expf(-(ir + hr)));
  float z = 1.f / (1.f + expf(-(iz + hz)));
  float n = tanhf(inn + r * hn);
  return (1.f - z) * n + z * ho;
}
// swizzled read offset within a [row][32]-elem chunk: row*32 + (fq^((row>>1)&3))*8
DEV int rdswz(int row, int fq) {
  return row * 32 + ((fq ^ ((row >> 1) & 3)) << 3);
}

// ----------------------- mega convert (one launch) --------------------------
#define NSEG 10
struct CvtSegs {
  const float* src[NSEG];
  unsigned short* dst[NSEG];
  int cum4[NSEG + 1];   // cumulative quad counts
};

__global__ __launch_bounds__(256) void k_cvt_multi(CvtSegs segs, int total4) {
  int i4 = blockIdx.x * 256 + threadIdx.x;
  if (i4 >= total4) return;
  int s = 0;
  while (i4 >= segs.cum4[s + 1]) s++;
  int off = (i4 - segs.cum4[s]) * 4;
  float4 v = *(const float4*)(segs.src[s] + off);
  unsigned short* d = segs.dst[s] + off;
  d[0] = f2bf(v.x); d[1] = f2bf(v.y); d[2] = f2bf(v.z); d[3] = f2bf(v.w);
}

// ctx_feat = [s1, s2, |s1-s2|, s1*s2]  -> bf16 [64, 16384]
__global__ __launch_bounds__(256) void k_build_ctx(const float* __restrict__ s1,
                                                   const float* __restrict__ s2,
                                                   unsigned short* __restrict__ ctx) {
  int j = blockIdx.x * 256 + threadIdx.x;
  int b = j >> 14, jj = j & 16383;
  int f = jj >> 12, k = jj & 4095;
  float a = s1[b * 4096 + k], c = s2[b * 4096 + k];
  float v = (f == 0) ? a : (f == 1) ? c : (f == 2) ? fabsf(a - c) : a * c;
  ctx[j] = f2bf(v);
}

// ---------------- fused kv GEMM, BK=64 + swizzle ----------------------------
// grid (128, 8): x = side*64 + row-block, y = col-block. EPI: tanh(+bias),
// split col 512, PERMUTED row store (tt*64+b -> b*128+tt).
__global__ __launch_bounds__(256) void k_gemm_kv(
    const unsigned short* __restrict__ enc1bf, const unsigned short* __restrict__ enc2bf,
    const unsigned short* __restrict__ wkv1, const unsigned short* __restrict__ wkv2,
    unsigned short* __restrict__ keys1, unsigned short* __restrict__ vals1,
    unsigned short* __restrict__ keys2, unsigned short* __restrict__ vals2,
    const float* __restrict__ bk1, const float* __restrict__ bv1,
    const float* __restrict__ bk2, const float* __restrict__ bv2)
{
  __shared__ __align__(16) unsigned short As[2][128 * 32];
  __shared__ __align__(16) unsigned short Bs[2][128 * 32];
  const int tid = threadIdx.x;
  const int side = blockIdx.x >> 6;
  const int r0 = (blockIdx.x & 63) * 128, c0 = blockIdx.y * 128;
  const unsigned short* A = side ? enc2bf : enc1bf;
  const unsigned short* B = side ? wkv2 : wkv1;
  unsigned short* kout = side ? keys2 : keys1;
  unsigned short* vout = side ? vals2 : vals1;
  const float* bk = side ? bk2 : bk1;
  const float* bv = side ? bv2 : bv1;

  const int lane = tid & 63, w = tid >> 6;
  const int wr = w >> 1, wc = w & 1;
  const int fr = lane & 15, fq = lane >> 4;
  f32x4 acc[4][4] = {};

  const int srow = tid >> 2;
  const int scol = ((tid & 3) ^ ((srow >> 1) & 3)) * 8;   // swizzled src slot
  const unsigned short* gA0 = A + (size_t)(r0 + srow) * 4096 + scol;
  const unsigned short* gA1 = A + (size_t)(r0 + 64 + srow) * 4096 + scol;
  const unsigned short* gB0 = B + (size_t)(c0 + srow) * 4096 + scol;
  const unsigned short* gB1 = B + (size_t)(c0 + 64 + srow) * 4096 + scol;

  for (int k = 0; k < 4096; k += 64) {
    #pragma unroll
    for (int c = 0; c < 2; c++) {
      gload16(gA0 + k + c * 32, As[c] + tid * 8);
      gload16(gA1 + k + c * 32, As[c] + 2048 + tid * 8);
      gload16(gB0 + k + c * 32, Bs[c] + tid * 8);
      gload16(gB1 + k + c * 32, Bs[c] + 2048 + tid * 8);
    }
    __syncthreads();

    #pragma unroll
    for (int c = 0; c < 2; c++) {
      u16x8 af[4], bfv[4];
      #pragma unroll
      for (int mi = 0; mi < 4; mi++)
        af[mi] = *(const u16x8*)&As[c][rdswz(wr * 64 + mi * 16 + fr, fq)];
      #pragma unroll
      for (int nj = 0; nj < 4; nj++)
        bfv[nj] = *(const u16x8*)&Bs[c][rdswz(wc * 64 + nj * 16 + fr, fq)];
      #pragma unroll
      for (int mi = 0; mi < 4; mi++)
        #pragma unroll
        for (int nj = 0; nj < 4; nj++)
          acc[mi][nj] = __builtin_amdgcn_mfma_f32_16x16x32_bf16(
              as_bf(af[mi]), as_bf(bfv[nj]), acc[mi][nj], 0, 0, 0);
    }
    __syncthreads();
  }

  #pragma unroll
  for (int mi = 0; mi < 4; mi++)
  #pragma unroll
  for (int nj = 0; nj < 4; nj++) {
    f32x4 a = acc[mi][nj];
    #pragma unroll
    for (int j = 0; j < 4; j++) {
      int grow = r0 + wr * 64 + mi * 16 + fq * 4 + j;
      int gcol = c0 + wc * 64 + nj * 16 + fr;
      float bias = gcol < 512 ? bk[gcol] : bv[gcol - 512];
      unsigned short r = f2bf(tanhf(a[j] + bias));
      int prow = ((grow & 63) << 7) | (grow >> 6);
      (gcol < 512 ? kout : vout)[(size_t)prow * 512 + (gcol & 511)] = r;
    }
  }
}

// ---------------- vocab GEMM, XCD remap + BK=64 + swizzle -------------------
__global__ __launch_bounds__(256) void k_gemm_voc(
    const unsigned short* __restrict__ A,       // outs_bf [2048][512]
    const unsigned short* __restrict__ B,       // wvoc [32000][512]
    float* __restrict__ of, const float* __restrict__ bias)
{
  const int L = blockIdx.x;
  const int xcd = L & 7, k = L >> 3;
  const int rb = k & 15, cb = xcd * 32 + (k >> 4);
  if (cb >= 250) return;
  const int r0 = rb * 128, c0 = cb * 128;

  __shared__ __align__(16) unsigned short As[2][128 * 32];
  __shared__ __align__(16) unsigned short Bs[2][128 * 32];
  const int tid = threadIdx.x;
  const int lane = tid & 63, w = tid >> 6;
  const int wr = w >> 1, wc = w & 1;
  const int fr = lane & 15, fq = lane >> 4;
  f32x4 acc[4][4] = {};

  const int srow = tid >> 2;
  const int scol = ((tid & 3) ^ ((srow >> 1) & 3)) * 8;
  const unsigned short* gA0 = A + (size_t)(r0 + srow) * 512 + scol;
  const unsigned short* gA1 = A + (size_t)(r0 + 64 + srow) * 512 + scol;
  const unsigned short* gB0 = B + (size_t)(c0 + srow) * 512 + scol;
  const unsigned short* gB1 = B + (size_t)(c0 + 64 + srow) * 512 + scol;

  for (int kk = 0; kk < 512; kk += 64) {
    #pragma unroll
    for (int c = 0; c < 2; c++) {
      gload16(gA0 + kk + c * 32, As[c] + tid * 8);
      gload16(gA1 + kk + c * 32, As[c] + 2048 + tid * 8);
      gload16(gB0 + kk + c * 32, Bs[c] + tid * 8);
      gload16(gB1 + kk + c * 32, Bs[c] + 2048 + tid * 8);
    }
    __syncthreads();

    #pragma unroll
    for (int c = 0; c < 2; c++) {
      u16x8 af[4], bfv[4];
      #pragma unroll
      for (int mi = 0; mi < 4; mi++)
        af[mi] = *(const u16x8*)&As[c][rdswz(wr * 64 + mi * 16 + fr, fq)];
      #pragma unroll
      for (int nj = 0; nj < 4; nj++)
        bfv[nj] = *(const u16x8*)&Bs[c][rdswz(wc * 64 + nj * 16 + fr, fq)];
      #pragma unroll
      for (int mi = 0; mi < 4; mi++)
        #pragma unroll
        for (int nj = 0; nj < 4; nj++)
          acc[mi][nj] = __builtin_amdgcn_mfma_f32_16x16x32_bf16(
              as_bf(af[mi]), as_bf(bfv[nj]), acc[mi][nj], 0, 0, 0);
    }
    __syncthreads();
  }

  #pragma unroll
  for (int mi = 0; mi < 4; mi++)
  #pragma unroll
  for (int nj = 0; nj < 4; nj++) {
    f32x4 a = acc[mi][nj];
    #pragma unroll
    for (int j = 0; j < 4; j++) {
      int grow = r0 + wr * 64 + mi * 16 + fq * 4 + j;
      int gcol = c0 + wc * 64 + nj * 16 + fr;
      of[(size_t)grow * 32000 + gcol] = a[j] + bias[gcol];
    }
  }
}

// ------------------------- h0 GEMM (A bf16, B f32) --------------------------
__global__ __launch_bounds__(256) void k_gemm_h0(
    const unsigned short* __restrict__ Ap, int lda, const float* __restrict__ Bp,
    int ldb, int M, int N, int kper, float* __restrict__ of)
{
  __shared__ __align__(16) unsigned short As[128 * 32];
  __shared__ __align__(16) unsigned short Bs[128 * 32];
  const int tid = threadIdx.x;
  const int c0 = blockIdx.x * 128, r0 = blockIdx.y * 128;
  const int k0 = blockIdx.z * kper;
  of += (size_t)blockIdx.z * M * N;

  const int lane = tid & 63, w = tid >> 6;
  const int wr = w >> 1, wc = w & 1;
  const int fr = lane & 15, fq = lane >> 4;
  f32x4 acc[4][4] = {};
  const int srow = tid >> 1, shalf = (tid & 1) * 16;

  for (int k = k0; k < k0 + kper; k += 32) {
    u16x8 a0, a1, b0, b1;
    {
      int gr = r0 + srow;
      if (gr < M) {
        const unsigned short* a = Ap + (size_t)gr * lda + k + shalf;
        a0 = *(const u16x8*)a; a1 = *(const u16x8*)(a + 8);
      } else {
        u16x8 z = {0,0,0,0,0,0,0,0}; a0 = z; a1 = z;
      }
    }
    {
      int gr = c0 + srow;
      const float* p = Bp + (size_t)gr * ldb + k + shalf;
      float4 f0 = ((const float4*)p)[0], f1 = ((const float4*)p)[1];
      float4 f2 = ((const float4*)p)[2], f3 = ((const float4*)p)[3];
      b0[0]=f2bf(f0.x); b0[1]=f2bf(f0.y); b0[2]=f2bf(f0.z); b0[3]=f2bf(f0.w);
      b0[4]=f2bf(f1.x); b0[5]=f2bf(f1.y); b0[6]=f2bf(f1.z); b0[7]=f2bf(f1.w);
      b1[0]=f2bf(f2.x); b1[1]=f2bf(f2.y); b1[2]=f2bf(f2.z); b1[3]=f2bf(f2.w);
      b1[4]=f2bf(f3.x); b1[5]=f2bf(f3.y); b1[6]=f2bf(f3.z); b1[7]=f2bf(f3.w);
    }
    *(u16x8*)&As[srow * 32 + shalf]     = a0;
    *(u16x8*)&As[srow * 32 + shalf + 8] = a1;
    *(u16x8*)&Bs[srow * 32 + shalf]     = b0;
    *(u16x8*)&Bs[srow * 32 + shalf + 8] = b1;
    __syncthreads();

    u16x8 af[4], bfv[4];
    #pragma unroll
    for (int mi = 0; mi < 4; mi++)
      af[mi] = *(const u16x8*)&As[(wr * 64 + mi * 16 + fr) * 32 + fq * 8];
    #pragma unroll
    for (int nj = 0; nj < 4; nj++)
      bfv[nj] = *(const u16x8*)&Bs[(wc * 64 + nj * 16 + fr) * 32 + fq * 8];
    #pragma unroll
    for (int mi = 0; mi < 4; mi++)
      #pragma unroll
      for (int nj = 0; nj < 4; nj++)
        acc[mi][nj] = __builtin_amdgcn_mfma_f32_16x16x32_bf16(
            as_bf(af[mi]), as_bf(bfv[nj]), acc[mi][nj], 0, 0, 0);
    __syncthreads();
  }

  #pragma unroll
  for (int mi = 0; mi < 4; mi++)
  #pragma unroll
  for (int nj = 0; nj < 4; nj++) {
    f32x4 a = acc[mi][nj];
    #pragma unroll
    for (int j = 0; j < 4; j++) {
      int grow = r0 + wr * 64 + mi * 16 + fq * 4 + j;
      int gcol = c0 + wc * 64 + nj * 16 + fr;
      if (grow < M) of[(size_t)grow * N + gcol] = a[j];
    }
  }
}

__global__ __launch_bounds__(256) void k_reduce_h0(const float* __restrict__ part,
                                                   const float* __restrict__ b_ctx,
                                                   float* __restrict__ h,
                                                   unsigned short* __restrict__ h_bf) {
  int j = blockIdx.x * 256 + threadIdx.x;   // < 64*512
  float s = b_ctx[j & 511];
  for (int z = 0; z < 8; z++) s += part[z * 32768 + j];
  h[j] = s;
  h_bf[j] = f2bf(s);
}

// ------------------- W_f = W_ih @ W_in  fold (one-time) ---------------------
__global__ __launch_bounds__(256) void k_wf(const float* __restrict__ W_ih,
                                            const float* __restrict__ W_in,
                                            unsigned short* __restrict__ wf_att,
                                            float* __restrict__ wfx) {
  __shared__ float wl[8][512];
  int ic = blockIdx.x, jc = blockIdx.y, tid = threadIdx.x;
  for (int x = tid; x < 8 * 512; x += 256)
    wl[x >> 9][x & 511] = W_ih[(ic * 8 + (x >> 9)) * 512 + (x & 511)];
  __syncthreads();
  int j = jc * 256 + tid;
  if (j >= 1324) return;
  float acc[8] = {};
  for (int d = 0; d < 512; d++) {
    float win = W_in[d * 1324 + j];
    #pragma unroll
    for (int r = 0; r < 8; r++) acc[r] += wl[r][d] * win;
  }
  for (int r = 0; r < 8; r++) {
    int i = ic * 8 + r;
    if (j < 300) wfx[i * 300 + j] = acc[r];
    else         wf_att[i * 1024 + (j - 300)] = f2bf(acc[r]);
  }
}

__global__ __launch_bounds__(256) void k_bfull(const float* __restrict__ W_ih,
                                               const float* __restrict__ b_in,
                                               const float* __restrict__ b_ih,
                                               float* __restrict__ bfull) {
  int i = blockIdx.x * 256 + threadIdx.x;
  if (i >= 1536) return;
  float acc = b_ih[i];
  for (int d = 0; d < 512; d++) acc += W_ih[i * 512 + d] * b_in[d];
  bfull[i] = acc;
}

// gi_x[t*64+b, :] = expl[t,b,:300] @ Wfx^T
__global__ __launch_bounds__(256) void k_gix(const float* __restrict__ expl,
                                             const float* __restrict__ wfx,
                                             float* __restrict__ gi_x) {
  __shared__ float el[16][300];
  int rc = blockIdx.x, ic = blockIdx.y, tid = threadIdx.x;
  for (int x = tid; x < 16 * 300; x += 256)
    el[x / 300][x % 300] = expl[(size_t)(rc * 16 + x / 300) * 300 + (x % 300)];
  __syncthreads();
  int c = ic * 256 + tid;
  float acc[16] = {};
  for (int k = 0; k < 300; k++) {
    float wv = wfx[c * 300 + k];
    #pragma unroll
    for (int r = 0; r < 16; r++) acc[r] += el[r][k] * wv;
  }
  for (int r = 0; r < 16; r++) gi_x[(size_t)(rc * 16 + r) * 1536 + c] = acc[r];
}

// ---- S1: [q|gh] matvec, fully staged + swizzle, ONE barrier ----------------
__global__ __launch_bounds__(256) void k_mv64f(
    const unsigned short* __restrict__ A,      // h_bf [64][512]
    const unsigned short* __restrict__ B,      // wcat [2560][512]
    const float* __restrict__ bq1, const float* __restrict__ bq2,
    const float* __restrict__ b_hh,
    float* __restrict__ qf, float* __restrict__ ghf)
{
  __shared__ __align__(16) unsigned short AL[16 * 2048];   // 64KB
  __shared__ __align__(16) unsigned short BL[16 * 2048];   // 64KB
  const int tid = threadIdx.x;
  const int n0 = blockIdx.x * 64;
  const int srow = tid >> 2;
  const int scol = ((tid & 3) ^ ((srow >> 1) & 3)) * 8;

  #pragma unroll
  for (int c = 0; c < 16; c++) {
    gload16(A + (size_t)srow * 512 + c * 32 + scol, AL + c * 2048 + tid * 8);
    gload16(B + (size_t)(n0 + srow) * 512 + c * 32 + scol, BL + c * 2048 + tid * 8);
  }
  __syncthreads();

  const int lane = tid & 63, w = tid >> 6;
  const int fr = lane & 15, fq = lane >> 4;
  f32x4 acc[4] = {};
  #pragma unroll
  for (int c = 0; c < 16; c++) {
    u16x8 af = *(const u16x8*)(AL + c * 2048 + rdswz(w * 16 + fr, fq));
    #pragma unroll
    for (int nj = 0; nj < 4; nj++) {
      u16x8 bv = *(const u16x8*)(BL + c * 2048 + rdswz(nj * 16 + fr, fq));
      acc[nj] = __builtin_amdgcn_mfma_f32_16x16x32_bf16(as_bf(af), as_bf(bv), acc[nj], 0, 0, 0);
    }
  }
  #pragma unroll
  for (int nj = 0; nj < 4; nj++) {
    #pragma unroll
    for (int j = 0; j < 4; j++) {
      int row = w * 16 + fq * 4 + j;
      int col = n0 + nj * 16 + fr;
      float v = acc[nj][j];
      if (col < 512)       qf[(size_t)row * 1024 + col] = tanhf(v + bq1[col]);
      else if (col < 1024) qf[(size_t)row * 1024 + col] = tanhf(v + bq2[col - 512]);
      else                 ghf[(size_t)row * 1536 + (col - 1024)] = v + b_hh[col - 1024];
    }
  }
}

// ------------------- S2: attention (R6 verbatim) ----------------------------
__global__ __launch_bounds__(256) void k_att(
    const float* __restrict__ qf,
    const unsigned short* __restrict__ keys1, const unsigned short* __restrict__ keys2,
    const unsigned short* __restrict__ vals1, const unsigned short* __restrict__ vals2,
    unsigned short* __restrict__ att_bf)
{
  const int id = blockIdx.x, side = id >> 6, b = id & 63;
  const int tid = threadIdx.x;
  __shared__ float qv[512];
  __shared__ float sred[128][2];
  __shared__ float pr[128];

  for (int i = tid; i < 512; i += 256)
    qv[i] = qf[(size_t)b * 1024 + side * 512 + i];
  __syncthreads();

  const unsigned short* keys = side ? keys2 : keys1;
  {
    int tt = tid >> 1, half = tid & 1;
    const u16x8* krow = (const u16x8*)(keys + ((size_t)(b * 128 + tt)) * 512 + half * 256);
    float acc = 0.f;
    #pragma unroll 4
    for (int k8 = 0; k8 < 32; k8++) {
      u16x8 kv = krow[k8];
      #pragma unroll
      for (int jj = 0; jj < 8; jj++) acc += qv[half * 256 + k8 * 8 + jj] * bf2f(kv[jj]);
    }
    sred[tt][half] = acc;
  }
  __syncthreads();

  if (tid < 64) {
    float s0 = sred[tid][0] + sred[tid][1];
    float s1 = sred[tid + 64][0] + sred[tid + 64][1];
    float m = fmaxf(s0, s1);
    #pragma unroll
    for (int off = 32; off; off >>= 1) m = fmaxf(m, __shfl_xor(m, off));
    float e0 = __expf(s0 - m), e1 = __expf(s1 - m);
    float ss = e0 + e1;
    #pragma unroll
    for (int off = 32; off; off >>= 1) ss += __shfl_xor(ss, off);
    float inv = 1.f / ss;
    pr[tid] = e0 * inv;
    pr[tid + 64] = e1 * inv;
  }
  __syncthreads();

  const unsigned short* vals = side ? vals2 : vals1;
  {
    int a0 = tid * 2;
    float acc0 = 0.f, acc1 = 0.f;
    for (int tt = 0; tt < 128; tt++) {
      float p = pr[tt];
      unsigned v = *(const unsigned*)(vals + ((size_t)(b * 128 + tt)) * 512 + a0);
      acc0 += p * bf2f((unsigned short)(v & 0xffffu));
      acc1 += p * bf2f((unsigned short)(v >> 16));
    }
    att_bf[(size_t)b * 1024 + side * 512 + a0]     = f2bf(acc0);
    att_bf[(size_t)b * 1024 + side * 512 + a0 + 1] = f2bf(acc1);
  }
}

// ---- S3: gi partials, split-K (2x24), fully staged + swizzle ---------------
__global__ __launch_bounds__(256) void k_giK(
    const unsigned short* __restrict__ att_bf,   // [64][1024]
    const unsigned short* __restrict__ wf_att,   // [1536][1024]
    float* __restrict__ gip)
{
  __shared__ __align__(16) unsigned short AL[16 * 2048];
  __shared__ __align__(16) unsigned short BL[16 * 2048];
  const int tid = threadIdx.x;
  const int j = blockIdx.x % 24, kh = blockIdx.x / 24;
  const int n0 = j * 64, k0 = kh * 512;
  const int srow = tid >> 2;
  const int scol = ((tid & 3) ^ ((srow >> 1) & 3)) * 8;

  #pragma unroll
  for (int c = 0; c < 16; c++) {
    gload16(att_bf + (size_t)srow * 1024 + k0 + c * 32 + scol, AL + c * 2048 + tid * 8);
    gload16(wf_att + (size_t)(n0 + srow) * 1024 + k0 + c * 32 + scol, BL + c * 2048 + tid * 8);
  }
  __syncthreads();

  const int lane = tid & 63, w = tid >> 6;
  const int fr = lane & 15, fq = lane >> 4;
  f32x4 acc[4] = {};
  #pragma unroll
  for (int c = 0; c < 16; c++) {
    u16x8 af = *(const u16x8*)(AL + c * 2048 + rdswz(w * 16 + fr, fq));
    #pragma unroll
    for (int nj = 0; nj < 4; nj++) {
      u16x8 bv = *(const u16x8*)(BL + c * 2048 + rdswz(nj * 16 + fr, fq));
      acc[nj] = __builtin_amdgcn_mfma_f32_16x16x32_bf16(as_bf(af), as_bf(bv), acc[nj], 0, 0, 0);
    }
  }
  #pragma unroll
  for (int nj = 0; nj < 4; nj++) {
    #pragma unroll
    for (int jj = 0; jj < 4; jj++) {
      int row = w * 16 + fq * 4 + jj;
      int col = n0 + nj * 16 + fr;
      gip[(size_t)(kh * 64 + row) * 1536 + col] = acc[nj][jj];
    }
  }
}

// ---- S4: combine partials + GRU (R12 verbatim) -----------------------------
__global__ __launch_bounds__(512) void k_gru2(
    int t, const float* __restrict__ gip, const float* __restrict__ gi_x,
    const float* __restrict__ bfull, const float* __restrict__ ghf,
    float* __restrict__ hst, unsigned short* __restrict__ h_bf,
    unsigned short* __restrict__ outs_bf)
{
  const int b = blockIdx.x, d = threadIdx.x;
  size_t gb = (size_t)(t * 64 + b) * 1536;
  float ir = gip[(size_t)b * 1536 + d] + gip[(size_t)(64 + b) * 1536 + d]
           + gi_x[gb + d] + bfull[d];
  float iz = gip[(size_t)b * 1536 + 512 + d] + gip[(size_t)(64 + b) * 1536 + 512 + d]
           + gi_x[gb + 512 + d] + bfull[512 + d];
  float inn = gip[(size_t)b * 1536 + 1024 + d] + gip[(size_t)(64 + b) * 1536 + 1024 + d]
           + gi_x[gb + 1024 + d] + bfull[1024 + d];
  float hv = gru1(ir, iz, inn,
                  ghf[b * 1536 + d], ghf[b * 1536 + 512 + d], ghf[b * 1536 + 1024 + d],
                  hst[b * 512 + d]);
  hst[b * 512 + d] = hv;
  unsigned short bf = f2bf(hv);
  h_bf[b * 512 + d] = bf;
  outs_bf[(size_t)(t * 64 + b) * 512 + d] = bf;
}

// ---------------------------------------------------------------------------
extern "C" void kernel_launch(void* const* d_in, const int* in_sizes, int n_in,
                              void* d_out, int out_size, void* d_ws, size_t ws_size,
                              hipStream_t stream) {
  const float* expl  = (const float*)d_in[0];
  const float* enc1  = (const float*)d_in[1];
  const float* enc2  = (const float*)d_in[2];
  const float* s1e   = (const float*)d_in[3];
  const float* s2e   = (const float*)d_in[4];
  const float* W_ctx = (const float*)d_in[5];
  const float* b_ctx = (const float*)d_in[6];
  const float* Wq1   = (const float*)d_in[7];
  const float* bq1   = (const float*)d_in[8];
  const float* Wk1   = (const float*)d_in[9];
  const float* bk1   = (const float*)d_in[10];
  const float* Wv1   = (const float*)d_in[11];
  const float* bv1   = (const float*)d_in[12];
  const float* Wq2   = (const float*)d_in[13];
  const float* bq2   = (const float*)d_in[14];
  const float* Wk2   = (const float*)d_in[15];
  const float* bk2   = (const float*)d_in[16];
  const float* Wv2   = (const float*)d_in[17];
  const float* bv2   = (const float*)d_in[18];
  const float* W_in  = (const float*)d_in[19];
  const float* b_in  = (const float*)d_in[20];
  const float* W_ih  = (const float*)d_in[21];
  const float* b_ih  = (const float*)d_in[22];
  const float* W_hh  = (const float*)d_in[23];
  const float* b_hh  = (const float*)d_in[24];
  const float* W_voc = (const float*)d_in[25];
  const float* b_voc = (const float*)d_in[26];
  float* out = (float*)d_out;

  char* ws = (char*)d_ws;
  unsigned short* keys1  = (unsigned short*)(ws + 0);
  unsigned short* vals1  = (unsigned short*)(ws + 8388608);
  unsigned short* keys2  = (unsigned short*)(ws + 16777216);
  unsigned short* vals2  = (unsigned short*)(ws + 25165824);
  unsigned short* encbf1 = (unsigned short*)(ws + 33554432);   // 67.1 MB
  unsigned short* encbf2 = (unsigned short*)(ws + 100663296);  // 67.1 MB
  unsigned short* wkv1   = (unsigned short*)(ws + 167772160);  // 8.4 MB
  unsigned short* wkv2   = (unsigned short*)(ws + 176160768);  // 8.4 MB
  unsigned short* wvoc   = (unsigned short*)(ws + 184549376);  // 32.8 MB
  unsigned short* wcat   = (unsigned short*)(ws + 217317376);  // [2560][512]
  unsigned short* wf_att = (unsigned short*)(ws + 219938816);  // [1536][1024]
  float*          wfx    = (float*)(ws + 223084544);
  float*          bfull  = (float*)(ws + 224927744);
  float*          gi_x   = (float*)(ws + 224933888);           // 12.6 MB
  unsigned short* ctx_bf = (unsigned short*)(ws + 237516800);
  float*          part   = (float*)(ws + 239613952);
  float*          hst    = (float*)(ws + 240662528);
  unsigned short* h_bf   = (unsigned short*)(ws + 240793600);
  float*          qf     = (float*)(ws + 240859136);
  float*          ghf    = (float*)(ws + 241121280);
  unsigned short* att_bf = (unsigned short*)(ws + 241514496);
  unsigned short* outs_bf= (unsigned short*)(ws + 241645568);
  float*          gip    = (float*)(ws + 243742720);
  // end ~244.5 MB

  // ---- ONE mega-convert for every f32->bf16 segment ----
  {
    CvtSegs segs;
    const float* srcs[NSEG] = { enc1, enc2, Wk1, Wv1, Wk2, Wv2, W_voc,
                                Wq1, Wq2, W_hh };
    unsigned short* dsts[NSEG] = { encbf1, encbf2, wkv1, wkv1 + 512*4096,
                                   wkv2, wkv2 + 512*4096, wvoc,
                                   wcat, wcat + 512*512, wcat + 1024*512 };
    int ns[NSEG] = { 8192*4096, 8192*4096, 512*4096, 512*4096, 512*4096,
                     512*4096, 32000*512, 512*512, 512*512, 1536*512 };
    int cum = 0;
    for (int s = 0; s < NSEG; s++) {
      segs.src[s] = srcs[s]; segs.dst[s] = dsts[s];
      segs.cum4[s] = cum; cum += ns[s] / 4;
    }
    segs.cum4[NSEG] = cum;
    k_cvt_multi<<<(cum + 255) / 256, 256, 0, stream>>>(segs, cum);
  }

  // ---- fused kv GEMM (both sides, one dispatch, BK=64 + swizzle) ----
  k_gemm_kv<<<dim3(128, 8), 256, 0, stream>>>(
      encbf1, encbf2, wkv1, wkv2, keys1, vals1, keys2, vals2,
      bk1, bv1, bk2, bv2);

  // ---- Wf fold + gi_x ----
  k_wf<<<dim3(192, 6), 256, 0, stream>>>(W_ih, W_in, wf_att, wfx);
  k_bfull<<<6, 256, 0, stream>>>(W_ih, b_in, b_ih, bfull);
  k_gix<<<dim3(128, 6), 256, 0, stream>>>(expl, wfx, gi_x);

  // ---- h0 ----
  k_build_ctx<<<4096, 256, 0, stream>>>(s1e, s2e, ctx_bf);
  k_gemm_h0<<<dim3(4, 1, 8), 256, 0, stream>>>(
      ctx_bf, 16384, W_ctx, 16384, 64, 512, 2048, part);
  k_reduce_h0<<<128, 256, 0, stream>>>(part, b_ctx, hst, h_bf);

  // ---- recurrence: 4 launches per step (R12 chain + swizzle) ----
  for (int t = 0; t < 32; t++) {
    k_mv64f<<<40, 256, 0, stream>>>(h_bf, wcat, bq1, bq2, b_hh, qf, ghf);
    k_att<<<128, 256, 0, stream>>>(qf, keys1, keys2, vals1, vals2, att_bf);
    k_giK<<<48, 256, 0, stream>>>(att_bf, wf_att, gip);
    k_gru2<<<64, 512, 0, stream>>>(t, gip, gi_x, bfull, ghf, hst, h_bf, outs_bf);
  }

  // ---- logits = outs @ W_voc^T + b_voc (XCD-remapped, BK=64 + swizzle) ----
  k_gemm_voc<<<4096, 256, 0, stream>>>(outs_bf, wvoc, out, b_voc);
}